// Round 5
// baseline (2163.467 us; speedup 1.0000x reference)
//
#include <hip/hip_runtime.h>
#include <hip/hip_bf16.h>
#include <math.h>

#define NLAYER 12
#define NB 8
#define NP 800
#define ND 1024
#define NH 8
#define NDH 256
#define NM 4096
#define NS 50
#define NA 32
#define NKEYS 850
#define KPAD 896      // padded key count (multiple of 64)

typedef unsigned short ushort_t;
typedef unsigned int u32;
using f32x4  = __attribute__((ext_vector_type(4))) float;
using short8 = __attribute__((ext_vector_type(8))) short;

__device__ __forceinline__ u32 pack_bf2(float lo, float hi) {
  u32 a = __float_as_uint(lo);
  u32 b = __float_as_uint(hi);
  a += 0x7fffu + ((a >> 16) & 1u);
  b += 0x7fffu + ((b >> 16) & 1u);
  return (a >> 16) | (b & 0xffff0000u);
}
__device__ __forceinline__ ushort_t bf1(float x) {
  u32 a = __float_as_uint(x);
  a += 0x7fffu + ((a >> 16) & 1u);
  return (ushort_t)(a >> 16);
}
__device__ __forceinline__ float ubf(ushort_t h) {
  return __uint_as_float(((u32)h) << 16);
}
__device__ __forceinline__ void async_cp16(const void* g, const void* l) {
  __builtin_amdgcn_global_load_lds(
      (const __attribute__((address_space(1))) u32*)g,
      (__attribute__((address_space(3))) u32*)l, 16, 0, 0);
}

// ---------------------------------------------------------------------------
// conversion kernels
// ---------------------------------------------------------------------------

__global__ void cvt_copy_kernel(const float* __restrict__ src, ushort_t* __restrict__ dst, long n) {
  long i = ((long)blockIdx.x * 256 + threadIdx.x) * 8;
  if (i >= n) return;
  const float4* s4 = reinterpret_cast<const float4*>(src + i);
  float4 a = s4[0], b = s4[1];
  *reinterpret_cast<uint4*>(dst + i) =
      make_uint4(pack_bf2(a.x, a.y), pack_bf2(a.z, a.w),
                 pack_bf2(b.x, b.y), pack_bf2(b.z, b.w));
}

// tiled transpose + cvt: src f32 [z][R][C] -> dst bf16, dst_row = map(src col)
// MODE 0: dst[c][r], row = c.   MODE 1 (g/u interleave): row = (c>>5)*64 + (c&31) + halfOff
template<int MODE>
__global__ __launch_bounds__(256) void transpose_cvt(
    const float* __restrict__ src, long sz, ushort_t* __restrict__ dst, long dz,
    int R, int C, int ldd, int halfOff) {
  __shared__ float Ls[64][65];
  const float* s = src + (long)blockIdx.z * sz;
  ushort_t* d    = dst + (long)blockIdx.z * dz;
  int c0 = blockIdx.x * 64, r0 = blockIdx.y * 64;
  int t = threadIdx.x;
  int rr = t >> 4;
  int cc = (t & 15) * 4;
#pragma unroll
  for (int j = 0; j < 4; ++j) {
    int rl = rr + j * 16;
    int r = r0 + rl;
    float4 v = make_float4(0.f, 0.f, 0.f, 0.f);
    if (r < R) v = *reinterpret_cast<const float4*>(s + (long)r * C + c0 + cc);
    Ls[rl][cc] = v.x; Ls[rl][cc+1] = v.y; Ls[rl][cc+2] = v.z; Ls[rl][cc+3] = v.w;
  }
  __syncthreads();
  int dr = t >> 2;            // src col within tile 0..63
  int rc = (t & 3) * 16;      // src-row chunk base
  int cg = c0 + dr;
  long orow;
  if (MODE == 0) orow = cg;
  else           orow = ((long)(cg >> 5) << 6) + (cg & 31) + halfOff;
  ushort_t* drow = d + orow * ldd + r0 + rc;
#pragma unroll
  for (int i = 0; i < 16; i += 2) {
    int sr = r0 + rc + i;
    if (sr < R) {
      u32 p = pack_bf2(Ls[rc + i][dr], Ls[rc + i + 1][dr]);
      *reinterpret_cast<u32*>(drow + i) = p;
    }
  }
}

// ---------------------------------------------------------------------------
// small kernels
// ---------------------------------------------------------------------------

__global__ void temb_kernel(const float* __restrict__ ts, float* __restrict__ temb) {
  int idx = blockIdx.x * 256 + threadIdx.x;
  if (idx >= NB * ND) return;
  int b = idx >> 10, d = idx & 1023;
  int i = d & 511;
  float f = __expf(-logf(10000.f) * (float)i / 512.f);
  float ang = ts[b] * f;
  temb[idx] = (d < 512) ? sinf(ang) : cosf(ang);
}

__global__ void suffix_kernel(const float* __restrict__ x_t, const float* __restrict__ w,
                              const float* __restrict__ bias, float* __restrict__ h) {
  int m = blockIdx.x;
  __shared__ float xs[NA];
  if (threadIdx.x < NA) xs[threadIdx.x] = x_t[m * NA + threadIdx.x];
  __syncthreads();
  for (int n = threadIdx.x; n < ND; n += 256) {
    float acc = bias[n];
#pragma unroll
    for (int k = 0; k < NA; ++k) acc += xs[k] * w[k * ND + n];
    h[m * ND + n] = acc * 32.0f;
  }
}

__global__ void rope_table_kernel(float* __restrict__ cosT, float* __restrict__ sinT) {
  int idx = blockIdx.x * 256 + threadIdx.x;
  if (idx >= NS * 128) return;
  int s = idx >> 7, i = idx & 127;
  float inv = __expf(-(float)(2 * i) / 256.f * logf(10000.f));
  float ang = (float)(NP + s) * inv;
  cosT[idx] = cosf(ang);
  sinT[idx] = sinf(ang);
}

// merged: rope Q (hh<8), rope K (hh==8), V scatter (hh==9)
// qkv = two bf16 partial slabs (split-K halves), summed here.
__global__ void rope3_kernel(const ushort_t* __restrict__ qkv0, const ushort_t* __restrict__ qkv1,
                             const float* __restrict__ cosT, const float* __restrict__ sinT,
                             ushort_t* __restrict__ qT, ushort_t* __restrict__ k_new,
                             ushort_t* __restrict__ vT_l) {
  int idx = blockIdx.x * 256 + threadIdx.x;
  if (idx >= 400 * 10 * 128) return;
  int i = idx & 127;
  int rest = idx >> 7;
  int hh = rest % 10;
  int m = rest / 10;
  int b = m / NS, s = m % NS;
  if (hh == 9) {
    int d = i;
    long base = (long)m * 2560 + 2304;
    float v0 = ubf(qkv0[base + d])       + ubf(qkv1[base + d]);
    float v1 = ubf(qkv0[base + d + 128]) + ubf(qkv1[base + d + 128]);
    vT_l[((long)(b * 256 + d)) * KPAD + NP + s]       = bf1(v0);
    vT_l[((long)(b * 256 + d + 128)) * KPAD + NP + s] = bf1(v1);
    return;
  }
  float c = cosT[s * 128 + i], sn = sinT[s * 128 + i];
  if (hh < NH) {
    long base = (long)m * 2560 + hh * 256;
    float x1 = ubf(qkv0[base + i])       + ubf(qkv1[base + i]);
    float x2 = ubf(qkv0[base + 128 + i]) + ubf(qkv1[base + 128 + i]);
    ushort_t* dst = qT + (((long)(b * NH + hh) * NS + s) * 256);
    dst[i]       = bf1(x1 * c - x2 * sn);
    dst[128 + i] = bf1(x2 * c + x1 * sn);
  } else {
    long base = (long)m * 2560 + 2048;
    float x1 = ubf(qkv0[base + i])       + ubf(qkv1[base + i]);
    float x2 = ubf(qkv0[base + 128 + i]) + ubf(qkv1[base + 128 + i]);
    ushort_t* dst = k_new + (long)m * 256;
    dst[i]       = bf1(x1 * c - x2 * sn);
    dst[128 + i] = bf1(x2 * c + x1 * sn);
  }
}

template<bool BFOUT>
__global__ void rms_kernel(const float* __restrict__ hin, const float* __restrict__ w,
                           const float* __restrict__ ada, void* __restrict__ outv) {
  int m = blockIdx.x;
  int b = m / NS;
  int d0 = threadIdx.x * 4;
  float4 v = *reinterpret_cast<const float4*>(hin + (long)m * ND + d0);
  float ss = v.x*v.x + v.y*v.y + v.z*v.z + v.w*v.w;
#pragma unroll
  for (int off = 32; off > 0; off >>= 1) ss += __shfl_down(ss, off);
  __shared__ float red[4];
  int lane = threadIdx.x & 63, wid = threadIdx.x >> 6;
  if (lane == 0) red[wid] = ss;
  __syncthreads();
  float tot = red[0] + red[1] + red[2] + red[3];
  float r = rsqrtf(tot * (1.f / ND) + 1e-6f);
  float4 wv = *reinterpret_cast<const float4*>(w + d0);
  float4 o;
  o.x = v.x * r * (1.f + wv.x);
  o.y = v.y * r * (1.f + wv.y);
  o.z = v.z * r * (1.f + wv.z);
  o.w = v.w * r * (1.f + wv.w);
  if (ada) {
    float4 av = *reinterpret_cast<const float4*>(ada + (long)b * ND + d0);
    o.x *= (1.f + av.x); o.y *= (1.f + av.y); o.z *= (1.f + av.z); o.w *= (1.f + av.w);
  }
  if (BFOUT) {
    *reinterpret_cast<uint2*>((ushort_t*)outv + (long)m * ND + d0) =
        make_uint2(pack_bf2(o.x, o.y), pack_bf2(o.z, o.w));
  } else {
    *reinterpret_cast<float4*>((float*)outv + (long)m * ND + d0) = o;
  }
}

// sc f32 [B*400][KPAD] -> P bf16 [B*400][KPAD] (softmax over first 850, zero tail)
__global__ void softmax_kernel(const float* __restrict__ sc, ushort_t* __restrict__ P) {
  int row = blockIdx.x;
  const float* p = sc + (long)row * KPAD;
  ushort_t* o = P + (long)row * KPAD;
  __shared__ float e[NKEYS];
  __shared__ float red[4];
  int lane = threadIdx.x & 63, wid = threadIdx.x >> 6;
  float mx = -1e30f;
  for (int t = threadIdx.x; t < NKEYS; t += 256) { float v = p[t]; e[t] = v; mx = fmaxf(mx, v); }
#pragma unroll
  for (int off = 32; off > 0; off >>= 1) mx = fmaxf(mx, __shfl_down(mx, off));
  if (lane == 0) red[wid] = mx;
  __syncthreads();
  mx = fmaxf(fmaxf(red[0], red[1]), fmaxf(red[2], red[3]));
  __syncthreads();
  float sum = 0.f;
  for (int t = threadIdx.x; t < NKEYS; t += 256) {
    float v = __expf(e[t] - mx);
    e[t] = v;
    sum += v;
  }
#pragma unroll
  for (int off = 32; off > 0; off >>= 1) sum += __shfl_down(sum, off);
  if (lane == 0) red[wid] = sum;
  __syncthreads();
  float inv = 1.f / (red[0] + red[1] + red[2] + red[3]);
  for (int t = threadIdx.x; t < KPAD; t += 256)
    o[t] = (t < NKEYS) ? bf1(e[t] * inv) : (ushort_t)0;
}

__global__ void final_kernel(const float* __restrict__ hf, const float* __restrict__ w,
                             const float* __restrict__ bias, const float* __restrict__ x_t,
                             const float* __restrict__ dt, float* __restrict__ out) {
  int m = blockIdx.x;
  int a = threadIdx.x & 31;
  int kg = threadIdx.x >> 5;
  float acc = 0.f;
  for (int k = kg; k < ND; k += 8) acc += hf[(long)m * ND + k] * w[k * NA + a];
  __shared__ float red[256];
  red[threadIdx.x] = acc;
  __syncthreads();
  if (threadIdx.x < NA) {
    float s = 0.f;
#pragma unroll
    for (int g = 0; g < 8; ++g) s += red[g * 32 + a];
    out[m * NA + a] = x_t[m * NA + a] + dt[0] * (s + bias[a]);
  }
}

// ---------------------------------------------------------------------------
// bf16 MFMA GEMM, BM=BN=64, BK=64, 2-phase double-buffered global_load_lds.
// A bf16 [M][lda], B bf16 [N][ldb] (n-major, k-contig). 4 waves (2x2 of 32x32).
// EPI: 0 = f32 store *scale; 3 = f32 atomicAdd; 4 = bf16 attn scatter; 5 = bf16 store
// SPL: B rows n<nsplit from B1, n<nlim2 from B2, else zpad
// SPLITK: blockIdx.z = k-chunk of kpb (batch z fixed 0); EPI5 writes per-chunk slab
// ---------------------------------------------------------------------------
template<int EPI, bool SPL, bool SPLITK>
__global__ __launch_bounds__(256) void gemm64(
    const ushort_t* __restrict__ A, long az,
    const ushort_t* __restrict__ B1, long b1z,
    const ushort_t* __restrict__ B2, long b2z, int nsplit, int nlim2,
    void* __restrict__ Cv, long cz,
    int M, int N, int K, int lda, int ldb, int ldc,
    float scale, int kpb, const ushort_t* __restrict__ zpad) {
  int z = blockIdx.z;
  int chunk = 0;
  int kbeg = 0, kend = K;
  if (SPLITK) { chunk = z; kbeg = z * kpb; kend = kbeg + kpb; z = 0; }
  const ushort_t* Ab  = A  + (long)z * az;
  const ushort_t* B1b = B1 + (long)z * b1z;
  const ushort_t* B2b = SPL ? (B2 + (long)z * b2z) : nullptr;

  const int m0 = blockIdx.x * 64;
  const int n0 = blockIdx.y * 64;
  const int tid = threadIdx.x;
  const int lane = tid & 63;
  const int wbase = tid & 192;
  const int wid = wbase >> 6;
  const int wm = (wid >> 1) * 32;
  const int wn = (wid & 1) * 32;
  const int l15 = lane & 15;
  const int l4  = lane >> 4;

  __shared__ ushort_t As[2][64 * 64];
  __shared__ ushort_t Bs[2][64 * 64];

  f32x4 acc[2][2] = {};

  const int ci0 = wbase + lane;
  const int row0 = ci0 >> 3;
  const int kc0 = (ci0 & 7) << 3;
  const int ci1 = 256 + ci0;
  const int row1 = ci1 >> 3;
  const int kc1 = (ci1 & 7) << 3;
  int gra0 = m0 + row0; if (gra0 > M - 1) gra0 = M - 1;
  int gra1 = m0 + row1; if (gra1 > M - 1) gra1 = M - 1;
  const int n_0 = n0 + row0;
  const int n_1 = n0 + row1;

  auto stage = [&](int buf, int k0) {
    async_cp16(Ab + (long)gra0 * lda + k0 + kc0, (const char*)As[buf] + ci0 * 16);
    const ushort_t* gp0;
    const ushort_t* gp1;
    if (SPL) {
      gp0 = (n_0 < nsplit) ? B1b + (long)n_0 * ldb + k0 + kc0
          : (n_0 < nlim2)  ? B2b + (long)(n_0 - nsplit) * ldb + k0 + kc0
                           : zpad + kc0;
      gp1 = (n_1 < nsplit) ? B1b + (long)n_1 * ldb + k0 + kc1
          : (n_1 < nlim2)  ? B2b + (long)(n_1 - nsplit) * ldb + k0 + kc1
                           : zpad + kc1;
    } else {
      gp0 = B1b + (long)n_0 * ldb + k0 + kc0;
      gp1 = B1b + (long)n_1 * ldb + k0 + kc1;
    }
    async_cp16(gp0, (const char*)Bs[buf] + ci0 * 16);
    async_cp16(Ab + (long)gra1 * lda + k0 + kc1, (const char*)As[buf] + ci1 * 16);
    async_cp16(gp1, (const char*)Bs[buf] + ci1 * 16);
  };

  const int nt = (kend - kbeg) >> 6;
  stage(0, kbeg);
  __syncthreads();
  int cur = 0;
  for (int t = 0; t < nt; ++t) {
    if (t + 1 < nt) stage(cur ^ 1, kbeg + (t + 1) * 64);
    const ushort_t* Ac = As[cur];
    const ushort_t* Bc = Bs[cur];
#pragma unroll
    for (int ks = 0; ks < 2; ++ks) {
      short8 af[2], bf[2];
#pragma unroll
      for (int mi = 0; mi < 2; ++mi)
        af[mi] = *reinterpret_cast<const short8*>(&Ac[(wm + mi * 16 + l15) * 64 + ks * 32 + l4 * 8]);
#pragma unroll
      for (int ni = 0; ni < 2; ++ni)
        bf[ni] = *reinterpret_cast<const short8*>(&Bc[(wn + ni * 16 + l15) * 64 + ks * 32 + l4 * 8]);
#pragma unroll
      for (int mi = 0; mi < 2; ++mi)
#pragma unroll
        for (int ni = 0; ni < 2; ++ni)
          acc[mi][ni] = __builtin_amdgcn_mfma_f32_16x16x32_bf16(af[mi], bf[ni], acc[mi][ni], 0, 0, 0);
    }
    __syncthreads();
    cur ^= 1;
  }

#pragma unroll
  for (int mi = 0; mi < 2; ++mi) {
#pragma unroll
    for (int ni = 0; ni < 2; ++ni) {
      int col = n0 + wn + ni * 16 + l15;
      int rb  = m0 + wm + mi * 16 + l4 * 4;
      if (col >= N) continue;
#pragma unroll
      for (int r = 0; r < 4; ++r) {
        int row = rb + r;
        if (row >= M) continue;
        float v = acc[mi][ni][r];
        if (EPI == 0) {
          ((float*)Cv)[(long)z * cz + (long)row * ldc + col] = v * scale;
        } else if (EPI == 3) {
          atomicAdd(&((float*)Cv)[(long)row * ldc + col], v);
        } else if (EPI == 4) {
          int hh = row / NS;
          int s  = row - hh * NS;
          ((ushort_t*)Cv)[((long)(blockIdx.z * NS + s)) * 2048 + hh * 256 + col] = bf1(v);
        } else if (EPI == 5) {
          long slab = SPLITK ? (long)chunk : (long)z;
          ((ushort_t*)Cv)[slab * cz + (long)row * ldc + col] = bf1(v);
        }
      }
    }
  }
}

// ---------------------------------------------------------------------------
// bf16 MFMA GEMM, BM=BN=128, BK=64, 2-phase double-buffered (m97-class).
// 4 waves (2x2 of 64x64), 4x4 frags. N must be a multiple of 128.
// EPI: 3 = f32 atomicAdd; 5 = bf16 store into per-chunk slab
// ---------------------------------------------------------------------------
template<int EPI, bool SPLITK>
__global__ __launch_bounds__(256) void gemm128(
    const ushort_t* __restrict__ A,
    const ushort_t* __restrict__ B,
    void* __restrict__ Cv, long cz,
    int M, int K, int lda, int ldb, int ldc, int kpb) {
  const int chunk = SPLITK ? blockIdx.z : 0;
  const int kbeg = SPLITK ? chunk * kpb : 0;
  const int kend = SPLITK ? kbeg + kpb : K;

  const int m0 = blockIdx.x * 128;
  const int n0 = blockIdx.y * 128;
  const int tid = threadIdx.x;
  const int lane = tid & 63;
  const int wid = tid >> 6;
  const int wm = (wid >> 1) * 64;
  const int wn = (wid & 1) * 64;
  const int l15 = lane & 15;
  const int l4  = lane >> 4;

  __shared__ ushort_t As[2][128 * 64];
  __shared__ ushort_t Bs[2][128 * 64];

  f32x4 acc[4][4] = {};

  int arow[4], brow[4], kcs[4];
#pragma unroll
  for (int i = 0; i < 4; ++i) {
    int ci = i * 256 + tid;
    int row = ci >> 3;
    kcs[i] = (ci & 7) << 3;
    int gr = m0 + row; if (gr > M - 1) gr = M - 1;
    arow[i] = gr;
    brow[i] = n0 + row;
  }

  auto stage = [&](int buf, int k0) {
#pragma unroll
    for (int i = 0; i < 4; ++i) {
      int ci = i * 256 + tid;
      async_cp16(A + (long)arow[i] * lda + k0 + kcs[i], (const char*)As[buf] + ci * 16);
      async_cp16(B + (long)brow[i] * ldb + k0 + kcs[i], (const char*)Bs[buf] + ci * 16);
    }
  };

  const int nt = (kend - kbeg) >> 6;
  stage(0, kbeg);
  __syncthreads();
  int cur = 0;
  for (int t = 0; t < nt; ++t) {
    if (t + 1 < nt) stage(cur ^ 1, kbeg + (t + 1) * 64);
    const ushort_t* Ac = As[cur];
    const ushort_t* Bc = Bs[cur];
#pragma unroll
    for (int ks = 0; ks < 2; ++ks) {
      short8 af[4], bf[4];
#pragma unroll
      for (int mi = 0; mi < 4; ++mi)
        af[mi] = *reinterpret_cast<const short8*>(&Ac[(wm + mi * 16 + l15) * 64 + ks * 32 + l4 * 8]);
#pragma unroll
      for (int ni = 0; ni < 4; ++ni)
        bf[ni] = *reinterpret_cast<const short8*>(&Bc[(wn + ni * 16 + l15) * 64 + ks * 32 + l4 * 8]);
#pragma unroll
      for (int mi = 0; mi < 4; ++mi)
#pragma unroll
        for (int ni = 0; ni < 4; ++ni)
          acc[mi][ni] = __builtin_amdgcn_mfma_f32_16x16x32_bf16(af[mi], bf[ni], acc[mi][ni], 0, 0, 0);
    }
    __syncthreads();
    cur ^= 1;
  }

#pragma unroll
  for (int mi = 0; mi < 4; ++mi) {
#pragma unroll
    for (int ni = 0; ni < 4; ++ni) {
      int col = n0 + wn + ni * 16 + l15;
      int rb  = m0 + wm + mi * 16 + l4 * 4;
#pragma unroll
      for (int r = 0; r < 4; ++r) {
        int row = rb + r;
        if (row >= M) continue;
        float v = acc[mi][ni][r];
        if (EPI == 3) {
          atomicAdd(&((float*)Cv)[(long)row * ldc + col], v);
        } else {
          ((ushort_t*)Cv)[(long)chunk * cz + (long)row * ldc + col] = bf1(v);
        }
      }
    }
  }
}

// ---------------------------------------------------------------------------
// gated GEMM 128x128 tile: B = wguT interleaved [8192][1024]
// (64-row granules: 32 g rows then 32 u rows). Wave n-range (64) = 1 granule:
// frags ni 0,1 = g; ni 2,3 = u. Output C[M][4096] = gelu(g)*u bf16.
// ---------------------------------------------------------------------------
__global__ __launch_bounds__(256) void gemm128G(
    const ushort_t* __restrict__ A, const ushort_t* __restrict__ B,
    ushort_t* __restrict__ C, int M, int K, int lda, int ldb, int ldc) {
  const int m0 = blockIdx.x * 128;
  const int n0 = blockIdx.y * 128;
  const int tid = threadIdx.x;
  const int lane = tid & 63;
  const int wid = tid >> 6;
  const int wm = (wid >> 1) * 64;
  const int wn = (wid & 1) * 64;
  const int l15 = lane & 15;
  const int l4  = lane >> 4;

  __shared__ ushort_t As[2][128 * 64];
  __shared__ ushort_t Bs[2][128 * 64];

  f32x4 acc[4][4] = {};

  int arow[4], brow[4], kcs[4];
#pragma unroll
  for (int i = 0; i < 4; ++i) {
    int ci = i * 256 + tid;
    int row = ci >> 3;
    kcs[i] = (ci & 7) << 3;
    int gr = m0 + row; if (gr > M - 1) gr = M - 1;
    arow[i] = gr;
    brow[i] = n0 + row;
  }

  auto stage = [&](int buf, int k0) {
#pragma unroll
    for (int i = 0; i < 4; ++i) {
      int ci = i * 256 + tid;
      async_cp16(A + (long)arow[i] * lda + k0 + kcs[i], (const char*)As[buf] + ci * 16);
      async_cp16(B + (long)brow[i] * ldb + k0 + kcs[i], (const char*)Bs[buf] + ci * 16);
    }
  };

  const int nt = K >> 6;
  stage(0, 0);
  __syncthreads();
  int cur = 0;
  for (int t = 0; t < nt; ++t) {
    if (t + 1 < nt) stage(cur ^ 1, (t + 1) * 64);
    const ushort_t* Ac = As[cur];
    const ushort_t* Bc = Bs[cur];
#pragma unroll
    for (int ks = 0; ks < 2; ++ks) {
      short8 af[4], bf[4];
#pragma unroll
      for (int mi = 0; mi < 4; ++mi)
        af[mi] = *reinterpret_cast<const short8*>(&Ac[(wm + mi * 16 + l15) * 64 + ks * 32 + l4 * 8]);
#pragma unroll
      for (int ni = 0; ni < 4; ++ni)
        bf[ni] = *reinterpret_cast<const short8*>(&Bc[(wn + ni * 16 + l15) * 64 + ks * 32 + l4 * 8]);
#pragma unroll
      for (int mi = 0; mi < 4; ++mi)
#pragma unroll
        for (int ni = 0; ni < 4; ++ni)
          acc[mi][ni] = __builtin_amdgcn_mfma_f32_16x16x32_bf16(af[mi], bf[ni], acc[mi][ni], 0, 0, 0);
    }
    __syncthreads();
    cur ^= 1;
  }

  const int gI = (n0 + wn) >> 6;   // granule index -> output col base gI*32
#pragma unroll
  for (int mi = 0; mi < 4; ++mi) {
#pragma unroll
    for (int ni = 0; ni < 2; ++ni) {
      int col = gI * 32 + ni * 16 + l15;
      int rb  = m0 + wm + mi * 16 + l4 * 4;
#pragma unroll
      for (int r = 0; r < 4; ++r) {
        int row = rb + r;
        if (row >= M) continue;
        float g = acc[mi][ni][r];
        float u = acc[mi][ni + 2][r];
        float inner = 0.7978845608028654f * (g + 0.044715f * g * g * g);
        float t = 0.5f * g * (1.f + tanhf(inner));
        C[(long)row * ldc + col] = bf1(t * u);
      }
    }
  }
}

// ---------------------------------------------------------------------------
// f32-input GEMM (cond path, M=8). EPI: 1=+bias 2=silu(acc+bias)
// ---------------------------------------------------------------------------
template<int EPI>
__global__ __launch_bounds__(256)
void gemm_f32_kernel(const float* __restrict__ A,
                     const float* __restrict__ B1,
                     float* __restrict__ C,
                     int M, int N, int K, int lda, int ldb, int ldc,
                     const float* __restrict__ bias) {
  const int m0 = blockIdx.x * 64;
  const int n0 = blockIdx.y * 64;
  const int tid = threadIdx.x;
  const int lane = tid & 63;
  const int wid = tid >> 6;
  const int wm = (wid >> 1) * 32;
  const int wn = (wid & 1) * 32;
  const int l15 = lane & 15;
  const int l4  = lane >> 4;

  __shared__ __align__(16) ushort_t As[64][72];
  __shared__ __align__(16) ushort_t Bs[64][72];

  f32x4 acc[2][2] = {};

  for (int k0 = 0; k0 < K; k0 += 64) {
#pragma unroll
    for (int pass = 0; pass < 2; ++pass) {
      int c = tid + pass * 256;
      int row = c >> 3;
      int kc = (c & 7) * 8;
      int gr = m0 + row, gk = k0 + kc;
      float v[8];
#pragma unroll
      for (int j = 0; j < 8; ++j)
        v[j] = (gr < M && gk + j < K) ? A[(long)gr * lda + gk + j] : 0.f;
      *reinterpret_cast<uint4*>(&As[row][kc]) =
          make_uint4(pack_bf2(v[0],v[1]), pack_bf2(v[2],v[3]),
                     pack_bf2(v[4],v[5]), pack_bf2(v[6],v[7]));
    }
    {
      int n = tid & 63;
      int kg = tid >> 6;
      int gn = n0 + n;
      u32 pk[8];
#pragma unroll
      for (int kk = 0; kk < 16; kk += 2) {
        int kga = k0 + kg * 16 + kk;
        float v0 = (gn < N && kga < K)     ? B1[(long)kga * ldb + gn] : 0.f;
        float v1 = (gn < N && kga + 1 < K) ? B1[(long)(kga + 1) * ldb + gn] : 0.f;
        pk[kk >> 1] = pack_bf2(v0, v1);
      }
      *reinterpret_cast<uint4*>(&Bs[n][kg * 16])     = make_uint4(pk[0],pk[1],pk[2],pk[3]);
      *reinterpret_cast<uint4*>(&Bs[n][kg * 16 + 8]) = make_uint4(pk[4],pk[5],pk[6],pk[7]);
    }
    __syncthreads();
#pragma unroll
    for (int ks = 0; ks < 2; ++ks) {
      short8 af[2], bfr[2];
#pragma unroll
      for (int mi = 0; mi < 2; ++mi)
        af[mi] = *reinterpret_cast<const short8*>(&As[wm + mi*16 + l15][ks*32 + l4*8]);
#pragma unroll
      for (int ni = 0; ni < 2; ++ni)
        bfr[ni] = *reinterpret_cast<const short8*>(&Bs[wn + ni*16 + l15][ks*32 + l4*8]);
#pragma unroll
      for (int mi = 0; mi < 2; ++mi)
#pragma unroll
        for (int ni = 0; ni < 2; ++ni)
          acc[mi][ni] = __builtin_amdgcn_mfma_f32_16x16x32_bf16(af[mi], bfr[ni], acc[mi][ni], 0, 0, 0);
    }
    __syncthreads();
  }

#pragma unroll
  for (int mi = 0; mi < 2; ++mi) {
#pragma unroll
    for (int ni = 0; ni < 2; ++ni) {
      int col = n0 + wn + ni * 16 + l15;
      int rb  = m0 + wm + mi * 16 + l4 * 4;
#pragma unroll
      for (int r = 0; r < 4; ++r) {
        int row = rb + r;
        if (row < M && col < N) {
          float v = acc[mi][ni][r];
          if (EPI == 1) C[(long)row * ldc + col] = v + bias[col];
          else {
            float t = v + bias[col];
            C[(long)row * ldc + col] = t / (1.f + __expf(-t));
          }
        }
      }
    }
  }
}

// f32-input GEMM with layer batching + split-K, atomicAdd epilogue (ada path, M=8)
__global__ __launch_bounds__(256)
void gemm_f32sk(const float* __restrict__ A,
                const float* __restrict__ B, long bz,
                float* __restrict__ C, long cz,
                int M, int N, int K, int lda, int ldb, int ldc, int nks) {
  const int zz = blockIdx.z;
  const int layer = zz / nks;
  const int chunk = zz % nks;
  const int kpb = K / nks;
  const int kbeg = chunk * kpb, kend = kbeg + kpb;
  const float* Bb = B + (long)layer * bz;
  float* Cb = C + (long)layer * cz;

  const int m0 = blockIdx.x * 64;
  const int n0 = blockIdx.y * 64;
  const int tid = threadIdx.x;
  const int lane = tid & 63;
  const int wid = tid >> 6;
  const int wm = (wid >> 1) * 32;
  const int wn = (wid & 1) * 32;
  const int l15 = lane & 15;
  const int l4  = lane >> 4;

  __shared__ __align__(16) ushort_t As[64][72];
  __shared__ __align__(16) ushort_t Bs[64][72];

  f32x4 acc[2][2] = {};

  for (int k0 = kbeg; k0 < kend; k0 += 64) {
#pragma unroll
    for (int pass = 0; pass < 2; ++pass) {
      int c = tid + pass * 256;
      int row = c >> 3;
      int kc = (c & 7) * 8;
      int gr = m0 + row, gk = k0 + kc;
      float v[8];
#pragma unroll
      for (int j = 0; j < 8; ++j)
        v[j] = (gr < M) ? A[(long)gr * lda + gk + j] : 0.f;
      *reinterpret_cast<uint4*>(&As[row][kc]) =
          make_uint4(pack_bf2(v[0],v[1]), pack_bf2(v[2],v[3]),
                     pack_bf2(v[4],v[5]), pack_bf2(v[6],v[7]));
    }
    {
      int n = tid & 63;
      int kg = tid >> 6;
      int gn = n0 + n;
      u32 pk[8];
#pragma unroll
      for (int kk = 0; kk < 16; kk += 2) {
        int kga = k0 + kg * 16 + kk;
        float v0 = Bb[(long)kga * ldb + gn];
        float v1 = Bb[(long)(kga + 1) * ldb + gn];
        pk[kk >> 1] = pack_bf2(v0, v1);
      }
      *reinterpret_cast<uint4*>(&Bs[n][kg * 16])     = make_uint4(pk[0],pk[1],pk[2],pk[3]);
      *reinterpret_cast<uint4*>(&Bs[n][kg * 16 + 8]) = make_uint4(pk[4],pk[5],pk[6],pk[7]);
    }
    __syncthreads();
#pragma unroll
    for (int ks = 0; ks < 2; ++ks) {
      short8 af[2], bfr[2];
#pragma unroll
      for (int mi = 0; mi < 2; ++mi)
        af[mi] = *reinterpret_cast<const short8*>(&As[wm + mi*16 + l15][ks*32 + l4*8]);
#pragma unroll
      for (int ni = 0; ni < 2; ++ni)
        bfr[ni] = *reinterpret_cast<const short8*>(&Bs[wn + ni*16 + l15][ks*32 + l4*8]);
#pragma unroll
      for (int mi = 0; mi < 2; ++mi)
#pragma unroll
        for (int ni = 0; ni < 2; ++ni)
          acc[mi][ni] = __builtin_amdgcn_mfma_f32_16x16x32_bf16(af[mi], bfr[ni], acc[mi][ni], 0, 0, 0);
    }
    __syncthreads();
  }

#pragma unroll
  for (int mi = 0; mi < 2; ++mi) {
#pragma unroll
    for (int ni = 0; ni < 2; ++ni) {
      int col = n0 + wn + ni * 16 + l15;
      int rb  = m0 + wm + mi * 16 + l4 * 4;
#pragma unroll
      for (int r = 0; r < 4; ++r) {
        int row = rb + r;
        if (row < M && col < N)
          atomicAdd(&Cb[(long)row * ldc + col], acc[mi][ni][r]);
      }
    }
  }
}

// ---------------------------------------------------------------------------
extern "C" void kernel_launch(void* const* d_in, const int* in_sizes, int n_in,
                              void* d_out, int out_size, void* d_ws, size_t ws_size,
                              hipStream_t stream) {
  (void)in_sizes; (void)n_in; (void)out_size; (void)ws_size;
  const float* x_t      = (const float*)d_in[1];
  const float* tstep    = (const float*)d_in[2];
  const float* dtp      = (const float*)d_in[3];
  const float* cache_k  = (const float*)d_in[4];
  const float* cache_v  = (const float*)d_in[5];
  const float* w_act_in = (const float*)d_in[6];
  const float* b_act_in = (const float*)d_in[7];
  const float* w_t1     = (const float*)d_in[8];
  const float* b_t1     = (const float*)d_in[9];
  const float* w_t2     = (const float*)d_in[10];
  const float* b_t2     = (const float*)d_in[11];
  const float* ln1_w    = (const float*)d_in[12];
  const float* ada1_w   = (const float*)d_in[13];
  const float* ln2_w    = (const float*)d_in[14];
  const float* wq       = (const float*)d_in[15];
  const float* wk       = (const float*)d_in[16];
  const float* wv       = (const float*)d_in[17];
  const float* wo       = (const float*)d_in[18];
  const float* wg       = (const float*)d_in[19];
  const float* wu       = (const float*)d_in[20];
  const float* wd       = (const float*)d_in[21];
  const float* lnf_w    = (const float*)d_in[22];
  const float* adaf_w   = (const float*)d_in[23];
  const float* wao      = (const float*)d_in[24];
  const float* bao      = (const float*)d_in[25];
  float* outp = (float*)d_out;

  char* p = (char*)d_ws;
  auto alloc = [&](size_t bytes) { char* r = p; p += (bytes + 255) & ~(size_t)255; return r; };

  ushort_t* wqkvT  = (ushort_t*)alloc((size_t)12 * 2560 * 1024 * 2);
  ushort_t* woT    = (ushort_t*)alloc((size_t)12 * 1024 * 2048 * 2);
  ushort_t* wguT   = (ushort_t*)alloc((size_t)12 * 8192 * 1024 * 2);
  ushort_t* wdT    = (ushort_t*)alloc((size_t)12 * 1024 * 4096 * 2);
  ushort_t* kcache = (ushort_t*)alloc((size_t)12 * 8 * NP * 256 * 2);
  ushort_t* vT     = (ushort_t*)alloc((size_t)12 * 8 * 256 * KPAD * 2);
  ushort_t* qkvp   = (ushort_t*)alloc((size_t)2 * 400 * 2560 * 2);   // split-K partials
  ushort_t* qT     = (ushort_t*)alloc((size_t)8 * 400 * 256 * 2);
  ushort_t* k_new  = (ushort_t*)alloc((size_t)400 * 256 * 2);
  float*    sc     = (float*)alloc((size_t)8 * 400 * KPAD * 4);
  ushort_t* P      = (ushort_t*)alloc((size_t)8 * 400 * KPAD * 2);
  ushort_t* o_buf  = (ushort_t*)alloc((size_t)400 * 2048 * 2);
  ushort_t* t_buf  = (ushort_t*)alloc((size_t)400 * 4096 * 2);
  ushort_t* x_buf  = (ushort_t*)alloc((size_t)400 * 1024 * 2);
  float*    h_buf  = (float*)alloc((size_t)400 * 1024 * 4);
  float*    hf     = (float*)alloc((size_t)400 * 1024 * 4);
  float*    temb   = (float*)alloc(8 * 1024 * 4);
  float*    tmp    = (float*)alloc(8 * 1024 * 4);
  float*    cond   = (float*)alloc(8 * 1024 * 4);
  float*    ada_all= (float*)alloc((size_t)12 * 8 * 1024 * 4);   // zeroed
  float*    adaf_o = (float*)alloc(8 * 1024 * 4);                // zeroed (adjacent)
  float*    cosT   = (float*)alloc(NS * 128 * 4);
  float*    sinT   = (float*)alloc(NS * 128 * 4);
  ushort_t* zpad   = (ushort_t*)alloc(512 * 2);

  hipMemsetAsync(zpad, 0, 512 * 2, stream);
  hipMemsetAsync(ada_all, 0, ((size_t)12 * 8 * 1024 + 8 * 1024) * 4, stream);

  // ---- conversion pass ----
  {
    long n = (long)12 * 8 * NP * 256;
    cvt_copy_kernel<<<(int)((n / 8 + 255) / 256), 256, 0, stream>>>(cache_k, kcache, n);
  }
  transpose_cvt<0><<<dim3(32, 16, 12), 256, 0, stream>>>(wq, (long)1024 * 2048, wqkvT, (long)2560 * 1024, 1024, 2048, 1024, 0);
  transpose_cvt<0><<<dim3(4, 16, 12), 256, 0, stream>>>(wk, (long)1024 * 256, wqkvT + (long)2048 * 1024, (long)2560 * 1024, 1024, 256, 1024, 0);
  transpose_cvt<0><<<dim3(4, 16, 12), 256, 0, stream>>>(wv, (long)1024 * 256, wqkvT + (long)2304 * 1024, (long)2560 * 1024, 1024, 256, 1024, 0);
  transpose_cvt<0><<<dim3(16, 32, 12), 256, 0, stream>>>(wo, (long)2048 * 1024, woT, (long)1024 * 2048, 2048, 1024, 2048, 0);
  transpose_cvt<1><<<dim3(64, 16, 12), 256, 0, stream>>>(wg, (long)1024 * 4096, wguT, (long)8192 * 1024, 1024, 4096, 1024, 0);
  transpose_cvt<1><<<dim3(64, 16, 12), 256, 0, stream>>>(wu, (long)1024 * 4096, wguT, (long)8192 * 1024, 1024, 4096, 1024, 32);
  transpose_cvt<0><<<dim3(16, 64, 12), 256, 0, stream>>>(wd, (long)4096 * 1024, wdT, (long)1024 * 4096, 4096, 1024, 4096, 0);
  transpose_cvt<0><<<dim3(4, 13, 96), 256, 0, stream>>>(cache_v, (long)NP * 256, vT, (long)256 * KPAD, NP, 256, KPAD, 0);

  // ---- embed + cond ----
  temb_kernel<<<32, 256, 0, stream>>>(tstep, temb);
  suffix_kernel<<<400, 256, 0, stream>>>(x_t, w_act_in, b_act_in, h_buf);
  rope_table_kernel<<<25, 256, 0, stream>>>(cosT, sinT);
  gemm_f32_kernel<2><<<dim3(1, 16, 1), 256, 0, stream>>>(temb, w_t1, tmp, NB, ND, ND, ND, ND, ND, b_t1);
  gemm_f32_kernel<1><<<dim3(1, 16, 1), 256, 0, stream>>>(tmp, w_t2, cond, NB, ND, ND, ND, ND, ND, b_t2);
  gemm_f32sk<<<dim3(1, 16, 48), 256, 0, stream>>>(cond, ada1_w, (long)ND * ND, ada_all, (long)NB * ND, NB, ND, ND, ND, ND, ND, 4);
  gemm_f32sk<<<dim3(1, 16, 4), 256, 0, stream>>>(cond, adaf_w, 0, adaf_o, 0, NB, ND, ND, ND, ND, ND, 4);

  for (int l = 0; l < NLAYER; ++l) {
    rms_kernel<true><<<400, 256, 0, stream>>>(h_buf, ln1_w + (long)l * ND, ada_all + (long)l * NB * ND, x_buf);
    // qkv split-K=2, 128x128 tile: grid (4,20,2)=160 blocks, K=512/chunk
    gemm128<5, true><<<dim3(4, 20, 2), 256, 0, stream>>>(
        x_buf, wqkvT + (long)l * 2560 * 1024,
        qkvp, (long)400 * 2560, 400, 1024, 1024, 1024, 2560, 512);
    rope3_kernel<<<2000, 256, 0, stream>>>(qkvp, qkvp + (long)400 * 2560, cosT, sinT,
                                           qT, k_new, vT + (long)l * 8 * 256 * KPAD);
    // scores f32 [8][400][KPAD]  (784 blocks)
    gemm64<0, true, false><<<dim3(7, 14, 8), 256, 0, stream>>>(
        qT, (long)400 * 256,
        kcache + (long)l * 8 * NP * 256, (long)NP * 256,
        k_new, (long)NS * 256, NP, NKEYS,
        sc, (long)400 * KPAD, 400, KPAD, 256, 256, 256, KPAD, 0.0625f, 0, zpad);
    softmax_kernel<<<3200, 256, 0, stream>>>(sc, P);
    // o = P @ V^T  (224 blocks, scatter bf16 into [400][2048])
    gemm64<4, false, false><<<dim3(7, 4, 8), 256, 0, stream>>>(
        P, (long)400 * KPAD,
        vT + (long)l * 8 * 256 * KPAD, (long)256 * KPAD, nullptr, 0, 0, 0,
        o_buf, 0, 400, 256, KPAD, KPAD, KPAD, 2048, 1.f, 0, zpad);
    // h += o @ woT^T  (split-K 4, 448 blocks, 64-tile)
    gemm64<3, false, true><<<dim3(7, 16, 4), 256, 0, stream>>>(
        o_buf, 0, woT + (long)l * 1024 * 2048, 0, nullptr, 0, 0, 0,
        h_buf, 0, 400, 1024, 2048, 2048, 2048, 1024, 1.f, 512, zpad);
    rms_kernel<true><<<400, 256, 0, stream>>>(h_buf, ln2_w + (long)l * ND, nullptr, x_buf);
    // t = gelu(x@wg)*(x@wu), 128x128 tile: grid (4,64)=256 blocks
    gemm128G<<<dim3(4, 64, 1), 256, 0, stream>>>(
        x_buf, wguT + (long)l * 8192 * 1024, t_buf, 400, 1024, 1024, 1024, 4096);
    // h += t @ wdT^T  (split-K 8, 128x128 tile: grid (4,8,8)=256 blocks, K=512/chunk)
    gemm128<3, true><<<dim3(4, 8, 8), 256, 0, stream>>>(
        t_buf, wdT + (long)l * 1024 * 4096,
        h_buf, 0, 400, 4096, 4096, 4096, 1024, 512);
  }

  rms_kernel<false><<<400, 256, 0, stream>>>(h_buf, lnf_w, adaf_o, hf);
  final_kernel<<<400, 256, 0, stream>>>(hf, wao, bao, x_t, dtp, outp);
}

// Round 6
// 2042.071 us; speedup vs baseline: 1.0594x; 1.0594x over previous
//
#include <hip/hip_runtime.h>
#include <hip/hip_bf16.h>
#include <math.h>

#define NLAYER 12
#define NB 8
#define NP 800
#define ND 1024
#define NH 8
#define NDH 256
#define NM 4096
#define NS 50
#define NA 32
#define NKEYS 850
#define KPAD 896      // padded key count
#define CH 128        // flash chunk keys (7 chunks)

typedef unsigned short ushort_t;
typedef unsigned int u32;
using f32x4  = __attribute__((ext_vector_type(4))) float;
using short8 = __attribute__((ext_vector_type(8))) short;

__device__ __forceinline__ u32 pack_bf2(float lo, float hi) {
  u32 a = __float_as_uint(lo);
  u32 b = __float_as_uint(hi);
  a += 0x7fffu + ((a >> 16) & 1u);
  b += 0x7fffu + ((b >> 16) & 1u);
  return (a >> 16) | (b & 0xffff0000u);
}
__device__ __forceinline__ ushort_t bf1(float x) {
  u32 a = __float_as_uint(x);
  a += 0x7fffu + ((a >> 16) & 1u);
  return (ushort_t)(a >> 16);
}
__device__ __forceinline__ float ubf(ushort_t h) {
  return __uint_as_float(((u32)h) << 16);
}
__device__ __forceinline__ void async_cp16(const void* g, const void* l) {
  __builtin_amdgcn_global_load_lds(
      (const __attribute__((address_space(1))) u32*)g,
      (__attribute__((address_space(3))) u32*)l, 16, 0, 0);
}

// ---------------------------------------------------------------------------
// conversion kernels
// ---------------------------------------------------------------------------

// kcache: f32 [rows][256] -> bf16 [rows][256] with d-permute j = 2*(d&127)+(d>>7)
__global__ void cvt_permute_kernel(const float* __restrict__ src, ushort_t* __restrict__ dst, long nrows) {
  long idx = (long)blockIdx.x * 256 + threadIdx.x;
  long row = idx >> 5;
  int t = (int)(idx & 31);
  if (row >= nrows) return;
  const float* s = src + row * 256 + t * 4;
  float4 lo = *reinterpret_cast<const float4*>(s);
  float4 hi = *reinterpret_cast<const float4*>(s + 128);
  ushort_t* d = dst + row * 256 + t * 8;
  *reinterpret_cast<uint4*>(d) =
      make_uint4(pack_bf2(lo.x, hi.x), pack_bf2(lo.y, hi.y),
                 pack_bf2(lo.z, hi.z), pack_bf2(lo.w, hi.w));
}

// tiled transpose + cvt: src f32 [z][R][C] -> dst bf16, dst_row = map(src col)
// MODE 0: row = c
// MODE 1 (g/u interleave): row = (c>>5)*64 + (c&31) + halfOff
// MODE 2 (rope pair-interleave per 256-head): row = (c&~255) + 2*(c&127) + ((c>>7)&1)
template<int MODE>
__global__ __launch_bounds__(256) void transpose_cvt(
    const float* __restrict__ src, long sz, ushort_t* __restrict__ dst, long dz,
    int R, int C, int ldd, int halfOff) {
  __shared__ float Ls[64][65];
  const float* s = src + (long)blockIdx.z * sz;
  ushort_t* d    = dst + (long)blockIdx.z * dz;
  int c0 = blockIdx.x * 64, r0 = blockIdx.y * 64;
  int t = threadIdx.x;
  int rr = t >> 4;
  int cc = (t & 15) * 4;
#pragma unroll
  for (int j = 0; j < 4; ++j) {
    int rl = rr + j * 16;
    int r = r0 + rl;
    float4 v = make_float4(0.f, 0.f, 0.f, 0.f);
    if (r < R) v = *reinterpret_cast<const float4*>(s + (long)r * C + c0 + cc);
    Ls[rl][cc] = v.x; Ls[rl][cc+1] = v.y; Ls[rl][cc+2] = v.z; Ls[rl][cc+3] = v.w;
  }
  __syncthreads();
  int dr = t >> 2;
  int rc = (t & 3) * 16;
  int cg = c0 + dr;
  long orow;
  if (MODE == 0)      orow = cg;
  else if (MODE == 1) orow = ((long)(cg >> 5) << 6) + (cg & 31) + halfOff;
  else                orow = (long)(cg & ~255) + ((cg & 127) << 1) + ((cg >> 7) & 1);
  ushort_t* drow = d + orow * ldd + r0 + rc;
#pragma unroll
  for (int i = 0; i < 16; i += 2) {
    int sr = r0 + rc + i;
    if (sr < R) {
      u32 p = pack_bf2(Ls[rc + i][dr], Ls[rc + i + 1][dr]);
      *reinterpret_cast<u32*>(drow + i) = p;
    }
  }
}

// ---------------------------------------------------------------------------
// small kernels
// ---------------------------------------------------------------------------

__global__ void temb_kernel(const float* __restrict__ ts, float* __restrict__ temb) {
  int idx = blockIdx.x * 256 + threadIdx.x;
  if (idx >= NB * ND) return;
  int b = idx >> 10, d = idx & 1023;
  int i = d & 511;
  float f = __expf(-logf(10000.f) * (float)i / 512.f);
  float ang = ts[b] * f;
  temb[idx] = (d < 512) ? sinf(ang) : cosf(ang);
}

__global__ void suffix_kernel(const float* __restrict__ x_t, const float* __restrict__ w,
                              const float* __restrict__ bias, float* __restrict__ h) {
  int m = blockIdx.x;
  __shared__ float xs[NA];
  if (threadIdx.x < NA) xs[threadIdx.x] = x_t[m * NA + threadIdx.x];
  __syncthreads();
  for (int n = threadIdx.x; n < ND; n += 256) {
    float acc = bias[n];
#pragma unroll
    for (int k = 0; k < NA; ++k) acc += xs[k] * w[k * ND + n];
    h[m * ND + n] = acc * 32.0f;
  }
}

__global__ void rope_table_kernel(float* __restrict__ cosT, float* __restrict__ sinT) {
  int idx = blockIdx.x * 256 + threadIdx.x;
  if (idx >= NS * 128) return;
  int s = idx >> 7, i = idx & 127;
  float inv = __expf(-(float)(2 * i) / 256.f * logf(10000.f));
  float ang = (float)(NP + s) * inv;
  cosT[idx] = cosf(ang);
  sinT[idx] = sinf(ang);
}

template<bool BFOUT>
__global__ void rms_kernel(const float* __restrict__ hin, const float* __restrict__ w,
                           const float* __restrict__ ada, void* __restrict__ outv) {
  int m = blockIdx.x;
  int b = m / NS;
  int d0 = threadIdx.x * 4;
  float4 v = *reinterpret_cast<const float4*>(hin + (long)m * ND + d0);
  float ss = v.x*v.x + v.y*v.y + v.z*v.z + v.w*v.w;
#pragma unroll
  for (int off = 32; off > 0; off >>= 1) ss += __shfl_down(ss, off);
  __shared__ float red[4];
  int lane = threadIdx.x & 63, wid = threadIdx.x >> 6;
  if (lane == 0) red[wid] = ss;
  __syncthreads();
  float tot = red[0] + red[1] + red[2] + red[3];
  float r = rsqrtf(tot * (1.f / ND) + 1e-6f);
  float4 wv = *reinterpret_cast<const float4*>(w + d0);
  float4 o;
  o.x = v.x * r * (1.f + wv.x);
  o.y = v.y * r * (1.f + wv.y);
  o.z = v.z * r * (1.f + wv.z);
  o.w = v.w * r * (1.f + wv.w);
  if (ada) {
    float4 av = *reinterpret_cast<const float4*>(ada + (long)b * ND + d0);
    o.x *= (1.f + av.x); o.y *= (1.f + av.y); o.z *= (1.f + av.z); o.w *= (1.f + av.w);
  }
  if (BFOUT) {
    *reinterpret_cast<uint2*>((ushort_t*)outv + (long)m * ND + d0) =
        make_uint2(pack_bf2(o.x, o.y), pack_bf2(o.z, o.w));
  } else {
    *reinterpret_cast<float4*>((float*)outv + (long)m * ND + d0) = o;
  }
}

__global__ void final_kernel(const float* __restrict__ hf, const float* __restrict__ w,
                             const float* __restrict__ bias, const float* __restrict__ x_t,
                             const float* __restrict__ dt, float* __restrict__ out) {
  int m = blockIdx.x;
  int a = threadIdx.x & 31;
  int kg = threadIdx.x >> 5;
  float acc = 0.f;
  for (int k = kg; k < ND; k += 8) acc += hf[(long)m * ND + k] * w[k * NA + a];
  __shared__ float red[256];
  red[threadIdx.x] = acc;
  __syncthreads();
  if (threadIdx.x < NA) {
    float s = 0.f;
#pragma unroll
    for (int g = 0; g < 8; ++g) s += red[g * 32 + a];
    out[m * NA + a] = x_t[m * NA + a] + dt[0] * (s + bias[a]);
  }
}

// ---------------------------------------------------------------------------
// generic 64x64 GEMM (2-phase dbuf), EPI 3 = f32 atomicAdd (wo / wd path)
// ---------------------------------------------------------------------------
__global__ __launch_bounds__(256) void gemm64acc(
    const ushort_t* __restrict__ A,
    const ushort_t* __restrict__ B,
    float* __restrict__ C,
    int M, int N, int K, int lda, int ldb, int ldc, int kpb) {
  const int kbeg = blockIdx.z * kpb;
  const int kend = kbeg + kpb;

  const int m0 = blockIdx.x * 64;
  const int n0 = blockIdx.y * 64;
  const int tid = threadIdx.x;
  const int lane = tid & 63;
  const int wbase = tid & 192;
  const int wid = wbase >> 6;
  const int wm = (wid >> 1) * 32;
  const int wn = (wid & 1) * 32;
  const int l15 = lane & 15;
  const int l4  = lane >> 4;

  __shared__ ushort_t As[2][64 * 64];
  __shared__ ushort_t Bs[2][64 * 64];

  f32x4 acc[2][2] = {};

  const int ci0 = wbase + lane;
  const int row0 = ci0 >> 3;
  const int kc0 = (ci0 & 7) << 3;
  const int ci1 = 256 + ci0;
  const int row1 = ci1 >> 3;
  const int kc1 = (ci1 & 7) << 3;
  int gra0 = m0 + row0; if (gra0 > M - 1) gra0 = M - 1;
  int gra1 = m0 + row1; if (gra1 > M - 1) gra1 = M - 1;
  const int n_0 = n0 + row0;
  const int n_1 = n0 + row1;

  auto stage = [&](int buf, int k0) {
    async_cp16(A + (long)gra0 * lda + k0 + kc0, (const char*)As[buf] + ci0 * 16);
    async_cp16(B + (long)n_0 * ldb + k0 + kc0, (const char*)Bs[buf] + ci0 * 16);
    async_cp16(A + (long)gra1 * lda + k0 + kc1, (const char*)As[buf] + ci1 * 16);
    async_cp16(B + (long)n_1 * ldb + k0 + kc1, (const char*)Bs[buf] + ci1 * 16);
  };

  const int nt = (kend - kbeg) >> 6;
  stage(0, kbeg);
  __syncthreads();
  int cur = 0;
  for (int t = 0; t < nt; ++t) {
    if (t + 1 < nt) stage(cur ^ 1, kbeg + (t + 1) * 64);
    const ushort_t* Ac = As[cur];
    const ushort_t* Bc = Bs[cur];
#pragma unroll
    for (int ks = 0; ks < 2; ++ks) {
      short8 af[2], bf[2];
#pragma unroll
      for (int mi = 0; mi < 2; ++mi)
        af[mi] = *reinterpret_cast<const short8*>(&Ac[(wm + mi * 16 + l15) * 64 + ks * 32 + l4 * 8]);
#pragma unroll
      for (int ni = 0; ni < 2; ++ni)
        bf[ni] = *reinterpret_cast<const short8*>(&Bc[(wn + ni * 16 + l15) * 64 + ks * 32 + l4 * 8]);
#pragma unroll
      for (int mi = 0; mi < 2; ++mi)
#pragma unroll
        for (int ni = 0; ni < 2; ++ni)
          acc[mi][ni] = __builtin_amdgcn_mfma_f32_16x16x32_bf16(af[mi], bf[ni], acc[mi][ni], 0, 0, 0);
    }
    __syncthreads();
    cur ^= 1;
  }

#pragma unroll
  for (int mi = 0; mi < 2; ++mi) {
#pragma unroll
    for (int ni = 0; ni < 2; ++ni) {
      int col = n0 + wn + ni * 16 + l15;
      int rb  = m0 + wm + mi * 16 + l4 * 4;
      if (col >= N) continue;
#pragma unroll
      for (int r = 0; r < 4; ++r) {
        int row = rb + r;
        if (row >= M) continue;
        atomicAdd(&C[(long)row * ldc + col], acc[mi][ni][r]);
      }
    }
  }
}

// ---------------------------------------------------------------------------
// qkv GEMM with fused RoPE epilogue. A = x_buf [400][1024], B = wqkvT
// (rows pair-interleaved j-space for q/k sections; v natural).
// cols [0,2048)=q -> qT[bh][50][256]; [2048,2304)=k -> k_new; [2304,2560)=v -> vT scatter
// ---------------------------------------------------------------------------
__global__ __launch_bounds__(256) void gemm64rope(
    const ushort_t* __restrict__ A,
    const ushort_t* __restrict__ B,
    const float* __restrict__ cosT, const float* __restrict__ sinT,
    ushort_t* __restrict__ qTo, ushort_t* __restrict__ k_new,
    ushort_t* __restrict__ vT_l) {
  const int M = 400, K = 1024, lda = 1024, ldb = 1024;
  const int m0 = blockIdx.x * 64;
  const int n0 = blockIdx.y * 64;
  const int tid = threadIdx.x;
  const int lane = tid & 63;
  const int wbase = tid & 192;
  const int wid = wbase >> 6;
  const int wm = (wid >> 1) * 32;
  const int wn = (wid & 1) * 32;
  const int l15 = lane & 15;
  const int l4  = lane >> 4;

  __shared__ ushort_t As[2][64 * 64];
  __shared__ ushort_t Bs[2][64 * 64];

  f32x4 acc[2][2] = {};

  const int ci0 = wbase + lane;
  const int row0 = ci0 >> 3;
  const int kc0 = (ci0 & 7) << 3;
  const int ci1 = 256 + ci0;
  const int row1 = ci1 >> 3;
  const int kc1 = (ci1 & 7) << 3;
  int gra0 = m0 + row0; if (gra0 > M - 1) gra0 = M - 1;
  int gra1 = m0 + row1; if (gra1 > M - 1) gra1 = M - 1;
  const int n_0 = n0 + row0;
  const int n_1 = n0 + row1;

  auto stage = [&](int buf, int k0) {
    async_cp16(A + (long)gra0 * lda + k0 + kc0, (const char*)As[buf] + ci0 * 16);
    async_cp16(B + (long)n_0 * ldb + k0 + kc0, (const char*)Bs[buf] + ci0 * 16);
    async_cp16(A + (long)gra1 * lda + k0 + kc1, (const char*)As[buf] + ci1 * 16);
    async_cp16(B + (long)n_1 * ldb + k0 + kc1, (const char*)Bs[buf] + ci1 * 16);
  };

  stage(0, 0);
  __syncthreads();
  int cur = 0;
  for (int t = 0; t < 16; ++t) {
    if (t + 1 < 16) stage(cur ^ 1, (t + 1) * 64);
    const ushort_t* Ac = As[cur];
    const ushort_t* Bc = Bs[cur];
#pragma unroll
    for (int ks = 0; ks < 2; ++ks) {
      short8 af[2], bf[2];
#pragma unroll
      for (int mi = 0; mi < 2; ++mi)
        af[mi] = *reinterpret_cast<const short8*>(&Ac[(wm + mi * 16 + l15) * 64 + ks * 32 + l4 * 8]);
#pragma unroll
      for (int ni = 0; ni < 2; ++ni)
        bf[ni] = *reinterpret_cast<const short8*>(&Bc[(wn + ni * 16 + l15) * 64 + ks * 32 + l4 * 8]);
#pragma unroll
      for (int mi = 0; mi < 2; ++mi)
#pragma unroll
        for (int ni = 0; ni < 2; ++ni)
          acc[mi][ni] = __builtin_amdgcn_mfma_f32_16x16x32_bf16(af[mi], bf[ni], acc[mi][ni], 0, 0, 0);
    }
    __syncthreads();
    cur ^= 1;
  }

#pragma unroll
  for (int mi = 0; mi < 2; ++mi) {
#pragma unroll
    for (int ni = 0; ni < 2; ++ni) {
      int col = n0 + wn + ni * 16 + l15;
      int rb  = m0 + wm + mi * 16 + l4 * 4;
      float pv[4];
#pragma unroll
      for (int r = 0; r < 4; ++r) pv[r] = __shfl_xor(acc[mi][ni][r], 1);
#pragma unroll
      for (int r = 0; r < 4; ++r) {
        int row = rb + r;
        if (row >= 400) continue;
        int b = row / NS, s = row - b * NS;
        float v = acc[mi][ni][r];
        if (col < 2304) {
          int j = col & 255;
          int i = j >> 1;
          float c = cosT[s * 128 + i], sn = sinT[s * 128 + i];
          float o = (col & 1) ? (v * c + pv[r] * sn) : (v * c - pv[r] * sn);
          if (col < 2048)
            qTo[((long)((b << 3) + (col >> 8)) * NS + s) * 256 + j] = bf1(o);
          else
            k_new[(long)row * 256 + j] = bf1(o);
        } else {
          vT_l[((long)(b * 256 + (col - 2304))) * KPAD + NP + s] = bf1(v);
        }
      }
    }
  }
}

// ---------------------------------------------------------------------------
// flash-decoding attention: grid (64 bh, 7 chunks of 128 keys), 256 threads.
// Q [64bh][50][256] j-space; K = kcache_l [8][800][256] j-space + k_new [400][256];
// V^T = vT_l [8*256][KPAD]. Writes opart f32 [bh][7][50][256] + m,l [bh][7][50].
// ---------------------------------------------------------------------------
__global__ __launch_bounds__(256) void flash_kernel(
    const ushort_t* __restrict__ qT,
    const ushort_t* __restrict__ kcache_l,
    const ushort_t* __restrict__ k_new,
    const ushort_t* __restrict__ vT_l,
    const ushort_t* __restrict__ zpad,
    float* __restrict__ opart, float* __restrict__ mpart, float* __restrict__ lpart) {
  const int bh = blockIdx.x;
  const int ch = blockIdx.y;
  const int b  = bh >> 3;
  const int tid = threadIdx.x;
  const int lane = tid & 63;
  const int w = tid >> 6;
  const int wm = (w >> 1) * 32;
  const int wns = (w & 1) * 64;
  const int l15 = lane & 15;
  const int l4  = lane >> 4;

  __shared__ __align__(16) char lds[66560];
  ushort_t* Qs = (ushort_t*)lds;               // [64][256]  32KB
  ushort_t* Ks = (ushort_t*)(lds + 32768);     // [128][64]  16KB
  ushort_t* Ps = (ushort_t*)(lds + 49152);     // [64][128]  16KB
  float* SMm = (float*)(lds + 65536);          // [2][64]
  float* SMl = (float*)(lds + 66048);          // [2][64]
  ushort_t* Vs = (ushort_t*)lds;               // [256][64]  32KB (reuses Q)

  // stage Q (rows >=50 duplicate row 49)
#pragma unroll
  for (int i = 0; i < 8; ++i) {
    int ci = i * 256 + tid;
    int qrow = ci >> 5; int seg = ci & 31;
    int qr = qrow < NS ? qrow : NS - 1;
    async_cp16(qT + ((long)bh * NS + qr) * 256 + seg * 8, (char*)Qs + ci * 16);
  }

  f32x4 s2[2][4] = {};
  for (int kk = 0; kk < 4; ++kk) {
#pragma unroll
    for (int i = 0; i < 4; ++i) {
      int ci = i * 256 + tid;
      int krow = ci >> 3; int seg = ci & 7;
      int key = ch * CH + krow;
      const ushort_t* src;
      if (key < NP)         src = kcache_l + ((long)(b * NP + key)) * 256 + kk * 64 + seg * 8;
      else if (key < NKEYS) src = k_new + ((long)(b * NS + key - NP)) * 256 + kk * 64 + seg * 8;
      else                  src = zpad + seg * 8;
      async_cp16(src, (char*)Ks + ci * 16);
    }
    __syncthreads();
#pragma unroll
    for (int ks = 0; ks < 2; ++ks) {
      short8 af[2], bf[4];
#pragma unroll
      for (int mi = 0; mi < 2; ++mi)
        af[mi] = *reinterpret_cast<const short8*>(&Qs[(wm + mi * 16 + l15) * 256 + kk * 64 + ks * 32 + l4 * 8]);
#pragma unroll
      for (int ni = 0; ni < 4; ++ni)
        bf[ni] = *reinterpret_cast<const short8*>(&Ks[(wns + ni * 16 + l15) * 64 + ks * 32 + l4 * 8]);
#pragma unroll
      for (int mi = 0; mi < 2; ++mi)
#pragma unroll
        for (int ni = 0; ni < 4; ++ni)
          s2[mi][ni] = __builtin_amdgcn_mfma_f32_16x16x32_bf16(af[mi], bf[ni], s2[mi][ni], 0, 0, 0);
    }
    __syncthreads();
  }

  // scale + mask + row max (this wave's 64 cols)
  float mx[2][4];
#pragma unroll
  for (int mi = 0; mi < 2; ++mi)
#pragma unroll
    for (int r = 0; r < 4; ++r) mx[mi][r] = -1e30f;
#pragma unroll
  for (int mi = 0; mi < 2; ++mi)
#pragma unroll
    for (int ni = 0; ni < 4; ++ni) {
      int key = ch * CH + wns + ni * 16 + l15;
      bool valid = key < NKEYS;
#pragma unroll
      for (int r = 0; r < 4; ++r) {
        float v = s2[mi][ni][r] * 0.0625f;
        v = valid ? v : -1e30f;
        s2[mi][ni][r] = v;
        mx[mi][r] = fmaxf(mx[mi][r], v);
      }
    }
#pragma unroll
  for (int off = 1; off < 16; off <<= 1)
#pragma unroll
    for (int mi = 0; mi < 2; ++mi)
#pragma unroll
      for (int r = 0; r < 4; ++r)
        mx[mi][r] = fmaxf(mx[mi][r], __shfl_xor(mx[mi][r], off));
  if (l15 == 0) {
#pragma unroll
    for (int mi = 0; mi < 2; ++mi)
#pragma unroll
      for (int r = 0; r < 4; ++r)
        SMm[(w & 1) * 64 + wm + mi * 16 + l4 * 4 + r] = mx[mi][r];
  }
  __syncthreads();
  float mrow[2][4], sum[2][4];
#pragma unroll
  for (int mi = 0; mi < 2; ++mi)
#pragma unroll
    for (int r = 0; r < 4; ++r) {
      int row = wm + mi * 16 + l4 * 4 + r;
      mrow[mi][r] = fmaxf(SMm[row], SMm[64 + row]);
      sum[mi][r] = 0.f;
    }
  // e = exp(s - m), write P to LDS, row sums
#pragma unroll
  for (int mi = 0; mi < 2; ++mi)
#pragma unroll
    for (int ni = 0; ni < 4; ++ni) {
      int colp = wns + ni * 16 + l15;
#pragma unroll
      for (int r = 0; r < 4; ++r) {
        float e = __expf(s2[mi][ni][r] - mrow[mi][r]);
        Ps[(wm + mi * 16 + l4 * 4 + r) * 128 + colp] = bf1(e);
        sum[mi][r] += e;
      }
    }
#pragma unroll
  for (int off = 1; off < 16; off <<= 1)
#pragma unroll
    for (int mi = 0; mi < 2; ++mi)
#pragma unroll
      for (int r = 0; r < 4; ++r)
        sum[mi][r] += __shfl_xor(sum[mi][r], off);
  if (l15 == 0) {
#pragma unroll
    for (int mi = 0; mi < 2; ++mi)
#pragma unroll
      for (int r = 0; r < 4; ++r)
        SMl[(w & 1) * 64 + wm + mi * 16 + l4 * 4 + r] = sum[mi][r];
  }
  __syncthreads();
  if ((w & 1) == 0 && l15 == 0) {
#pragma unroll
    for (int mi = 0; mi < 2; ++mi)
#pragma unroll
      for (int r = 0; r < 4; ++r) {
        int row = wm + mi * 16 + l4 * 4 + r;
        if (row < NS) {
          mpart[((long)bh * 7 + ch) * NS + row] = mrow[mi][r];
          lpart[((long)bh * 7 + ch) * NS + row] = SMl[row] + SMl[64 + row];
        }
      }
  }

  // PV: O[64][256] = Ps[64][128] @ V[128][256]; V^T staged 64-key slices
  f32x4 o2[2][8] = {};
  for (int kk = 0; kk < 2; ++kk) {
#pragma unroll
    for (int i = 0; i < 8; ++i) {
      int ci = i * 256 + tid;
      int vd = ci >> 3; int seg = ci & 7;
      async_cp16(vT_l + ((long)(b * 256 + vd)) * KPAD + ch * CH + kk * 64 + seg * 8,
                 (char*)Vs + ci * 16);
    }
    __syncthreads();
#pragma unroll
    for (int ks = 0; ks < 2; ++ks) {
      short8 af[2], bf[8];
#pragma unroll
      for (int mi = 0; mi < 2; ++mi)
        af[mi] = *reinterpret_cast<const short8*>(&Ps[(wm + mi * 16 + l15) * 128 + kk * 64 + ks * 32 + l4 * 8]);
#pragma unroll
      for (int ni = 0; ni < 8; ++ni)
        bf[ni] = *reinterpret_cast<const short8*>(&Vs[((w & 1) * 128 + ni * 16 + l15) * 64 + ks * 32 + l4 * 8]);
#pragma unroll
      for (int mi = 0; mi < 2; ++mi)
#pragma unroll
        for (int ni = 0; ni < 8; ++ni)
          o2[mi][ni] = __builtin_amdgcn_mfma_f32_16x16x32_bf16(af[mi], bf[ni], o2[mi][ni], 0, 0, 0);
    }
    __syncthreads();
  }

#pragma unroll
  for (int mi = 0; mi < 2; ++mi)
#pragma unroll
    for (int ni = 0; ni < 8; ++ni) {
      int col = (w & 1) * 128 + ni * 16 + l15;
#pragma unroll
      for (int r = 0; r < 4; ++r) {
        int row = wm + mi * 16 + l4 * 4 + r;
        if (row < NS)
          opart[(((long)bh * 7 + ch) * NS + row) * 256 + col] = o2[mi][ni][r];
      }
    }
}

// combine 7 chunk partials -> o_buf bf16 [400][2048]
__global__ void att_combine(const float* __restrict__ opart, const float* __restrict__ mpart,
                            const float* __restrict__ lpart, ushort_t* __restrict__ o_buf) {
  int blk = blockIdx.x;           // b*50+s
  int b = blk / NS, s = blk - b * NS;
  int d = threadIdx.x;            // 0..255
  for (int h = 0; h < NH; ++h) {
    int bh = b * NH + h;
    float mv[7];
    float m = -1e30f;
#pragma unroll
    for (int c = 0; c < 7; ++c) {
      mv[c] = mpart[((long)bh * 7 + c) * NS + s];
      m = fmaxf(m, mv[c]);
    }
    float den = 0.f, o = 0.f;
#pragma unroll
    for (int c = 0; c < 7; ++c) {
      float wgt = __expf(mv[c] - m);
      den += wgt * lpart[((long)bh * 7 + c) * NS + s];
      o   += wgt * opart[(((long)bh * 7 + c) * NS + s) * 256 + d];
    }
    o_buf[(long)blk * 2048 + h * 256 + d] = bf1(o / den);
  }
}

// ---------------------------------------------------------------------------
// gated GEMM (2-phase): B = wguT interleaved [8192][1024]
// 4 waves as 4x1 (wave tile 16m x 64n). out = gelu(g)*u, bf16 [M][4096].
// ---------------------------------------------------------------------------
__global__ __launch_bounds__(256) void gemm64G(
    const ushort_t* __restrict__ A, const ushort_t* __restrict__ B,
    ushort_t* __restrict__ C, int M, int K, int lda, int ldb, int ldc) {
  const int m0 = blockIdx.x * 64;
  const int n0 = blockIdx.y * 64;
  const int tid = threadIdx.x;
  const int lane = tid & 63;
  const int wbase = tid & 192;
  const int wid = wbase >> 6;
  const int l15 = lane & 15;
  const int l4  = lane >> 4;

  __shared__ ushort_t As[2][64 * 64];
  __shared__ ushort_t Bs[2][64 * 64];

  f32x4 acc[4] = {};

  const int ci0 = wbase + lane;
  const int row0 = ci0 >> 3;
  const int kc0 = (ci0 & 7) << 3;
  const int ci1 = 256 + ci0;
  const int row1 = ci1 >> 3;
  const int kc1 = (ci1 & 7) << 3;
  int gra0 = m0 + row0; if (gra0 > M - 1) gra0 = M - 1;
  int gra1 = m0 + row1; if (gra1 > M - 1) gra1 = M - 1;

  auto stage = [&](int buf, int k0) {
    async_cp16(A + (long)gra0 * lda + k0 + kc0, (const char*)As[buf] + ci0 * 16);
    async_cp16(B + (long)(n0 + row0) * ldb + k0 + kc0, (const char*)Bs[buf] + ci0 * 16);
    async_cp16(A + (long)gra1 * lda + k0 + kc1, (const char*)As[buf] + ci1 * 16);
    async_cp16(B + (long)(n0 + row1) * ldb + k0 + kc1, (const char*)Bs[buf] + ci1 * 16);
  };

  const int nt = K >> 6;
  stage(0, 0);
  __syncthreads();
  int cur = 0;
  for (int t = 0; t < nt; ++t) {
    if (t + 1 < nt) stage(cur ^ 1, (t + 1) * 64);
    const ushort_t* Ac = As[cur];
    const ushort_t* Bc = Bs[cur];
#pragma unroll
    for (int ks = 0; ks < 2; ++ks) {
      short8 af = *reinterpret_cast<const short8*>(&Ac[(wid * 16 + l15) * 64 + ks * 32 + l4 * 8]);
#pragma unroll
      for (int ni = 0; ni < 4; ++ni) {
        short8 bf = *reinterpret_cast<const short8*>(&Bc[(ni * 16 + l15) * 64 + ks * 32 + l4 * 8]);
        acc[ni] = __builtin_amdgcn_mfma_f32_16x16x32_bf16(af, bf, acc[ni], 0, 0, 0);
      }
    }
    __syncthreads();
    cur ^= 1;
  }

#pragma unroll
  for (int ni = 0; ni < 2; ++ni) {
    int col = (n0 >> 1) + ni * 16 + l15;
    int rb  = m0 + wid * 16 + l4 * 4;
#pragma unroll
    for (int r = 0; r < 4; ++r) {
      int row = rb + r;
      if (row >= M) continue;
      float g = acc[ni][r];
      float u = acc[ni + 2][r];
      float inner = 0.7978845608028654f * (g + 0.044715f * g * g * g);
      float t = 0.5f * g * (1.f + tanhf(inner));
      C[(long)row * ldc + col] = bf1(t * u);
    }
  }
}

// ---------------------------------------------------------------------------
// f32-input GEMM (cond path, M=8). EPI: 1=+bias 2=silu(acc+bias)
// ---------------------------------------------------------------------------
template<int EPI>
__global__ __launch_bounds__(256)
void gemm_f32_kernel(const float* __restrict__ A,
                     const float* __restrict__ B1,
                     float* __restrict__ C,
                     int M, int N, int K, int lda, int ldb, int ldc,
                     const float* __restrict__ bias) {
  const int m0 = blockIdx.x * 64;
  const int n0 = blockIdx.y * 64;
  const int tid = threadIdx.x;
  const int lane = tid & 63;
  const int wid = tid >> 6;
  const int wm = (wid >> 1) * 32;
  const int wn = (wid & 1) * 32;
  const int l15 = lane & 15;
  const int l4  = lane >> 4;

  __shared__ __align__(16) ushort_t As[64][72];
  __shared__ __align__(16) ushort_t Bs[64][72];

  f32x4 acc[2][2] = {};

  for (int k0 = 0; k0 < K; k0 += 64) {
#pragma unroll
    for (int pass = 0; pass < 2; ++pass) {
      int c = tid + pass * 256;
      int row = c >> 3;
      int kc = (c & 7) * 8;
      int gr = m0 + row, gk = k0 + kc;
      float v[8];
#pragma unroll
      for (int j = 0; j < 8; ++j)
        v[j] = (gr < M && gk + j < K) ? A[(long)gr * lda + gk + j] : 0.f;
      *reinterpret_cast<uint4*>(&As[row][kc]) =
          make_uint4(pack_bf2(v[0],v[1]), pack_bf2(v[2],v[3]),
                     pack_bf2(v[4],v[5]), pack_bf2(v[6],v[7]));
    }
    {
      int n = tid & 63;
      int kg = tid >> 6;
      int gn = n0 + n;
      u32 pk[8];
#pragma unroll
      for (int kk = 0; kk < 16; kk += 2) {
        int kga = k0 + kg * 16 + kk;
        float v0 = (gn < N && kga < K)     ? B1[(long)kga * ldb + gn] : 0.f;
        float v1 = (gn < N && kga + 1 < K) ? B1[(long)(kga + 1) * ldb + gn] : 0.f;
        pk[kk >> 1] = pack_bf2(v0, v1);
      }
      *reinterpret_cast<uint4*>(&Bs[n][kg * 16])     = make_uint4(pk[0],pk[1],pk[2],pk[3]);
      *reinterpret_cast<uint4*>(&Bs[n][kg * 16 + 8]) = make_uint4(pk[4],pk[5],pk[6],pk[7]);
    }
    __syncthreads();
#pragma unroll
    for (int ks = 0; ks < 2; ++ks) {
      short8 af[2], bfr[2];
#pragma unroll
      for (int mi = 0; mi < 2; ++mi)
        af[mi] = *reinterpret_cast<const short8*>(&As[wm + mi*16 + l15][ks*32 + l4*8]);
#pragma unroll
      for (int ni = 0; ni < 2; ++ni)
        bfr[ni] = *reinterpret_cast<const short8*>(&Bs[wn + ni*16 + l15][ks*32 + l4*8]);
#pragma unroll
      for (int mi = 0; mi < 2; ++mi)
#pragma unroll
        for (int ni = 0; ni < 2; ++ni)
          acc[mi][ni] = __builtin_amdgcn_mfma_f32_16x16x32_bf16(af[mi], bfr[ni], acc[mi][ni], 0, 0, 0);
    }
    __syncthreads();
  }

#pragma unroll
  for (int mi = 0; mi < 2; ++mi) {
#pragma unroll
    for (int ni = 0; ni < 2; ++ni) {
      int col = n0 + wn + ni * 16 + l15;
      int rb  = m0 + wm + mi * 16 + l4 * 4;
#pragma unroll
      for (int r = 0; r < 4; ++r) {
        int row = rb + r;
        if (row < M && col < N) {
          float v = acc[mi][ni][r];
          if (EPI == 1) C[(long)row * ldc + col] = v + bias[col];
          else {
            float t = v + bias[col];
            C[(long)row * ldc + col] = t / (1.f + __expf(-t));
          }
        }
      }
    }
  }
}

// f32-input GEMM with layer batching + split-K, atomicAdd (ada path, M=8)
__global__ __launch_bounds__(256)
void gemm_f32sk(const float* __restrict__ A,
                const float* __restrict__ B, long bz,
                float* __restrict__ C, long cz,
                int M, int N, int K, int lda, int ldb, int ldc, int nks) {
  const int zz = blockIdx.z;
  const int layer = zz / nks;
  const int chunk = zz % nks;
  const int kpb = K / nks;
  const int kbeg = chunk * kpb, kend = kbeg + kpb;
  const float* Bb = B + (long)layer * bz;
  float* Cb = C + (long)layer * cz;

  const int m0 = blockIdx.x * 64;
  const int n0 = blockIdx.y * 64;
  const int tid = threadIdx.x;
  const int lane = tid & 63;
  const int wid = tid >> 6;
  const int wm = (wid >> 1) * 32;
  const int wn = (wid & 1) * 32;
  const int l15 = lane & 15;
  const int l4  = lane >> 4;

  __shared__ __align__(16) ushort_t As[64][72];
  __shared__ __align__(16) ushort_t Bs[64][72];

  f32x4 acc[2][2] = {};

  for (int k0 = kbeg; k0 < kend; k0 += 64) {
#pragma unroll
    for (int pass = 0; pass < 2; ++pass) {
      int c = tid + pass * 256;
      int row = c >> 3;
      int kc = (c & 7) * 8;
      int gr = m0 + row, gk = k0 + kc;
      float v[8];
#pragma unroll
      for (int j = 0; j < 8; ++j)
        v[j] = (gr < M) ? A[(long)gr * lda + gk + j] : 0.f;
      *reinterpret_cast<uint4*>(&As[row][kc]) =
          make_uint4(pack_bf2(v[0],v[1]), pack_bf2(v[2],v[3]),
                     pack_bf2(v[4],v[5]), pack_bf2(v[6],v[7]));
    }
    {
      int n = tid & 63;
      int kg = tid >> 6;
      int gn = n0 + n;
      u32 pk[8];
#pragma unroll
      for (int kk = 0; kk < 16; kk += 2) {
        int kga = k0 + kg * 16 + kk;
        float v0 = Bb[(long)kga * ldb + gn];
        float v1 = Bb[(long)(kga + 1) * ldb + gn];
        pk[kk >> 1] = pack_bf2(v0, v1);
      }
      *reinterpret_cast<uint4*>(&Bs[n][kg * 16])     = make_uint4(pk[0],pk[1],pk[2],pk[3]);
      *reinterpret_cast<uint4*>(&Bs[n][kg * 16 + 8]) = make_uint4(pk[4],pk[5],pk[6],pk[7]);
    }
    __syncthreads();
#pragma unroll
    for (int ks = 0; ks < 2; ++ks) {
      short8 af[2], bfr[2];
#pragma unroll
      for (int mi = 0; mi < 2; ++mi)
        af[mi] = *reinterpret_cast<const short8*>(&As[wm + mi*16 + l15][ks*32 + l4*8]);
#pragma unroll
      for (int ni = 0; ni < 2; ++ni)
        bfr[ni] = *reinterpret_cast<const short8*>(&Bs[wn + ni*16 + l15][ks*32 + l4*8]);
#pragma unroll
      for (int mi = 0; mi < 2; ++mi)
#pragma unroll
        for (int ni = 0; ni < 2; ++ni)
          acc[mi][ni] = __builtin_amdgcn_mfma_f32_16x16x32_bf16(af[mi], bfr[ni], acc[mi][ni], 0, 0, 0);
    }
    __syncthreads();
  }

#pragma unroll
  for (int mi = 0; mi < 2; ++mi) {
#pragma unroll
    for (int ni = 0; ni < 2; ++ni) {
      int col = n0 + wn + ni * 16 + l15;
      int rb  = m0 + wm + mi * 16 + l4 * 4;
#pragma unroll
      for (int r = 0; r < 4; ++r) {
        int row = rb + r;
        if (row < M && col < N)
          atomicAdd(&Cb[(long)row * ldc + col], acc[mi][ni][r]);
      }
    }
  }
}

// ---------------------------------------------------------------------------
extern "C" void kernel_launch(void* const* d_in, const int* in_sizes, int n_in,
                              void* d_out, int out_size, void* d_ws, size_t ws_size,
                              hipStream_t stream) {
  (void)in_sizes; (void)n_in; (void)out_size; (void)ws_size;
  const float* x_t      = (const float*)d_in[1];
  const float* tstep    = (const float*)d_in[2];
  const float* dtp      = (const float*)d_in[3];
  const float* cache_k  = (const float*)d_in[4];
  const float* cache_v  = (const float*)d_in[5];
  const float* w_act_in = (const float*)d_in[6];
  const float* b_act_in = (const float*)d_in[7];
  const float* w_t1     = (const float*)d_in[8];
  const float* b_t1     = (const float*)d_in[9];
  const float* w_t2     = (const float*)d_in[10];
  const float* b_t2     = (const float*)d_in[11];
  const float* ln1_w    = (const float*)d_in[12];
  const float* ada1_w   = (const float*)d_in[13];
  const float* ln2_w    = (const float*)d_in[14];
  const float* wq       = (const float*)d_in[15];
  const float* wk       = (const float*)d_in[16];
  const float* wv       = (const float*)d_in[17];
  const float* wo       = (const float*)d_in[18];
  const float* wg       = (const float*)d_in[19];
  const float* wu       = (const float*)d_in[20];
  const float* wd       = (const float*)d_in[21];
  const float* lnf_w    = (const float*)d_in[22];
  const float* adaf_w   = (const float*)d_in[23];
  const float* wao      = (const float*)d_in[24];
  const float* bao      = (const float*)d_in[25];
  float* outp = (float*)d_out;

  char* p = (char*)d_ws;
  auto alloc = [&](size_t bytes) { char* r = p; p += (bytes + 255) & ~(size_t)255; return r; };

  ushort_t* wqkvT  = (ushort_t*)alloc((size_t)12 * 2560 * 1024 * 2);
  ushort_t* woT    = (ushort_t*)alloc((size_t)12 * 1024 * 2048 * 2);
  ushort_t* wguT   = (ushort_t*)alloc((size_t)12 * 8192 * 1024 * 2);
  ushort_t* wdT    = (ushort_t*)alloc((size_t)12 * 1024 * 4096 * 2);
  ushort_t* kcache = (ushort_t*)alloc((size_t)12 * 8 * NP * 256 * 2);
  ushort_t* vT     = (ushort_t*)alloc((size_t)12 * 8 * 256 * KPAD * 2);
  ushort_t* qT     = (ushort_t*)alloc((size_t)64 * NS * 256 * 2);
  ushort_t* k_new  = (ushort_t*)alloc((size_t)400 * 256 * 2);
  float*    opart  = (float*)alloc((size_t)64 * 7 * NS * 256 * 4);
  float*    mpart  = (float*)alloc((size_t)64 * 7 * NS * 4);
  float*    lpart  = (float*)alloc((size_t)64 * 7 * NS * 4);
  ushort_t* o_buf  = (ushort_t*)alloc((size_t)400 * 2048 * 2);
  ushort_t* t_buf  = (ushort_t*)alloc((size_t)400 * 4096 * 2);
  ushort_t* x_buf  = (ushort_t*)alloc((size_t)400 * 1024 * 2);
  float*    h_buf  = (float*)alloc((size_t)400 * 1024 * 4);
  float*    hf     = (float*)alloc((size_t)400 * 1024 * 4);
  float*    temb   = (float*)alloc(8 * 1024 * 4);
  float*    tmp    = (float*)alloc(8 * 1024 * 4);
  float*    cond   = (float*)alloc(8 * 1024 * 4);
  float*    ada_all= (float*)alloc((size_t)12 * 8 * 1024 * 4);   // zeroed
  float*    adaf_o = (float*)alloc(8 * 1024 * 4);                // zeroed (adjacent)
  float*    cosT   = (float*)alloc(NS * 128 * 4);
  float*    sinT   = (float*)alloc(NS * 128 * 4);
  ushort_t* zpad   = (ushort_t*)alloc(512 * 2);

  hipMemsetAsync(zpad, 0, 512 * 2, stream);
  hipMemsetAsync(ada_all, 0, ((size_t)12 * 8 * 1024 + 8 * 1024) * 4, stream);

  // ---- conversion pass ----
  cvt_permute_kernel<<<9600, 256, 0, stream>>>(cache_k, kcache, (long)12 * 8 * NP);
  transpose_cvt<2><<<dim3(32, 16, 12), 256, 0, stream>>>(wq, (long)1024 * 2048, wqkvT, (long)2560 * 1024, 1024, 2048, 1024, 0);
  transpose_cvt<2><<<dim3(4, 16, 12), 256, 0, stream>>>(wk, (long)1024 * 256, wqkvT + (long)2048 * 1024, (long)2560 * 1024, 1024, 256, 1024, 0);
  transpose_cvt<0><<<dim3(4, 16, 12), 256, 0, stream>>>(wv, (long)1024 * 256, wqkvT + (long)2304 * 1024, (long)2560 * 1024, 1024, 256, 1024, 0);
  transpose_cvt<0><<<dim3(16, 32, 12), 256, 0, stream>>>(wo, (long)2048 * 1024, woT, (long)1024 * 2048, 2048, 1024, 2048, 0);
  transpose_cvt<1><<<dim3(64, 16, 12), 256, 0, stream>>>(wg, (long)1024 * 4096, wguT, (long)8192 * 1024, 1024, 4096, 1024, 0);
  transpose_cvt<1><<<dim3(64, 16, 12), 256, 0, stream>>>(wu, (long)1024 * 4096, wguT, (long)8192 * 1024, 1024, 4096, 1024, 32);
  transpose_cvt<0><<<dim3(16, 64, 12), 256, 0, stream>>>(wd, (long)4096 * 1024, wdT, (long)1024 * 4096, 4096, 1024, 4096, 0);
  transpose_cvt<0><<<dim3(4, 13, 96), 256, 0, stream>>>(cache_v, (long)NP * 256, vT, (long)256 * KPAD, NP, 256, KPAD, 0);

  // ---- embed + cond ----
  temb_kernel<<<32, 256, 0, stream>>>(tstep, temb);
  suffix_kernel<<<400, 256, 0, stream>>>(x_t, w_act_in, b_act_in, h_buf);
  rope_table_kernel<<<25, 256, 0, stream>>>(cosT, sinT);
  gemm_f32_kernel<2><<<dim3(1, 16, 1), 256, 0, stream>>>(temb, w_t1, tmp, NB, ND, ND, ND, ND, ND, b_t1);
  gemm_f32_kernel<1><<<dim3(1, 16, 1), 256, 0, stream>>>(tmp, w_t2, cond, NB, ND, ND, ND, ND, ND, b_t2);
  gemm_f32sk<<<dim3(1, 16, 48), 256, 0, stream>>>(cond, ada1_w, (long)ND * ND, ada_all, (long)NB * ND, NB, ND, ND, ND, ND, ND, 4);
  gemm_f32sk<<<dim3(1, 16, 4), 256, 0, stream>>>(cond, adaf_w, 0, adaf_o, 0, NB, ND, ND, ND, ND, ND, 4);

  for (int l = 0; l < NLAYER; ++l) {
    ushort_t* vT_l = vT + (long)l * 8 * 256 * KPAD;
    rms_kernel<true><<<400, 256, 0, stream>>>(h_buf, ln1_w + (long)l * ND, ada_all + (long)l * NB * ND, x_buf);
    // qkv + fused rope scatter (280 blocks)
    gemm64rope<<<dim3(7, 40, 1), 256, 0, stream>>>(
        x_buf, wqkvT + (long)l * 2560 * 1024, cosT, sinT, qT, k_new, vT_l);
    // flash attention partials (448 blocks)
    flash_kernel<<<dim3(64, 7, 1), 256, 0, stream>>>(
        qT, kcache + (long)l * 8 * NP * 256, k_new, vT_l, zpad, opart, mpart, lpart);
    att_combine<<<400, 256, 0, stream>>>(opart, mpart, lpart, o_buf);
    // h += o @ woT^T  (split-K 4, 448 blocks)
    gemm64acc<<<dim3(7, 16, 4), 256, 0, stream>>>(
        o_buf, woT + (long)l * 1024 * 2048, h_buf, 400, 1024, 2048, 2048, 2048, 1024, 512);
    rms_kernel<true><<<400, 256, 0, stream>>>(h_buf, ln2_w + (long)l * ND, nullptr, x_buf);
    // t = gelu(x@wg)*(x@wu)  fused  (896 blocks)
    gemm64G<<<dim3(7, 128, 1), 256, 0, stream>>>(
        x_buf, wguT + (long)l * 8192 * 1024, t_buf, 400, 1024, 1024, 1024, 4096);
    // h += t @ wdT^T  (split-K 4, 448 blocks)
    gemm64acc<<<dim3(7, 16, 4), 256, 0, stream>>>(
        t_buf, wdT + (long)l * 1024 * 4096, h_buf, 400, 1024, 4096, 4096, 4096, 1024, 1024);
  }

  rms_kernel<false><<<400, 256, 0, stream>>>(h_buf, lnf_w, adaf_o, hf);
  final_kernel<<<400, 256, 0, stream>>>(hf, wao, bao, x_t, dtp, outp);
}

// Round 7
// 1997.504 us; speedup vs baseline: 1.0831x; 1.0223x over previous
//
#include <hip/hip_runtime.h>
#include <hip/hip_bf16.h>
#include <math.h>

#define NLAYER 12
#define NB 8
#define NP 800
#define ND 1024
#define NH 8
#define NDH 256
#define NM 4096
#define NS 50
#define NA 32
#define NKEYS 850
#define KPAD 1024     // padded key count (covers 4 chunks of 256)

typedef unsigned short ushort_t;
typedef unsigned int u32;
using f32x4  = __attribute__((ext_vector_type(4))) float;
using short8 = __attribute__((ext_vector_type(8))) short;

__device__ __forceinline__ u32 pack_bf2(float lo, float hi) {
  u32 a = __float_as_uint(lo);
  u32 b = __float_as_uint(hi);
  a += 0x7fffu + ((a >> 16) & 1u);
  b += 0x7fffu + ((b >> 16) & 1u);
  return (a >> 16) | (b & 0xffff0000u);
}
__device__ __forceinline__ ushort_t bf1(float x) {
  u32 a = __float_as_uint(x);
  a += 0x7fffu + ((a >> 16) & 1u);
  return (ushort_t)(a >> 16);
}
__device__ __forceinline__ float ubf(ushort_t h) {
  return __uint_as_float(((u32)h) << 16);
}
__device__ __forceinline__ void async_cp16(const void* g, const void* l) {
  __builtin_amdgcn_global_load_lds(
      (const __attribute__((address_space(1))) u32*)g,
      (__attribute__((address_space(3))) u32*)l, 16, 0, 0);
}

// ---------------------------------------------------------------------------
// conversion kernels
// ---------------------------------------------------------------------------

// kcache: f32 [rows][256] -> bf16 [rows][256] with d-permute j = 2*(d&127)+(d>>7)
__global__ void cvt_permute_kernel(const float* __restrict__ src, ushort_t* __restrict__ dst, long nrows) {
  long idx = (long)blockIdx.x * 256 + threadIdx.x;
  long row = idx >> 5;
  int t = (int)(idx & 31);
  if (row >= nrows) return;
  const float* s = src + row * 256 + t * 4;
  float4 lo = *reinterpret_cast<const float4*>(s);
  float4 hi = *reinterpret_cast<const float4*>(s + 128);
  ushort_t* d = dst + row * 256 + t * 8;
  *reinterpret_cast<uint4*>(d) =
      make_uint4(pack_bf2(lo.x, hi.x), pack_bf2(lo.y, hi.y),
                 pack_bf2(lo.z, hi.z), pack_bf2(lo.w, hi.w));
}

// tiled transpose + cvt: src f32 [z][R][C] -> dst bf16, dst_row = map(src col)
// MODE 0: row = c
// MODE 1 (g/u interleave): row = (c>>5)*64 + (c&31) + halfOff
// MODE 2 (rope pair-interleave per 256-head): row = (c&~255) + 2*(c&127) + ((c>>7)&1)
template<int MODE>
__global__ __launch_bounds__(256) void transpose_cvt(
    const float* __restrict__ src, long sz, ushort_t* __restrict__ dst, long dz,
    int R, int C, int ldd, int halfOff) {
  __shared__ float Ls[64][65];
  const float* s = src + (long)blockIdx.z * sz;
  ushort_t* d    = dst + (long)blockIdx.z * dz;
  int c0 = blockIdx.x * 64, r0 = blockIdx.y * 64;
  int t = threadIdx.x;
  int rr = t >> 4;
  int cc = (t & 15) * 4;
#pragma unroll
  for (int j = 0; j < 4; ++j) {
    int rl = rr + j * 16;
    int r = r0 + rl;
    float4 v = make_float4(0.f, 0.f, 0.f, 0.f);
    if (r < R) v = *reinterpret_cast<const float4*>(s + (long)r * C + c0 + cc);
    Ls[rl][cc] = v.x; Ls[rl][cc+1] = v.y; Ls[rl][cc+2] = v.z; Ls[rl][cc+3] = v.w;
  }
  __syncthreads();
  int dr = t >> 2;
  int rc = (t & 3) * 16;
  int cg = c0 + dr;
  long orow;
  if (MODE == 0)      orow = cg;
  else if (MODE == 1) orow = ((long)(cg >> 5) << 6) + (cg & 31) + halfOff;
  else                orow = (long)(cg & ~255) + ((cg & 127) << 1) + ((cg >> 7) & 1);
  ushort_t* drow = d + orow * ldd + r0 + rc;
#pragma unroll
  for (int i = 0; i < 16; i += 2) {
    int sr = r0 + rc + i;
    if (sr < R) {
      u32 p = pack_bf2(Ls[rc + i][dr], Ls[rc + i + 1][dr]);
      *reinterpret_cast<u32*>(drow + i) = p;
    }
  }
}

// ---------------------------------------------------------------------------
// small kernels
// ---------------------------------------------------------------------------

__global__ void temb_kernel(const float* __restrict__ ts, float* __restrict__ temb) {
  int idx = blockIdx.x * 256 + threadIdx.x;
  if (idx >= NB * ND) return;
  int b = idx >> 10, d = idx & 1023;
  int i = d & 511;
  float f = __expf(-logf(10000.f) * (float)i / 512.f);
  float ang = ts[b] * f;
  temb[idx] = (d < 512) ? sinf(ang) : cosf(ang);
}

__global__ void suffix_kernel(const float* __restrict__ x_t, const float* __restrict__ w,
                              const float* __restrict__ bias, float* __restrict__ h) {
  int m = blockIdx.x;
  __shared__ float xs[NA];
  if (threadIdx.x < NA) xs[threadIdx.x] = x_t[m * NA + threadIdx.x];
  __syncthreads();
  for (int n = threadIdx.x; n < ND; n += 256) {
    float acc = bias[n];
#pragma unroll
    for (int k = 0; k < NA; ++k) acc += xs[k] * w[k * ND + n];
    h[m * ND + n] = acc * 32.0f;
  }
}

__global__ void rope_table_kernel(float* __restrict__ cosT, float* __restrict__ sinT) {
  int idx = blockIdx.x * 256 + threadIdx.x;
  if (idx >= NS * 128) return;
  int s = idx >> 7, i = idx & 127;
  float inv = __expf(-(float)(2 * i) / 256.f * logf(10000.f));
  float ang = (float)(NP + s) * inv;
  cosT[idx] = cosf(ang);
  sinT[idx] = sinf(ang);
}

template<bool BFOUT>
__global__ void rms_kernel(const float* __restrict__ hin, const float* __restrict__ w,
                           const float* __restrict__ ada, void* __restrict__ outv) {
  int m = blockIdx.x;
  int b = m / NS;
  int d0 = threadIdx.x * 4;
  float4 v = *reinterpret_cast<const float4*>(hin + (long)m * ND + d0);
  float ss = v.x*v.x + v.y*v.y + v.z*v.z + v.w*v.w;
#pragma unroll
  for (int off = 32; off > 0; off >>= 1) ss += __shfl_down(ss, off);
  __shared__ float red[4];
  int lane = threadIdx.x & 63, wid = threadIdx.x >> 6;
  if (lane == 0) red[wid] = ss;
  __syncthreads();
  float tot = red[0] + red[1] + red[2] + red[3];
  float r = rsqrtf(tot * (1.f / ND) + 1e-6f);
  float4 wv = *reinterpret_cast<const float4*>(w + d0);
  float4 o;
  o.x = v.x * r * (1.f + wv.x);
  o.y = v.y * r * (1.f + wv.y);
  o.z = v.z * r * (1.f + wv.z);
  o.w = v.w * r * (1.f + wv.w);
  if (ada) {
    float4 av = *reinterpret_cast<const float4*>(ada + (long)b * ND + d0);
    o.x *= (1.f + av.x); o.y *= (1.f + av.y); o.z *= (1.f + av.z); o.w *= (1.f + av.w);
  }
  if (BFOUT) {
    *reinterpret_cast<uint2*>((ushort_t*)outv + (long)m * ND + d0) =
        make_uint2(pack_bf2(o.x, o.y), pack_bf2(o.z, o.w));
  } else {
    *reinterpret_cast<float4*>((float*)outv + (long)m * ND + d0) = o;
  }
}

// fused final rms + out projection + euler step
__global__ void final_fused(const float* __restrict__ hin, const float* __restrict__ lnf,
                            const float* __restrict__ adaf, const float* __restrict__ w,
                            const float* __restrict__ bias, const float* __restrict__ x_t,
                            const float* __restrict__ dt, float* __restrict__ out) {
  int m = blockIdx.x;
  int b = m / NS;
  int d0 = threadIdx.x * 4;
  __shared__ float hfs[ND];
  __shared__ float red[256];
  float4 v = *reinterpret_cast<const float4*>(hin + (long)m * ND + d0);
  float ss = v.x*v.x + v.y*v.y + v.z*v.z + v.w*v.w;
#pragma unroll
  for (int off = 32; off > 0; off >>= 1) ss += __shfl_down(ss, off);
  __shared__ float red4[4];
  int lane = threadIdx.x & 63, wid = threadIdx.x >> 6;
  if (lane == 0) red4[wid] = ss;
  __syncthreads();
  float tot = red4[0] + red4[1] + red4[2] + red4[3];
  float r = rsqrtf(tot * (1.f / ND) + 1e-6f);
  float4 wv = *reinterpret_cast<const float4*>(lnf + d0);
  float4 av = *reinterpret_cast<const float4*>(adaf + (long)b * ND + d0);
  hfs[d0]     = v.x * r * (1.f + wv.x) * (1.f + av.x);
  hfs[d0 + 1] = v.y * r * (1.f + wv.y) * (1.f + av.y);
  hfs[d0 + 2] = v.z * r * (1.f + wv.z) * (1.f + av.z);
  hfs[d0 + 3] = v.w * r * (1.f + wv.w) * (1.f + av.w);
  __syncthreads();
  int a = threadIdx.x & 31;
  int kg = threadIdx.x >> 5;
  float acc = 0.f;
  for (int k = kg; k < ND; k += 8) acc += hfs[k] * w[k * NA + a];
  red[threadIdx.x] = acc;
  __syncthreads();
  if (threadIdx.x < NA) {
    float s = 0.f;
#pragma unroll
    for (int g = 0; g < 8; ++g) s += red[g * 32 + a];
    out[m * NA + a] = x_t[m * NA + a] + dt[0] * (s + bias[a]);
  }
}

// ---------------------------------------------------------------------------
// generic 64x64 GEMM (2-phase dbuf), f32 atomicAdd epilogue (wo / wd path)
// ---------------------------------------------------------------------------
__global__ __launch_bounds__(256) void gemm64acc(
    const ushort_t* __restrict__ A,
    const ushort_t* __restrict__ B,
    float* __restrict__ C,
    int M, int N, int K, int lda, int ldb, int ldc, int kpb) {
  const int kbeg = blockIdx.z * kpb;
  const int kend = kbeg + kpb;

  const int m0 = blockIdx.x * 64;
  const int n0 = blockIdx.y * 64;
  const int tid = threadIdx.x;
  const int lane = tid & 63;
  const int wbase = tid & 192;
  const int wid = wbase >> 6;
  const int wm = (wid >> 1) * 32;
  const int wn = (wid & 1) * 32;
  const int l15 = lane & 15;
  const int l4  = lane >> 4;

  __shared__ ushort_t As[2][64 * 64];
  __shared__ ushort_t Bs[2][64 * 64];

  f32x4 acc[2][2] = {};

  const int ci0 = wbase + lane;
  const int row0 = ci0 >> 3;
  const int kc0 = (ci0 & 7) << 3;
  const int ci1 = 256 + ci0;
  const int row1 = ci1 >> 3;
  const int kc1 = (ci1 & 7) << 3;
  int gra0 = m0 + row0; if (gra0 > M - 1) gra0 = M - 1;
  int gra1 = m0 + row1; if (gra1 > M - 1) gra1 = M - 1;
  const int n_0 = n0 + row0;
  const int n_1 = n0 + row1;

  auto stage = [&](int buf, int k0) {
    async_cp16(A + (long)gra0 * lda + k0 + kc0, (const char*)As[buf] + ci0 * 16);
    async_cp16(B + (long)n_0 * ldb + k0 + kc0, (const char*)Bs[buf] + ci0 * 16);
    async_cp16(A + (long)gra1 * lda + k0 + kc1, (const char*)As[buf] + ci1 * 16);
    async_cp16(B + (long)n_1 * ldb + k0 + kc1, (const char*)Bs[buf] + ci1 * 16);
  };

  const int nt = (kend - kbeg) >> 6;
  stage(0, kbeg);
  __syncthreads();
  int cur = 0;
  for (int t = 0; t < nt; ++t) {
    if (t + 1 < nt) stage(cur ^ 1, kbeg + (t + 1) * 64);
    const ushort_t* Ac = As[cur];
    const ushort_t* Bc = Bs[cur];
#pragma unroll
    for (int ks = 0; ks < 2; ++ks) {
      short8 af[2], bf[2];
#pragma unroll
      for (int mi = 0; mi < 2; ++mi)
        af[mi] = *reinterpret_cast<const short8*>(&Ac[(wm + mi * 16 + l15) * 64 + ks * 32 + l4 * 8]);
#pragma unroll
      for (int ni = 0; ni < 2; ++ni)
        bf[ni] = *reinterpret_cast<const short8*>(&Bc[(wn + ni * 16 + l15) * 64 + ks * 32 + l4 * 8]);
#pragma unroll
      for (int mi = 0; mi < 2; ++mi)
#pragma unroll
        for (int ni = 0; ni < 2; ++ni)
          acc[mi][ni] = __builtin_amdgcn_mfma_f32_16x16x32_bf16(af[mi], bf[ni], acc[mi][ni], 0, 0, 0);
    }
    __syncthreads();
    cur ^= 1;
  }

#pragma unroll
  for (int mi = 0; mi < 2; ++mi) {
#pragma unroll
    for (int ni = 0; ni < 2; ++ni) {
      int col = n0 + wn + ni * 16 + l15;
      int rb  = m0 + wm + mi * 16 + l4 * 4;
      if (col >= N) continue;
#pragma unroll
      for (int r = 0; r < 4; ++r) {
        int row = rb + r;
        if (row >= M) continue;
        atomicAdd(&C[(long)row * ldc + col], acc[mi][ni][r]);
      }
    }
  }
}

// ---------------------------------------------------------------------------
// qkv GEMM with fused RoPE epilogue. A = x_buf [400][1024], B = wqkvT
// (rows pair-interleaved j-space for q/k sections; v natural).
// cols [0,2048)=q -> qT[bh][50][256]; [2048,2304)=k -> k_new; [2304,2560)=v -> vT scatter
// ---------------------------------------------------------------------------
__global__ __launch_bounds__(256) void gemm64rope(
    const ushort_t* __restrict__ A,
    const ushort_t* __restrict__ B,
    const float* __restrict__ cosT, const float* __restrict__ sinT,
    ushort_t* __restrict__ qTo, ushort_t* __restrict__ k_new,
    ushort_t* __restrict__ vT_l) {
  const int M = 400, lda = 1024, ldb = 1024;
  const int m0 = blockIdx.x * 64;
  const int n0 = blockIdx.y * 64;
  const int tid = threadIdx.x;
  const int lane = tid & 63;
  const int wbase = tid & 192;
  const int wid = wbase >> 6;
  const int wm = (wid >> 1) * 32;
  const int wn = (wid & 1) * 32;
  const int l15 = lane & 15;
  const int l4  = lane >> 4;

  __shared__ ushort_t As[2][64 * 64];
  __shared__ ushort_t Bs[2][64 * 64];

  f32x4 acc[2][2] = {};

  const int ci0 = wbase + lane;
  const int row0 = ci0 >> 3;
  const int kc0 = (ci0 & 7) << 3;
  const int ci1 = 256 + ci0;
  const int row1 = ci1 >> 3;
  const int kc1 = (ci1 & 7) << 3;
  int gra0 = m0 + row0; if (gra0 > M - 1) gra0 = M - 1;
  int gra1 = m0 + row1; if (gra1 > M - 1) gra1 = M - 1;
  const int n_0 = n0 + row0;
  const int n_1 = n0 + row1;

  auto stage = [&](int buf, int k0) {
    async_cp16(A + (long)gra0 * lda + k0 + kc0, (const char*)As[buf] + ci0 * 16);
    async_cp16(B + (long)n_0 * ldb + k0 + kc0, (const char*)Bs[buf] + ci0 * 16);
    async_cp16(A + (long)gra1 * lda + k0 + kc1, (const char*)As[buf] + ci1 * 16);
    async_cp16(B + (long)n_1 * ldb + k0 + kc1, (const char*)Bs[buf] + ci1 * 16);
  };

  stage(0, 0);
  __syncthreads();
  int cur = 0;
  for (int t = 0; t < 16; ++t) {
    if (t + 1 < 16) stage(cur ^ 1, (t + 1) * 64);
    const ushort_t* Ac = As[cur];
    const ushort_t* Bc = Bs[cur];
#pragma unroll
    for (int ks = 0; ks < 2; ++ks) {
      short8 af[2], bf[2];
#pragma unroll
      for (int mi = 0; mi < 2; ++mi)
        af[mi] = *reinterpret_cast<const short8*>(&Ac[(wm + mi * 16 + l15) * 64 + ks * 32 + l4 * 8]);
#pragma unroll
      for (int ni = 0; ni < 2; ++ni)
        bf[ni] = *reinterpret_cast<const short8*>(&Bc[(wn + ni * 16 + l15) * 64 + ks * 32 + l4 * 8]);
#pragma unroll
      for (int mi = 0; mi < 2; ++mi)
#pragma unroll
        for (int ni = 0; ni < 2; ++ni)
          acc[mi][ni] = __builtin_amdgcn_mfma_f32_16x16x32_bf16(af[mi], bf[ni], acc[mi][ni], 0, 0, 0);
    }
    __syncthreads();
    cur ^= 1;
  }

#pragma unroll
  for (int mi = 0; mi < 2; ++mi) {
#pragma unroll
    for (int ni = 0; ni < 2; ++ni) {
      int col = n0 + wn + ni * 16 + l15;
      int rb  = m0 + wm + mi * 16 + l4 * 4;
      float pv[4];
#pragma unroll
      for (int r = 0; r < 4; ++r) pv[r] = __shfl_xor(acc[mi][ni][r], 1);
#pragma unroll
      for (int r = 0; r < 4; ++r) {
        int row = rb + r;
        if (row >= 400) continue;
        int b = row / NS, s = row - b * NS;
        float v = acc[mi][ni][r];
        if (col < 2304) {
          int j = col & 255;
          int i = j >> 1;
          float c = cosT[s * 128 + i], sn = sinT[s * 128 + i];
          float o = (col & 1) ? (v * c + pv[r] * sn) : (v * c - pv[r] * sn);
          if (col < 2048)
            qTo[((long)((b << 3) + (col >> 8)) * NS + s) * 256 + j] = bf1(o);
          else
            k_new[(long)row * 256 + j] = bf1(o);
        } else {
          vT_l[((long)(b * 256 + (col - 2304))) * KPAD + NP + s] = bf1(v);
        }
      }
    }
  }
}

// ---------------------------------------------------------------------------
// flash2: grid (64 bh, 4 chunks of 256 keys), 256 threads, dbuf K/V staging.
// Q frags loaded straight from L2 to registers. Writes opart f32
// [bh][4][50][256] + m,l [bh][4][50].
// ---------------------------------------------------------------------------
__global__ __launch_bounds__(256) void flash2_kernel(
    const ushort_t* __restrict__ qT,
    const ushort_t* __restrict__ kcache_l,
    const ushort_t* __restrict__ k_new,
    const ushort_t* __restrict__ vT_l,
    const ushort_t* __restrict__ zpad,
    float* __restrict__ opart, float* __restrict__ mpart, float* __restrict__ lpart) {
  const int bh = blockIdx.x;
  const int ch = blockIdx.y;
  const int b  = bh >> 3;
  const int tid = threadIdx.x;
  const int lane = tid & 63;
  const int w = tid >> 6;
  const int wm = (w >> 1) * 32;     // q-row base of this wave
  const int wn = (w & 1) * 128;     // key / dout base of this wave
  const int l15 = lane & 15;
  const int l4  = lane >> 4;

  __shared__ __align__(16) char lds[100352];
  ushort_t* KV0 = (ushort_t*)lds;                   // 32KB
  ushort_t* KV1 = (ushort_t*)(lds + 32768);         // 32KB
  ushort_t* Ps  = (ushort_t*)(lds + 65536);         // [64][264] 33792B
  float* SMm = (float*)(lds + 99328);               // [2][64]
  float* SMl = (float*)(lds + 99840);               // [2][64]

  // ---- Q fragments straight to registers (rows wm..wm+31, dup rows >= 50) ----
  short8 qf[4][2][2];
  {
    const ushort_t* qbase = qT + (long)bh * NS * 256;
#pragma unroll
    for (int mi = 0; mi < 2; ++mi) {
      int row = wm + mi * 16 + l15;
      int qr = row < NS ? row : NS - 1;
      const ushort_t* qrow = qbase + (long)qr * 256;
#pragma unroll
      for (int s = 0; s < 4; ++s)
#pragma unroll
        for (int ks = 0; ks < 2; ++ks)
          qf[s][mi][ks] = *reinterpret_cast<const short8*>(qrow + s * 64 + ks * 32 + l4 * 8);
    }
  }

  // K slice stage: [256 keys][64 d] for d-slice s
  auto stageK = [&](ushort_t* buf, int s) {
#pragma unroll
    for (int i = 0; i < 8; ++i) {
      int ci = i * 256 + tid;
      int key = ch * 256 + (ci >> 3);
      int seg = ci & 7;
      const ushort_t* src;
      if (key < NP)         src = kcache_l + ((long)(b * NP + key)) * 256 + s * 64 + seg * 8;
      else if (key < NKEYS) src = k_new + ((long)(b * NS + key - NP)) * 256 + s * 64 + seg * 8;
      else                  src = zpad + seg * 8;
      async_cp16(src, (char*)buf + ci * 16);
    }
  };
  // V slice stage: [256 dout][64 keys] for key-slice s
  auto stageV = [&](ushort_t* buf, int s) {
#pragma unroll
    for (int i = 0; i < 8; ++i) {
      int ci = i * 256 + tid;
      int dout = ci >> 3;
      int seg = ci & 7;
      async_cp16(vT_l + ((long)(b * 256 + dout)) * KPAD + ch * 256 + s * 64 + seg * 8,
                 (char*)buf + ci * 16);
    }
  };

  // ---- QK^T: S[64 rows][256 keys], d-loop 4 slices, double-buffered ----
  f32x4 s2[2][8] = {};
  stageK(KV0, 0);
  __syncthreads();
#pragma unroll
  for (int s = 0; s < 4; ++s) {
    ushort_t* buf = (s & 1) ? KV1 : KV0;
    ushort_t* nxt = (s & 1) ? KV0 : KV1;
    if (s < 3) stageK(nxt, s + 1);
    __builtin_amdgcn_s_setprio(1);
#pragma unroll
    for (int ks = 0; ks < 2; ++ks) {
      short8 bf[8];
#pragma unroll
      for (int ni = 0; ni < 8; ++ni)
        bf[ni] = *reinterpret_cast<const short8*>(&buf[(wn + ni * 16 + l15) * 64 + ks * 32 + l4 * 8]);
#pragma unroll
      for (int mi = 0; mi < 2; ++mi)
#pragma unroll
        for (int ni = 0; ni < 8; ++ni)
          s2[mi][ni] = __builtin_amdgcn_mfma_f32_16x16x32_bf16(qf[s][mi][ks], bf[ni], s2[mi][ni], 0, 0, 0);
    }
    __builtin_amdgcn_s_setprio(0);
    __syncthreads();
  }

  // V slice 0 loads fly under the softmax
  stageV(KV0, 0);

  // ---- softmax: scale, mask, row max / sum across the 256 keys ----
  float mx[2][4];
#pragma unroll
  for (int mi = 0; mi < 2; ++mi)
#pragma unroll
    for (int r = 0; r < 4; ++r) mx[mi][r] = -1e30f;
#pragma unroll
  for (int mi = 0; mi < 2; ++mi)
#pragma unroll
    for (int ni = 0; ni < 8; ++ni) {
      int key = ch * 256 + wn + ni * 16 + l15;
      bool valid = key < NKEYS;
#pragma unroll
      for (int r = 0; r < 4; ++r) {
        float v = s2[mi][ni][r] * 0.0625f;
        v = valid ? v : -1e30f;
        s2[mi][ni][r] = v;
        mx[mi][r] = fmaxf(mx[mi][r], v);
      }
    }
#pragma unroll
  for (int off = 1; off < 16; off <<= 1)
#pragma unroll
    for (int mi = 0; mi < 2; ++mi)
#pragma unroll
      for (int r = 0; r < 4; ++r)
        mx[mi][r] = fmaxf(mx[mi][r], __shfl_xor(mx[mi][r], off));
  if (l15 == 0) {
#pragma unroll
    for (int mi = 0; mi < 2; ++mi)
#pragma unroll
      for (int r = 0; r < 4; ++r)
        SMm[(w & 1) * 64 + wm + mi * 16 + l4 * 4 + r] = mx[mi][r];
  }
  __syncthreads();
  float mrow[2][4], sum[2][4];
#pragma unroll
  for (int mi = 0; mi < 2; ++mi)
#pragma unroll
    for (int r = 0; r < 4; ++r) {
      int row = wm + mi * 16 + l4 * 4 + r;
      mrow[mi][r] = fmaxf(SMm[row], SMm[64 + row]);
      sum[mi][r] = 0.f;
    }
#pragma unroll
  for (int mi = 0; mi < 2; ++mi)
#pragma unroll
    for (int ni = 0; ni < 8; ++ni) {
      int colp = wn + ni * 16 + l15;
#pragma unroll
      for (int r = 0; r < 4; ++r) {
        float e = __expf(s2[mi][ni][r] - mrow[mi][r]);
        Ps[(wm + mi * 16 + l4 * 4 + r) * 264 + colp] = bf1(e);
        sum[mi][r] += e;
      }
    }
#pragma unroll
  for (int off = 1; off < 16; off <<= 1)
#pragma unroll
    for (int mi = 0; mi < 2; ++mi)
#pragma unroll
      for (int r = 0; r < 4; ++r)
        sum[mi][r] += __shfl_xor(sum[mi][r], off);
  if (l15 == 0) {
#pragma unroll
    for (int mi = 0; mi < 2; ++mi)
#pragma unroll
      for (int r = 0; r < 4; ++r)
        SMl[(w & 1) * 64 + wm + mi * 16 + l4 * 4 + r] = sum[mi][r];
  }
  __syncthreads();
  if ((w & 1) == 0 && l15 == 0) {
#pragma unroll
    for (int mi = 0; mi < 2; ++mi)
#pragma unroll
      for (int r = 0; r < 4; ++r) {
        int row = wm + mi * 16 + l4 * 4 + r;
        if (row < NS) {
          mpart[((long)bh * 4 + ch) * NS + row] = mrow[mi][r];
          lpart[((long)bh * 4 + ch) * NS + row] = SMl[row] + SMl[64 + row];
        }
      }
  }

  // ---- PV: O[64][256] = P[64][256] @ V[256][256], key-loop dbuf ----
  f32x4 o2[2][8] = {};
#pragma unroll
  for (int s = 0; s < 4; ++s) {
    ushort_t* buf = (s & 1) ? KV1 : KV0;
    ushort_t* nxt = (s & 1) ? KV0 : KV1;
    if (s < 3) stageV(nxt, s + 1);
    __builtin_amdgcn_s_setprio(1);
#pragma unroll
    for (int ks = 0; ks < 2; ++ks) {
      short8 af[2], bf[8];
#pragma unroll
      for (int mi = 0; mi < 2; ++mi)
        af[mi] = *reinterpret_cast<const short8*>(&Ps[(wm + mi * 16 + l15) * 264 + s * 64 + ks * 32 + l4 * 8]);
#pragma unroll
      for (int ni = 0; ni < 8; ++ni)
        bf[ni] = *reinterpret_cast<const short8*>(&buf[(wn + ni * 16 + l15) * 64 + ks * 32 + l4 * 8]);
#pragma unroll
      for (int mi = 0; mi < 2; ++mi)
#pragma unroll
        for (int ni = 0; ni < 8; ++ni)
          o2[mi][ni] = __builtin_amdgcn_mfma_f32_16x16x32_bf16(af[mi], bf[ni], o2[mi][ni], 0, 0, 0);
    }
    __builtin_amdgcn_s_setprio(0);
    __syncthreads();
  }

#pragma unroll
  for (int mi = 0; mi < 2; ++mi)
#pragma unroll
    for (int ni = 0; ni < 8; ++ni) {
      int col = wn + ni * 16 + l15;
#pragma unroll
      for (int r = 0; r < 4; ++r) {
        int row = wm + mi * 16 + l4 * 4 + r;
        if (row < NS)
          opart[(((long)bh * 4 + ch) * NS + row) * 256 + col] = o2[mi][ni][r];
      }
    }
}

// combine 4 chunk partials -> o_buf bf16 [400][2048]
__global__ void att_combine(const float* __restrict__ opart, const float* __restrict__ mpart,
                            const float* __restrict__ lpart, ushort_t* __restrict__ o_buf) {
  int blk = blockIdx.x;           // b*50+s
  int b = blk / NS, s = blk - b * NS;
  int d = threadIdx.x;            // 0..255
  for (int h = 0; h < NH; ++h) {
    int bh = b * NH + h;
    float mv[4];
    float m = -1e30f;
#pragma unroll
    for (int c = 0; c < 4; ++c) {
      mv[c] = mpart[((long)bh * 4 + c) * NS + s];
      m = fmaxf(m, mv[c]);
    }
    float den = 0.f, o = 0.f;
#pragma unroll
    for (int c = 0; c < 4; ++c) {
      float wgt = __expf(mv[c] - m);
      den += wgt * lpart[((long)bh * 4 + c) * NS + s];
      o   += wgt * opart[(((long)bh * 4 + c) * NS + s) * 256 + d];
    }
    o_buf[(long)blk * 2048 + h * 256 + d] = bf1(o / den);
  }
}

// ---------------------------------------------------------------------------
// gated GEMM (2-phase): B = wguT interleaved [8192][1024]
// 4 waves as 4x1 (wave tile 16m x 64n). out = gelu(g)*u, bf16 [M][4096].
// ---------------------------------------------------------------------------
__global__ __launch_bounds__(256) void gemm64G(
    const ushort_t* __restrict__ A, const ushort_t* __restrict__ B,
    ushort_t* __restrict__ C, int M, int K, int lda, int ldb, int ldc) {
  const int m0 = blockIdx.x * 64;
  const int n0 = blockIdx.y * 64;
  const int tid = threadIdx.x;
  const int lane = tid & 63;
  const int wbase = tid & 192;
  const int wid = wbase >> 6;
  const int l15 = lane & 15;
  const int l4  = lane >> 4;

  __shared__ ushort_t As[2][64 * 64];
  __shared__ ushort_t Bs[2][64 * 64];

  f32x4 acc[4] = {};

  const int ci0 = wbase + lane;
  const int row0 = ci0 >> 3;
  const int kc0 = (ci0 & 7) << 3;
  const int ci1 = 256 + ci0;
  const int row1 = ci1 >> 3;
  const int kc1 = (ci1 & 7) << 3;
  int gra0 = m0 + row0; if (gra0 > M - 1) gra0 = M - 1;
  int gra1 = m0 + row1; if (gra1 > M - 1) gra1 = M - 1;

  auto stage = [&](int buf, int k0) {
    async_cp16(A + (long)gra0 * lda + k0 + kc0, (const char*)As[buf] + ci0 * 16);
    async_cp16(B + (long)(n0 + row0) * ldb + k0 + kc0, (const char*)Bs[buf] + ci0 * 16);
    async_cp16(A + (long)gra1 * lda + k0 + kc1, (const char*)As[buf] + ci1 * 16);
    async_cp16(B + (long)(n0 + row1) * ldb + k0 + kc1, (const char*)Bs[buf] + ci1 * 16);
  };

  const int nt = K >> 6;
  stage(0, 0);
  __syncthreads();
  int cur = 0;
  for (int t = 0; t < nt; ++t) {
    if (t + 1 < nt) stage(cur ^ 1, (t + 1) * 64);
    const ushort_t* Ac = As[cur];
    const ushort_t* Bc = Bs[cur];
#pragma unroll
    for (int ks = 0; ks < 2; ++ks) {
      short8 af = *reinterpret_cast<const short8*>(&Ac[(wid * 16 + l15) * 64 + ks * 32 + l4 * 8]);
#pragma unroll
      for (int ni = 0; ni < 4; ++ni) {
        short8 bf = *reinterpret_cast<const short8*>(&Bc[(ni * 16 + l15) * 64 + ks * 32 + l4 * 8]);
        acc[ni] = __builtin_amdgcn_mfma_f32_16x16x32_bf16(af, bf, acc[ni], 0, 0, 0);
      }
    }
    __syncthreads();
    cur ^= 1;
  }

#pragma unroll
  for (int ni = 0; ni < 2; ++ni) {
    int col = (n0 >> 1) + ni * 16 + l15;
    int rb  = m0 + wid * 16 + l4 * 4;
#pragma unroll
    for (int r = 0; r < 4; ++r) {
      int row = rb + r;
      if (row >= M) continue;
      float g = acc[ni][r];
      float u = acc[ni + 2][r];
      float inner = 0.7978845608028654f * (g + 0.044715f * g * g * g);
      float t = 0.5f * g * (1.f + tanhf(inner));
      C[(long)row * ldc + col] = bf1(t * u);
    }
  }
}

// ---------------------------------------------------------------------------
// f32-input GEMM (cond path, M=8). EPI: 1=+bias 2=silu(acc+bias)
// ---------------------------------------------------------------------------
template<int EPI>
__global__ __launch_bounds__(256)
void gemm_f32_kernel(const float* __restrict__ A,
                     const float* __restrict__ B1,
                     float* __restrict__ C,
                     int M, int N, int K, int lda, int ldb, int ldc,
                     const float* __restrict__ bias) {
  const int m0 = blockIdx.x * 64;
  const int n0 = blockIdx.y * 64;
  const int tid = threadIdx.x;
  const int lane = tid & 63;
  const int wid = tid >> 6;
  const int wm = (wid >> 1) * 32;
  const int wn = (wid & 1) * 32;
  const int l15 = lane & 15;
  const int l4  = lane >> 4;

  __shared__ __align__(16) ushort_t As[64][72];
  __shared__ __align__(16) ushort_t Bs[64][72];

  f32x4 acc[2][2] = {};

  for (int k0 = 0; k0 < K; k0 += 64) {
#pragma unroll
    for (int pass = 0; pass < 2; ++pass) {
      int c = tid + pass * 256;
      int row = c >> 3;
      int kc = (c & 7) * 8;
      int gr = m0 + row, gk = k0 + kc;
      float v[8];
#pragma unroll
      for (int j = 0; j < 8; ++j)
        v[j] = (gr < M && gk + j < K) ? A[(long)gr * lda + gk + j] : 0.f;
      *reinterpret_cast<uint4*>(&As[row][kc]) =
          make_uint4(pack_bf2(v[0],v[1]), pack_bf2(v[2],v[3]),
                     pack_bf2(v[4],v[5]), pack_bf2(v[6],v[7]));
    }
    {
      int n = tid & 63;
      int kg = tid >> 6;
      int gn = n0 + n;
      u32 pk[8];
#pragma unroll
      for (int kk = 0; kk < 16; kk += 2) {
        int kga = k0 + kg * 16 + kk;
        float v0 = (gn < N && kga < K)     ? B1[(long)kga * ldb + gn] : 0.f;
        float v1 = (gn < N && kga + 1 < K) ? B1[(long)(kga + 1) * ldb + gn] : 0.f;
        pk[kk >> 1] = pack_bf2(v0, v1);
      }
      *reinterpret_cast<uint4*>(&Bs[n][kg * 16])     = make_uint4(pk[0],pk[1],pk[2],pk[3]);
      *reinterpret_cast<uint4*>(&Bs[n][kg * 16 + 8]) = make_uint4(pk[4],pk[5],pk[6],pk[7]);
    }
    __syncthreads();
#pragma unroll
    for (int ks = 0; ks < 2; ++ks) {
      short8 af[2], bfr[2];
#pragma unroll
      for (int mi = 0; mi < 2; ++mi)
        af[mi] = *reinterpret_cast<const short8*>(&As[wm + mi*16 + l15][ks*32 + l4*8]);
#pragma unroll
      for (int ni = 0; ni < 2; ++ni)
        bfr[ni] = *reinterpret_cast<const short8*>(&Bs[wn + ni*16 + l15][ks*32 + l4*8]);
#pragma unroll
      for (int mi = 0; mi < 2; ++mi)
#pragma unroll
        for (int ni = 0; ni < 2; ++ni)
          acc[mi][ni] = __builtin_amdgcn_mfma_f32_16x16x32_bf16(af[mi], bfr[ni], acc[mi][ni], 0, 0, 0);
    }
    __syncthreads();
  }

#pragma unroll
  for (int mi = 0; mi < 2; ++mi) {
#pragma unroll
    for (int ni = 0; ni < 2; ++ni) {
      int col = n0 + wn + ni * 16 + l15;
      int rb  = m0 + wm + mi * 16 + l4 * 4;
#pragma unroll
      for (int r = 0; r < 4; ++r) {
        int row = rb + r;
        if (row < M && col < N) {
          float v = acc[mi][ni][r];
          if (EPI == 1) C[(long)row * ldc + col] = v + bias[col];
          else {
            float t = v + bias[col];
            C[(long)row * ldc + col] = t / (1.f + __expf(-t));
          }
        }
      }
    }
  }
}

// f32-input GEMM with layer batching + split-K, atomicAdd (ada path, M=8)
__global__ __launch_bounds__(256)
void gemm_f32sk(const float* __restrict__ A,
                const float* __restrict__ B, long bz,
                float* __restrict__ C, long cz,
                int M, int N, int K, int lda, int ldb, int ldc, int nks) {
  const int zz = blockIdx.z;
  const int layer = zz / nks;
  const int chunk = zz % nks;
  const int kpb = K / nks;
  const int kbeg = chunk * kpb, kend = kbeg + kpb;
  const float* Bb = B + (long)layer * bz;
  float* Cb = C + (long)layer * cz;

  const int m0 = blockIdx.x * 64;
  const int n0 = blockIdx.y * 64;
  const int tid = threadIdx.x;
  const int lane = tid & 63;
  const int wid = tid >> 6;
  const int wm = (wid >> 1) * 32;
  const int wn = (wid & 1) * 32;
  const int l15 = lane & 15;
  const int l4  = lane >> 4;

  __shared__ __align__(16) ushort_t As[64][72];
  __shared__ __align__(16) ushort_t Bs[64][72];

  f32x4 acc[2][2] = {};

  for (int k0 = kbeg; k0 < kend; k0 += 64) {
#pragma unroll
    for (int pass = 0; pass < 2; ++pass) {
      int c = tid + pass * 256;
      int row = c >> 3;
      int kc = (c & 7) * 8;
      int gr = m0 + row, gk = k0 + kc;
      float v[8];
#pragma unroll
      for (int j = 0; j < 8; ++j)
        v[j] = (gr < M) ? A[(long)gr * lda + gk + j] : 0.f;
      *reinterpret_cast<uint4*>(&As[row][kc]) =
          make_uint4(pack_bf2(v[0],v[1]), pack_bf2(v[2],v[3]),
                     pack_bf2(v[4],v[5]), pack_bf2(v[6],v[7]));
    }
    {
      int n = tid & 63;
      int kg = tid >> 6;
      int gn = n0 + n;
      u32 pk[8];
#pragma unroll
      for (int kk = 0; kk < 16; kk += 2) {
        int kga = k0 + kg * 16 + kk;
        float v0 = Bb[(long)kga * ldb + gn];
        float v1 = Bb[(long)(kga + 1) * ldb + gn];
        pk[kk >> 1] = pack_bf2(v0, v1);
      }
      *reinterpret_cast<uint4*>(&Bs[n][kg * 16])     = make_uint4(pk[0],pk[1],pk[2],pk[3]);
      *reinterpret_cast<uint4*>(&Bs[n][kg * 16 + 8]) = make_uint4(pk[4],pk[5],pk[6],pk[7]);
    }
    __syncthreads();
#pragma unroll
    for (int ks = 0; ks < 2; ++ks) {
      short8 af[2], bfr[2];
#pragma unroll
      for (int mi = 0; mi < 2; ++mi)
        af[mi] = *reinterpret_cast<const short8*>(&As[wm + mi*16 + l15][ks*32 + l4*8]);
#pragma unroll
      for (int ni = 0; ni < 2; ++ni)
        bfr[ni] = *reinterpret_cast<const short8*>(&Bs[wn + ni*16 + l15][ks*32 + l4*8]);
#pragma unroll
      for (int mi = 0; mi < 2; ++mi)
#pragma unroll
        for (int ni = 0; ni < 2; ++ni)
          acc[mi][ni] = __builtin_amdgcn_mfma_f32_16x16x32_bf16(af[mi], bfr[ni], acc[mi][ni], 0, 0, 0);
    }
    __syncthreads();
  }

#pragma unroll
  for (int mi = 0; mi < 2; ++mi) {
#pragma unroll
    for (int ni = 0; ni < 2; ++ni) {
      int col = n0 + wn + ni * 16 + l15;
      int rb  = m0 + wm + mi * 16 + l4 * 4;
#pragma unroll
      for (int r = 0; r < 4; ++r) {
        int row = rb + r;
        if (row < M && col < N)
          atomicAdd(&Cb[(long)row * ldc + col], acc[mi][ni][r]);
      }
    }
  }
}

// ---------------------------------------------------------------------------
extern "C" void kernel_launch(void* const* d_in, const int* in_sizes, int n_in,
                              void* d_out, int out_size, void* d_ws, size_t ws_size,
                              hipStream_t stream) {
  (void)in_sizes; (void)n_in; (void)out_size; (void)ws_size;
  const float* x_t      = (const float*)d_in[1];
  const float* tstep    = (const float*)d_in[2];
  const float* dtp      = (const float*)d_in[3];
  const float* cache_k  = (const float*)d_in[4];
  const float* cache_v  = (const float*)d_in[5];
  const float* w_act_in = (const float*)d_in[6];
  const float* b_act_in = (const float*)d_in[7];
  const float* w_t1     = (const float*)d_in[8];
  const float* b_t1     = (const float*)d_in[9];
  const float* w_t2     = (const float*)d_in[10];
  const float* b_t2     = (const float*)d_in[11];
  const float* ln1_w    = (const float*)d_in[12];
  const float* ada1_w   = (const float*)d_in[13];
  const float* ln2_w    = (const float*)d_in[14];
  const float* wq       = (const float*)d_in[15];
  const float* wk       = (const float*)d_in[16];
  const float* wv       = (const float*)d_in[17];
  const float* wo       = (const float*)d_in[18];
  const float* wg       = (const float*)d_in[19];
  const float* wu       = (const float*)d_in[20];
  const float* wd       = (const float*)d_in[21];
  const float* lnf_w    = (const float*)d_in[22];
  const float* adaf_w   = (const float*)d_in[23];
  const float* wao      = (const float*)d_in[24];
  const float* bao      = (const float*)d_in[25];
  float* outp = (float*)d_out;

  char* p = (char*)d_ws;
  auto alloc = [&](size_t bytes) { char* r = p; p += (bytes + 255) & ~(size_t)255; return r; };

  ushort_t* wqkvT  = (ushort_t*)alloc((size_t)12 * 2560 * 1024 * 2);
  ushort_t* woT    = (ushort_t*)alloc((size_t)12 * 1024 * 2048 * 2);
  ushort_t* wguT   = (ushort_t*)alloc((size_t)12 * 8192 * 1024 * 2);
  ushort_t* wdT    = (ushort_t*)alloc((size_t)12 * 1024 * 4096 * 2);
  ushort_t* kcache = (ushort_t*)alloc((size_t)12 * 8 * NP * 256 * 2);
  ushort_t* vT     = (ushort_t*)alloc((size_t)12 * 8 * 256 * KPAD * 2);
  ushort_t* qT     = (ushort_t*)alloc((size_t)64 * NS * 256 * 2);
  ushort_t* k_new  = (ushort_t*)alloc((size_t)400 * 256 * 2);
  float*    opart  = (float*)alloc((size_t)64 * 4 * NS * 256 * 4);
  float*    mpart  = (float*)alloc((size_t)64 * 4 * NS * 4);
  float*    lpart  = (float*)alloc((size_t)64 * 4 * NS * 4);
  ushort_t* o_buf  = (ushort_t*)alloc((size_t)400 * 2048 * 2);
  ushort_t* t_buf  = (ushort_t*)alloc((size_t)400 * 4096 * 2);
  ushort_t* x_buf  = (ushort_t*)alloc((size_t)400 * 1024 * 2);
  float*    h_buf  = (float*)alloc((size_t)400 * 1024 * 4);
  float*    temb   = (float*)alloc(8 * 1024 * 4);
  float*    tmp    = (float*)alloc(8 * 1024 * 4);
  float*    cond   = (float*)alloc(8 * 1024 * 4);
  float*    ada_all= (float*)alloc((size_t)12 * 8 * 1024 * 4);   // zeroed
  float*    adaf_o = (float*)alloc(8 * 1024 * 4);                // zeroed (adjacent)
  float*    cosT   = (float*)alloc(NS * 128 * 4);
  float*    sinT   = (float*)alloc(NS * 128 * 4);
  ushort_t* zpad   = (ushort_t*)alloc(512 * 2);

  hipMemsetAsync(zpad, 0, 512 * 2, stream);
  hipMemsetAsync(ada_all, 0, ((size_t)12 * 8 * 1024 + 8 * 1024) * 4, stream);

  // ---- conversion pass ----
  cvt_permute_kernel<<<9600, 256, 0, stream>>>(cache_k, kcache, (long)12 * 8 * NP);
  transpose_cvt<2><<<dim3(32, 16, 12), 256, 0, stream>>>(wq, (long)1024 * 2048, wqkvT, (long)2560 * 1024, 1024, 2048, 1024, 0);
  transpose_cvt<2><<<dim3(4, 16, 12), 256, 0, stream>>>(wk, (long)1024 * 256, wqkvT + (long)2048 * 1024, (long)2560 * 1024, 1024, 256, 1024, 0);
  transpose_cvt<0><<<dim3(4, 16, 12), 256, 0, stream>>>(wv, (long)1024 * 256, wqkvT + (long)2304 * 1024, (long)2560 * 1024, 1024, 256, 1024, 0);
  transpose_cvt<0><<<dim3(16, 32, 12), 256, 0, stream>>>(wo, (long)2048 * 1024, woT, (long)1024 * 2048, 2048, 1024, 2048, 0);
  transpose_cvt<1><<<dim3(64, 16, 12), 256, 0, stream>>>(wg, (long)1024 * 4096, wguT, (long)8192 * 1024, 1024, 4096, 1024, 0);
  transpose_cvt<1><<<dim3(64, 16, 12), 256, 0, stream>>>(wu, (long)1024 * 4096, wguT, (long)8192 * 1024, 1024, 4096, 1024, 32);
  transpose_cvt<0><<<dim3(16, 64, 12), 256, 0, stream>>>(wd, (long)4096 * 1024, wdT, (long)1024 * 4096, 4096, 1024, 4096, 0);
  transpose_cvt<0><<<dim3(4, 13, 96), 256, 0, stream>>>(cache_v, (long)NP * 256, vT, (long)256 * KPAD, NP, 256, KPAD, 0);

  // ---- embed + cond ----
  temb_kernel<<<32, 256, 0, stream>>>(tstep, temb);
  suffix_kernel<<<400, 256, 0, stream>>>(x_t, w_act_in, b_act_in, h_buf);
  rope_table_kernel<<<25, 256, 0, stream>>>(cosT, sinT);
  gemm_f32_kernel<2><<<dim3(1, 16, 1), 256, 0, stream>>>(temb, w_t1, tmp, NB, ND, ND, ND, ND, ND, b_t1);
  gemm_f32_kernel<1><<<dim3(1, 16, 1), 256, 0, stream>>>(tmp, w_t2, cond, NB, ND, ND, ND, ND, ND, b_t2);
  gemm_f32sk<<<dim3(1, 16, 48), 256, 0, stream>>>(cond, ada1_w, (long)ND * ND, ada_all, (long)NB * ND, NB, ND, ND, ND, ND, ND, 4);
  gemm_f32sk<<<dim3(1, 16, 4), 256, 0, stream>>>(cond, adaf_w, 0, adaf_o, 0, NB, ND, ND, ND, ND, ND, 4);

  for (int l = 0; l < NLAYER; ++l) {
    ushort_t* vT_l = vT + (long)l * 8 * 256 * KPAD;
    rms_kernel<true><<<400, 256, 0, stream>>>(h_buf, ln1_w + (long)l * ND, ada_all + (long)l * NB * ND, x_buf);
    // qkv + fused rope scatter (280 blocks)
    gemm64rope<<<dim3(7, 40, 1), 256, 0, stream>>>(
        x_buf, wqkvT + (long)l * 2560 * 1024, cosT, sinT, qT, k_new, vT_l);
    // flash2 attention partials (256 blocks, 4 chunks of 256 keys)
    flash2_kernel<<<dim3(64, 4, 1), 256, 0, stream>>>(
        qT, kcache + (long)l * 8 * NP * 256, k_new, vT_l, zpad, opart, mpart, lpart);
    att_combine<<<400, 256, 0, stream>>>(opart, mpart, lpart, o_buf);
    // h += o @ woT^T  (split-K 4, 448 blocks)
    gemm64acc<<<dim3(7, 16, 4), 256, 0, stream>>>(
        o_buf, woT + (long)l * 1024 * 2048, h_buf, 400, 1024, 2048, 2048, 2048, 1024, 512);
    rms_kernel<true><<<400, 256, 0, stream>>>(h_buf, ln2_w + (long)l * ND, nullptr, x_buf);
    // t = gelu(x@wg)*(x@wu)  fused  (896 blocks)
    gemm64G<<<dim3(7, 128, 1), 256, 0, stream>>>(
        x_buf, wguT + (long)l * 8192 * 1024, t_buf, 400, 1024, 1024, 1024, 4096);
    // h += t @ wdT^T  (split-K 4, 448 blocks)
    gemm64acc<<<dim3(7, 16, 4), 256, 0, stream>>>(
        t_buf, wdT + (long)l * 1024 * 4096, h_buf, 400, 1024, 4096, 4096, 4096, 1024, 1024);
  }

  final_fused<<<400, 256, 0, stream>>>(h_buf, lnf_w, adaf_o, wao, bao, x_t, dtp, outp);
}

// Round 8
// 1921.766 us; speedup vs baseline: 1.1258x; 1.0394x over previous
//
#include <hip/hip_runtime.h>
#include <hip/hip_bf16.h>
#include <math.h>

#define NLAYER 12
#define NB 8
#define NP 800
#define ND 1024
#define NH 8
#define NDH 256
#define NM 4096
#define NS 50
#define NA 32
#define NKEYS 850
#define KPAD 1024     // padded key count (covers 4 chunks of 256)

typedef unsigned short ushort_t;
typedef unsigned int u32;
using f32x4  = __attribute__((ext_vector_type(4))) float;
using short8 = __attribute__((ext_vector_type(8))) short;

__device__ __forceinline__ u32 pack_bf2(float lo, float hi) {
  u32 a = __float_as_uint(lo);
  u32 b = __float_as_uint(hi);
  a += 0x7fffu + ((a >> 16) & 1u);
  b += 0x7fffu + ((b >> 16) & 1u);
  return (a >> 16) | (b & 0xffff0000u);
}
__device__ __forceinline__ ushort_t bf1(float x) {
  u32 a = __float_as_uint(x);
  a += 0x7fffu + ((a >> 16) & 1u);
  return (ushort_t)(a >> 16);
}
__device__ __forceinline__ float ubf(ushort_t h) {
  return __uint_as_float(((u32)h) << 16);
}
__device__ __forceinline__ void async_cp16(const void* g, const void* l) {
  __builtin_amdgcn_global_load_lds(
      (const __attribute__((address_space(1))) u32*)g,
      (__attribute__((address_space(3))) u32*)l, 16, 0, 0);
}
// swizzled column index (ushort units) for 64-ushort LDS rows:
// element (row, c) lives at row*64 + (c ^ ((row&7)<<3))
#define SWZ(row, c) ((c) ^ (((row) & 7) << 3))

// ---------------------------------------------------------------------------
// conversion kernels
// ---------------------------------------------------------------------------

// kcache: f32 [rows][256] -> bf16 [rows][256] with d-permute j = 2*(d&127)+(d>>7)
__global__ void cvt_permute_kernel(const float* __restrict__ src, ushort_t* __restrict__ dst, long nrows) {
  long idx = (long)blockIdx.x * 256 + threadIdx.x;
  long row = idx >> 5;
  int t = (int)(idx & 31);
  if (row >= nrows) return;
  const float* s = src + row * 256 + t * 4;
  float4 lo = *reinterpret_cast<const float4*>(s);
  float4 hi = *reinterpret_cast<const float4*>(s + 128);
  ushort_t* d = dst + row * 256 + t * 8;
  *reinterpret_cast<uint4*>(d) =
      make_uint4(pack_bf2(lo.x, hi.x), pack_bf2(lo.y, hi.y),
                 pack_bf2(lo.z, hi.z), pack_bf2(lo.w, hi.w));
}

// tiled transpose + cvt: src f32 [z][R][C] -> dst bf16, dst_row = map(src col)
// MODE 0: row = c
// MODE 1 (g/u interleave): row = (c>>5)*64 + (c&31) + halfOff
// MODE 2 (rope pair-interleave per 256-head): row = (c&~255) + 2*(c&127) + ((c>>7)&1)
template<int MODE>
__global__ __launch_bounds__(256) void transpose_cvt(
    const float* __restrict__ src, long sz, ushort_t* __restrict__ dst, long dz,
    int R, int C, int ldd, int halfOff) {
  __shared__ float Ls[64][65];
  const float* s = src + (long)blockIdx.z * sz;
  ushort_t* d    = dst + (long)blockIdx.z * dz;
  int c0 = blockIdx.x * 64, r0 = blockIdx.y * 64;
  int t = threadIdx.x;
  int rr = t >> 4;
  int cc = (t & 15) * 4;
#pragma unroll
  for (int j = 0; j < 4; ++j) {
    int rl = rr + j * 16;
    int r = r0 + rl;
    float4 v = make_float4(0.f, 0.f, 0.f, 0.f);
    if (r < R) v = *reinterpret_cast<const float4*>(s + (long)r * C + c0 + cc);
    Ls[rl][cc] = v.x; Ls[rl][cc+1] = v.y; Ls[rl][cc+2] = v.z; Ls[rl][cc+3] = v.w;
  }
  __syncthreads();
  int dr = t >> 2;
  int rc = (t & 3) * 16;
  int cg = c0 + dr;
  long orow;
  if (MODE == 0)      orow = cg;
  else if (MODE == 1) orow = ((long)(cg >> 5) << 6) + (cg & 31) + halfOff;
  else                orow = (long)(cg & ~255) + ((cg & 127) << 1) + ((cg >> 7) & 1);
  ushort_t* drow = d + orow * ldd + r0 + rc;
#pragma unroll
  for (int i = 0; i < 16; i += 2) {
    int sr = r0 + rc + i;
    if (sr < R) {
      u32 p = pack_bf2(Ls[rc + i][dr], Ls[rc + i + 1][dr]);
      *reinterpret_cast<u32*>(drow + i) = p;
    }
  }
}

// ---------------------------------------------------------------------------
// small kernels
// ---------------------------------------------------------------------------

__global__ void temb_kernel(const float* __restrict__ ts, float* __restrict__ temb) {
  int idx = blockIdx.x * 256 + threadIdx.x;
  if (idx >= NB * ND) return;
  int b = idx >> 10, d = idx & 1023;
  int i = d & 511;
  float f = __expf(-logf(10000.f) * (float)i / 512.f);
  float ang = ts[b] * f;
  temb[idx] = (d < 512) ? sinf(ang) : cosf(ang);
}

__global__ void suffix_kernel(const float* __restrict__ x_t, const float* __restrict__ w,
                              const float* __restrict__ bias, float* __restrict__ h) {
  int m = blockIdx.x;
  __shared__ float xs[NA];
  if (threadIdx.x < NA) xs[threadIdx.x] = x_t[m * NA + threadIdx.x];
  __syncthreads();
  for (int n = threadIdx.x; n < ND; n += 256) {
    float acc = bias[n];
#pragma unroll
    for (int k = 0; k < NA; ++k) acc += xs[k] * w[k * ND + n];
    h[m * ND + n] = acc * 32.0f;
  }
}

__global__ void rope_table_kernel(float* __restrict__ cosT, float* __restrict__ sinT) {
  int idx = blockIdx.x * 256 + threadIdx.x;
  if (idx >= NS * 128) return;
  int s = idx >> 7, i = idx & 127;
  float inv = __expf(-(float)(2 * i) / 256.f * logf(10000.f));
  float ang = (float)(NP + s) * inv;
  cosT[idx] = cosf(ang);
  sinT[idx] = sinf(ang);
}

template<bool BFOUT>
__global__ void rms_kernel(const float* __restrict__ hin, const float* __restrict__ w,
                           const float* __restrict__ ada, void* __restrict__ outv) {
  int m = blockIdx.x;
  int b = m / NS;
  int d0 = threadIdx.x * 4;
  float4 v = *reinterpret_cast<const float4*>(hin + (long)m * ND + d0);
  float ss = v.x*v.x + v.y*v.y + v.z*v.z + v.w*v.w;
#pragma unroll
  for (int off = 32; off > 0; off >>= 1) ss += __shfl_down(ss, off);
  __shared__ float red[4];
  int lane = threadIdx.x & 63, wid = threadIdx.x >> 6;
  if (lane == 0) red[wid] = ss;
  __syncthreads();
  float tot = red[0] + red[1] + red[2] + red[3];
  float r = rsqrtf(tot * (1.f / ND) + 1e-6f);
  float4 wv = *reinterpret_cast<const float4*>(w + d0);
  float4 o;
  o.x = v.x * r * (1.f + wv.x);
  o.y = v.y * r * (1.f + wv.y);
  o.z = v.z * r * (1.f + wv.z);
  o.w = v.w * r * (1.f + wv.w);
  if (ada) {
    float4 av = *reinterpret_cast<const float4*>(ada + (long)b * ND + d0);
    o.x *= (1.f + av.x); o.y *= (1.f + av.y); o.z *= (1.f + av.z); o.w *= (1.f + av.w);
  }
  if (BFOUT) {
    *reinterpret_cast<uint2*>((ushort_t*)outv + (long)m * ND + d0) =
        make_uint2(pack_bf2(o.x, o.y), pack_bf2(o.z, o.w));
  } else {
    *reinterpret_cast<float4*>((float*)outv + (long)m * ND + d0) = o;
  }
}

// fused final rms + out projection + euler step
__global__ void final_fused(const float* __restrict__ hin, const float* __restrict__ lnf,
                            const float* __restrict__ adaf, const float* __restrict__ w,
                            const float* __restrict__ bias, const float* __restrict__ x_t,
                            const float* __restrict__ dt, float* __restrict__ out) {
  int m = blockIdx.x;
  int b = m / NS;
  int d0 = threadIdx.x * 4;
  __shared__ float hfs[ND];
  __shared__ float red[256];
  float4 v = *reinterpret_cast<const float4*>(hin + (long)m * ND + d0);
  float ss = v.x*v.x + v.y*v.y + v.z*v.z + v.w*v.w;
#pragma unroll
  for (int off = 32; off > 0; off >>= 1) ss += __shfl_down(ss, off);
  __shared__ float red4[4];
  int lane = threadIdx.x & 63, wid = threadIdx.x >> 6;
  if (lane == 0) red4[wid] = ss;
  __syncthreads();
  float tot = red4[0] + red4[1] + red4[2] + red4[3];
  float r = rsqrtf(tot * (1.f / ND) + 1e-6f);
  float4 wv = *reinterpret_cast<const float4*>(lnf + d0);
  float4 av = *reinterpret_cast<const float4*>(adaf + (long)b * ND + d0);
  hfs[d0]     = v.x * r * (1.f + wv.x) * (1.f + av.x);
  hfs[d0 + 1] = v.y * r * (1.f + wv.y) * (1.f + av.y);
  hfs[d0 + 2] = v.z * r * (1.f + wv.z) * (1.f + av.z);
  hfs[d0 + 3] = v.w * r * (1.f + wv.w) * (1.f + av.w);
  __syncthreads();
  int a = threadIdx.x & 31;
  int kg = threadIdx.x >> 5;
  float acc = 0.f;
  for (int k = kg; k < ND; k += 8) acc += hfs[k] * w[k * NA + a];
  red[threadIdx.x] = acc;
  __syncthreads();
  if (threadIdx.x < NA) {
    float s = 0.f;
#pragma unroll
    for (int g = 0; g < 8; ++g) s += red[g * 32 + a];
    out[m * NA + a] = x_t[m * NA + a] + dt[0] * (s + bias[a]);
  }
}

// ---------------------------------------------------------------------------
// generic 64x64 GEMM (2-phase dbuf, swizzled LDS), f32 atomicAdd epilogue
// ---------------------------------------------------------------------------
__global__ __launch_bounds__(256) void gemm64acc(
    const ushort_t* __restrict__ A,
    const ushort_t* __restrict__ B,
    float* __restrict__ C,
    int M, int N, int K, int lda, int ldb, int ldc, int kpb) {
  const int kbeg = blockIdx.z * kpb;
  const int kend = kbeg + kpb;

  const int m0 = blockIdx.x * 64;
  const int n0 = blockIdx.y * 64;
  const int tid = threadIdx.x;
  const int lane = tid & 63;
  const int wbase = tid & 192;
  const int wid = wbase >> 6;
  const int wm = (wid >> 1) * 32;
  const int wn = (wid & 1) * 32;
  const int l15 = lane & 15;
  const int l4  = lane >> 4;

  __shared__ ushort_t As[2][64 * 64];
  __shared__ ushort_t Bs[2][64 * 64];

  f32x4 acc[2][2] = {};

  const int ci0 = wbase + lane;
  const int row0 = ci0 >> 3;
  const int kc0 = (((ci0 & 7) ^ (row0 & 7)) << 3);   // inverse-swizzled source slot
  const int ci1 = 256 + ci0;
  const int row1 = ci1 >> 3;
  const int kc1 = (((ci1 & 7) ^ (row1 & 7)) << 3);
  int gra0 = m0 + row0; if (gra0 > M - 1) gra0 = M - 1;
  int gra1 = m0 + row1; if (gra1 > M - 1) gra1 = M - 1;
  const int n_0 = n0 + row0;
  const int n_1 = n0 + row1;

  auto stage = [&](int buf, int k0) {
    async_cp16(A + (long)gra0 * lda + k0 + kc0, (const char*)As[buf] + ci0 * 16);
    async_cp16(B + (long)n_0 * ldb + k0 + kc0, (const char*)Bs[buf] + ci0 * 16);
    async_cp16(A + (long)gra1 * lda + k0 + kc1, (const char*)As[buf] + ci1 * 16);
    async_cp16(B + (long)n_1 * ldb + k0 + kc1, (const char*)Bs[buf] + ci1 * 16);
  };

  const int nt = (kend - kbeg) >> 6;
  stage(0, kbeg);
  __syncthreads();
  int cur = 0;
  for (int t = 0; t < nt; ++t) {
    if (t + 1 < nt) stage(cur ^ 1, kbeg + (t + 1) * 64);
    const ushort_t* Ac = As[cur];
    const ushort_t* Bc = Bs[cur];
#pragma unroll
    for (int ks = 0; ks < 2; ++ks) {
      short8 af[2], bf[2];
#pragma unroll
      for (int mi = 0; mi < 2; ++mi) {
        int row = wm + mi * 16 + l15;
        af[mi] = *reinterpret_cast<const short8*>(&Ac[row * 64 + SWZ(row, ks * 32 + l4 * 8)]);
      }
#pragma unroll
      for (int ni = 0; ni < 2; ++ni) {
        int row = wn + ni * 16 + l15;
        bf[ni] = *reinterpret_cast<const short8*>(&Bc[row * 64 + SWZ(row, ks * 32 + l4 * 8)]);
      }
#pragma unroll
      for (int mi = 0; mi < 2; ++mi)
#pragma unroll
        for (int ni = 0; ni < 2; ++ni)
          acc[mi][ni] = __builtin_amdgcn_mfma_f32_16x16x32_bf16(af[mi], bf[ni], acc[mi][ni], 0, 0, 0);
    }
    __syncthreads();
    cur ^= 1;
  }

#pragma unroll
  for (int mi = 0; mi < 2; ++mi) {
#pragma unroll
    for (int ni = 0; ni < 2; ++ni) {
      int col = n0 + wn + ni * 16 + l15;
      int rb  = m0 + wm + mi * 16 + l4 * 4;
      if (col >= N) continue;
#pragma unroll
      for (int r = 0; r < 4; ++r) {
        int row = rb + r;
        if (row >= M) continue;
        atomicAdd(&C[(long)row * ldc + col], acc[mi][ni][r]);
      }
    }
  }
}

// ---------------------------------------------------------------------------
// qkv GEMM with fused RoPE epilogue (swizzled LDS). A = x_buf [400][1024],
// B = wqkvT (rows pair-interleaved j-space for q/k sections; v natural).
// cols [0,2048)=q -> qT[bh][50][256]; [2048,2304)=k -> k_new; [2304,2560)=v -> vT scatter
// ---------------------------------------------------------------------------
__global__ __launch_bounds__(256) void gemm64rope(
    const ushort_t* __restrict__ A,
    const ushort_t* __restrict__ B,
    const float* __restrict__ cosT, const float* __restrict__ sinT,
    ushort_t* __restrict__ qTo, ushort_t* __restrict__ k_new,
    ushort_t* __restrict__ vT_l) {
  const int M = 400, lda = 1024, ldb = 1024;
  const int m0 = blockIdx.x * 64;
  const int n0 = blockIdx.y * 64;
  const int tid = threadIdx.x;
  const int lane = tid & 63;
  const int wbase = tid & 192;
  const int wid = wbase >> 6;
  const int wm = (wid >> 1) * 32;
  const int wn = (wid & 1) * 32;
  const int l15 = lane & 15;
  const int l4  = lane >> 4;

  __shared__ ushort_t As[2][64 * 64];
  __shared__ ushort_t Bs[2][64 * 64];

  f32x4 acc[2][2] = {};

  const int ci0 = wbase + lane;
  const int row0 = ci0 >> 3;
  const int kc0 = (((ci0 & 7) ^ (row0 & 7)) << 3);
  const int ci1 = 256 + ci0;
  const int row1 = ci1 >> 3;
  const int kc1 = (((ci1 & 7) ^ (row1 & 7)) << 3);
  int gra0 = m0 + row0; if (gra0 > M - 1) gra0 = M - 1;
  int gra1 = m0 + row1; if (gra1 > M - 1) gra1 = M - 1;
  const int n_0 = n0 + row0;
  const int n_1 = n0 + row1;

  auto stage = [&](int buf, int k0) {
    async_cp16(A + (long)gra0 * lda + k0 + kc0, (const char*)As[buf] + ci0 * 16);
    async_cp16(B + (long)n_0 * ldb + k0 + kc0, (const char*)Bs[buf] + ci0 * 16);
    async_cp16(A + (long)gra1 * lda + k0 + kc1, (const char*)As[buf] + ci1 * 16);
    async_cp16(B + (long)n_1 * ldb + k0 + kc1, (const char*)Bs[buf] + ci1 * 16);
  };

  stage(0, 0);
  __syncthreads();
  int cur = 0;
  for (int t = 0; t < 16; ++t) {
    if (t + 1 < 16) stage(cur ^ 1, (t + 1) * 64);
    const ushort_t* Ac = As[cur];
    const ushort_t* Bc = Bs[cur];
#pragma unroll
    for (int ks = 0; ks < 2; ++ks) {
      short8 af[2], bf[2];
#pragma unroll
      for (int mi = 0; mi < 2; ++mi) {
        int row = wm + mi * 16 + l15;
        af[mi] = *reinterpret_cast<const short8*>(&Ac[row * 64 + SWZ(row, ks * 32 + l4 * 8)]);
      }
#pragma unroll
      for (int ni = 0; ni < 2; ++ni) {
        int row = wn + ni * 16 + l15;
        bf[ni] = *reinterpret_cast<const short8*>(&Bc[row * 64 + SWZ(row, ks * 32 + l4 * 8)]);
      }
#pragma unroll
      for (int mi = 0; mi < 2; ++mi)
#pragma unroll
        for (int ni = 0; ni < 2; ++ni)
          acc[mi][ni] = __builtin_amdgcn_mfma_f32_16x16x32_bf16(af[mi], bf[ni], acc[mi][ni], 0, 0, 0);
    }
    __syncthreads();
    cur ^= 1;
  }

#pragma unroll
  for (int mi = 0; mi < 2; ++mi) {
#pragma unroll
    for (int ni = 0; ni < 2; ++ni) {
      int col = n0 + wn + ni * 16 + l15;
      int rb  = m0 + wm + mi * 16 + l4 * 4;
      float pv[4];
#pragma unroll
      for (int r = 0; r < 4; ++r) pv[r] = __shfl_xor(acc[mi][ni][r], 1);
#pragma unroll
      for (int r = 0; r < 4; ++r) {
        int row = rb + r;
        if (row >= 400) continue;
        int b = row / NS, s = row - b * NS;
        float v = acc[mi][ni][r];
        if (col < 2304) {
          int j = col & 255;
          int i = j >> 1;
          float c = cosT[s * 128 + i], sn = sinT[s * 128 + i];
          float o = (col & 1) ? (v * c + pv[r] * sn) : (v * c - pv[r] * sn);
          if (col < 2048)
            qTo[((long)((b << 3) + (col >> 8)) * NS + s) * 256 + j] = bf1(o);
          else
            k_new[(long)row * 256 + j] = bf1(o);
        } else {
          vT_l[((long)(b * 256 + (col - 2304))) * KPAD + NP + s] = bf1(v);
        }
      }
    }
  }
}

// ---------------------------------------------------------------------------
// flash2: grid (64 bh, 4 chunks of 256 keys), 256 threads, dbuf + swizzled K/V.
// Q frags loaded straight from L2 to registers. Writes opart f32
// [bh][4][50][256] + m,l [bh][4][50].
// ---------------------------------------------------------------------------
__global__ __launch_bounds__(256) void flash2_kernel(
    const ushort_t* __restrict__ qT,
    const ushort_t* __restrict__ kcache_l,
    const ushort_t* __restrict__ k_new,
    const ushort_t* __restrict__ vT_l,
    const ushort_t* __restrict__ zpad,
    float* __restrict__ opart, float* __restrict__ mpart, float* __restrict__ lpart) {
  const int bh = blockIdx.x;
  const int ch = blockIdx.y;
  const int b  = bh >> 3;
  const int tid = threadIdx.x;
  const int lane = tid & 63;
  const int w = tid >> 6;
  const int wm = (w >> 1) * 32;     // q-row base of this wave
  const int wn = (w & 1) * 128;     // key / dout base of this wave
  const int l15 = lane & 15;
  const int l4  = lane >> 4;

  __shared__ __align__(16) char lds[100352];
  ushort_t* KV0 = (ushort_t*)lds;                   // 32KB
  ushort_t* KV1 = (ushort_t*)(lds + 32768);         // 32KB
  ushort_t* Ps  = (ushort_t*)(lds + 65536);         // [64][264] 33792B
  float* SMm = (float*)(lds + 99328);               // [2][64]
  float* SMl = (float*)(lds + 99840);               // [2][64]

  // ---- Q fragments straight to registers (rows wm..wm+31, dup rows >= 50) ----
  short8 qf[4][2][2];
  {
    const ushort_t* qbase = qT + (long)bh * NS * 256;
#pragma unroll
    for (int mi = 0; mi < 2; ++mi) {
      int row = wm + mi * 16 + l15;
      int qr = row < NS ? row : NS - 1;
      const ushort_t* qrow = qbase + (long)qr * 256;
#pragma unroll
      for (int s = 0; s < 4; ++s)
#pragma unroll
        for (int ks = 0; ks < 2; ++ks)
          qf[s][mi][ks] = *reinterpret_cast<const short8*>(qrow + s * 64 + ks * 32 + l4 * 8);
    }
  }

  // K slice stage: [256 keys][64 d] for d-slice s (inverse-swizzled source slot)
  auto stageK = [&](ushort_t* buf, int s) {
#pragma unroll
    for (int i = 0; i < 8; ++i) {
      int ci = i * 256 + tid;
      int key = ch * 256 + (ci >> 3);
      int seg = (ci ^ (ci >> 3)) & 7;
      const ushort_t* src;
      if (key < NP)         src = kcache_l + ((long)(b * NP + key)) * 256 + s * 64 + seg * 8;
      else if (key < NKEYS) src = k_new + ((long)(b * NS + key - NP)) * 256 + s * 64 + seg * 8;
      else                  src = zpad + seg * 8;
      async_cp16(src, (char*)buf + ci * 16);
    }
  };
  // V slice stage: [256 dout][64 keys] for key-slice s
  auto stageV = [&](ushort_t* buf, int s) {
#pragma unroll
    for (int i = 0; i < 8; ++i) {
      int ci = i * 256 + tid;
      int dout = ci >> 3;
      int seg = (ci ^ (ci >> 3)) & 7;
      async_cp16(vT_l + ((long)(b * 256 + dout)) * KPAD + ch * 256 + s * 64 + seg * 8,
                 (char*)buf + ci * 16);
    }
  };

  // ---- QK^T: S[64 rows][256 keys], d-loop 4 slices, double-buffered ----
  f32x4 s2[2][8] = {};
  stageK(KV0, 0);
  __syncthreads();
#pragma unroll
  for (int s = 0; s < 4; ++s) {
    ushort_t* buf = (s & 1) ? KV1 : KV0;
    ushort_t* nxt = (s & 1) ? KV0 : KV1;
    if (s < 3) stageK(nxt, s + 1);
    __builtin_amdgcn_s_setprio(1);
#pragma unroll
    for (int ks = 0; ks < 2; ++ks) {
      short8 bf[8];
#pragma unroll
      for (int ni = 0; ni < 8; ++ni) {
        int row = wn + ni * 16 + l15;
        bf[ni] = *reinterpret_cast<const short8*>(&buf[row * 64 + SWZ(row, ks * 32 + l4 * 8)]);
      }
#pragma unroll
      for (int mi = 0; mi < 2; ++mi)
#pragma unroll
        for (int ni = 0; ni < 8; ++ni)
          s2[mi][ni] = __builtin_amdgcn_mfma_f32_16x16x32_bf16(qf[s][mi][ks], bf[ni], s2[mi][ni], 0, 0, 0);
    }
    __builtin_amdgcn_s_setprio(0);
    __syncthreads();
  }

  // V slice 0 loads fly under the softmax
  stageV(KV0, 0);

  // ---- softmax: scale, mask, row max / sum across the 256 keys ----
  float mx[2][4];
#pragma unroll
  for (int mi = 0; mi < 2; ++mi)
#pragma unroll
    for (int r = 0; r < 4; ++r) mx[mi][r] = -1e30f;
#pragma unroll
  for (int mi = 0; mi < 2; ++mi)
#pragma unroll
    for (int ni = 0; ni < 8; ++ni) {
      int key = ch * 256 + wn + ni * 16 + l15;
      bool valid = key < NKEYS;
#pragma unroll
      for (int r = 0; r < 4; ++r) {
        float v = s2[mi][ni][r] * 0.0625f;
        v = valid ? v : -1e30f;
        s2[mi][ni][r] = v;
        mx[mi][r] = fmaxf(mx[mi][r], v);
      }
    }
#pragma unroll
  for (int off = 1; off < 16; off <<= 1)
#pragma unroll
    for (int mi = 0; mi < 2; ++mi)
#pragma unroll
      for (int r = 0; r < 4; ++r)
        mx[mi][r] = fmaxf(mx[mi][r], __shfl_xor(mx[mi][r], off));
  if (l15 == 0) {
#pragma unroll
    for (int mi = 0; mi < 2; ++mi)
#pragma unroll
      for (int r = 0; r < 4; ++r)
        SMm[(w & 1) * 64 + wm + mi * 16 + l4 * 4 + r] = mx[mi][r];
  }
  __syncthreads();
  float mrow[2][4], sum[2][4];
#pragma unroll
  for (int mi = 0; mi < 2; ++mi)
#pragma unroll
    for (int r = 0; r < 4; ++r) {
      int row = wm + mi * 16 + l4 * 4 + r;
      mrow[mi][r] = fmaxf(SMm[row], SMm[64 + row]);
      sum[mi][r] = 0.f;
    }
#pragma unroll
  for (int mi = 0; mi < 2; ++mi)
#pragma unroll
    for (int ni = 0; ni < 8; ++ni) {
      int colp = wn + ni * 16 + l15;
#pragma unroll
      for (int r = 0; r < 4; ++r) {
        float e = __expf(s2[mi][ni][r] - mrow[mi][r]);
        Ps[(wm + mi * 16 + l4 * 4 + r) * 264 + colp] = bf1(e);
        sum[mi][r] += e;
      }
    }
#pragma unroll
  for (int off = 1; off < 16; off <<= 1)
#pragma unroll
    for (int mi = 0; mi < 2; ++mi)
#pragma unroll
      for (int r = 0; r < 4; ++r)
        sum[mi][r] += __shfl_xor(sum[mi][r], off);
  if (l15 == 0) {
#pragma unroll
    for (int mi = 0; mi < 2; ++mi)
#pragma unroll
      for (int r = 0; r < 4; ++r)
        SMl[(w & 1) * 64 + wm + mi * 16 + l4 * 4 + r] = sum[mi][r];
  }
  __syncthreads();
  if ((w & 1) == 0 && l15 == 0) {
#pragma unroll
    for (int mi = 0; mi < 2; ++mi)
#pragma unroll
      for (int r = 0; r < 4; ++r) {
        int row = wm + mi * 16 + l4 * 4 + r;
        if (row < NS) {
          mpart[((long)bh * 4 + ch) * NS + row] = mrow[mi][r];
          lpart[((long)bh * 4 + ch) * NS + row] = SMl[row] + SMl[64 + row];
        }
      }
  }

  // ---- PV: O[64][256] = P[64][256] @ V[256][256], key-loop dbuf ----
  f32x4 o2[2][8] = {};
#pragma unroll
  for (int s = 0; s < 4; ++s) {
    ushort_t* buf = (s & 1) ? KV1 : KV0;
    ushort_t* nxt = (s & 1) ? KV0 : KV1;
    if (s < 3) stageV(nxt, s + 1);
    __builtin_amdgcn_s_setprio(1);
#pragma unroll
    for (int ks = 0; ks < 2; ++ks) {
      short8 af[2], bf[8];
#pragma unroll
      for (int mi = 0; mi < 2; ++mi)
        af[mi] = *reinterpret_cast<const short8*>(&Ps[(wm + mi * 16 + l15) * 264 + s * 64 + ks * 32 + l4 * 8]);
#pragma unroll
      for (int ni = 0; ni < 8; ++ni) {
        int row = wn + ni * 16 + l15;
        bf[ni] = *reinterpret_cast<const short8*>(&buf[row * 64 + SWZ(row, ks * 32 + l4 * 8)]);
      }
#pragma unroll
      for (int mi = 0; mi < 2; ++mi)
#pragma unroll
        for (int ni = 0; ni < 8; ++ni)
          o2[mi][ni] = __builtin_amdgcn_mfma_f32_16x16x32_bf16(af[mi], bf[ni], o2[mi][ni], 0, 0, 0);
    }
    __builtin_amdgcn_s_setprio(0);
    __syncthreads();
  }

#pragma unroll
  for (int mi = 0; mi < 2; ++mi)
#pragma unroll
    for (int ni = 0; ni < 8; ++ni) {
      int col = wn + ni * 16 + l15;
#pragma unroll
      for (int r = 0; r < 4; ++r) {
        int row = wm + mi * 16 + l4 * 4 + r;
        if (row < NS)
          opart[(((long)bh * 4 + ch) * NS + row) * 256 + col] = o2[mi][ni][r];
      }
    }
}

// combine 4 chunk partials -> o_buf bf16 [400][2048]
__global__ void att_combine(const float* __restrict__ opart, const float* __restrict__ mpart,
                            const float* __restrict__ lpart, ushort_t* __restrict__ o_buf) {
  int blk = blockIdx.x;           // b*50+s
  int b = blk / NS, s = blk - b * NS;
  int d = threadIdx.x;            // 0..255
  for (int h = 0; h < NH; ++h) {
    int bh = b * NH + h;
    float mv[4];
    float m = -1e30f;
#pragma unroll
    for (int c = 0; c < 4; ++c) {
      mv[c] = mpart[((long)bh * 4 + c) * NS + s];
      m = fmaxf(m, mv[c]);
    }
    float den = 0.f, o = 0.f;
#pragma unroll
    for (int c = 0; c < 4; ++c) {
      float wgt = __expf(mv[c] - m);
      den += wgt * lpart[((long)bh * 4 + c) * NS + s];
      o   += wgt * opart[(((long)bh * 4 + c) * NS + s) * 256 + d];
    }
    o_buf[(long)blk * 2048 + h * 256 + d] = bf1(o / den);
  }
}

// ---------------------------------------------------------------------------
// gated GEMM (2-phase, swizzled LDS): B = wguT interleaved [8192][1024]
// 4 waves as 4x1 (wave tile 16m x 64n). out = gelu(g)*u, bf16 [M][4096].
// ---------------------------------------------------------------------------
__global__ __launch_bounds__(256) void gemm64G(
    const ushort_t* __restrict__ A, const ushort_t* __restrict__ B,
    ushort_t* __restrict__ C, int M, int K, int lda, int ldb, int ldc) {
  const int m0 = blockIdx.x * 64;
  const int n0 = blockIdx.y * 64;
  const int tid = threadIdx.x;
  const int lane = tid & 63;
  const int wbase = tid & 192;
  const int wid = wbase >> 6;
  const int l15 = lane & 15;
  const int l4  = lane >> 4;

  __shared__ ushort_t As[2][64 * 64];
  __shared__ ushort_t Bs[2][64 * 64];

  f32x4 acc[4] = {};

  const int ci0 = wbase + lane;
  const int row0 = ci0 >> 3;
  const int kc0 = (((ci0 & 7) ^ (row0 & 7)) << 3);
  const int ci1 = 256 + ci0;
  const int row1 = ci1 >> 3;
  const int kc1 = (((ci1 & 7) ^ (row1 & 7)) << 3);
  int gra0 = m0 + row0; if (gra0 > M - 1) gra0 = M - 1;
  int gra1 = m0 + row1; if (gra1 > M - 1) gra1 = M - 1;

  auto stage = [&](int buf, int k0) {
    async_cp16(A + (long)gra0 * lda + k0 + kc0, (const char*)As[buf] + ci0 * 16);
    async_cp16(B + (long)(n0 + row0) * ldb + k0 + kc0, (const char*)Bs[buf] + ci0 * 16);
    async_cp16(A + (long)gra1 * lda + k0 + kc1, (const char*)As[buf] + ci1 * 16);
    async_cp16(B + (long)(n0 + row1) * ldb + k0 + kc1, (const char*)Bs[buf] + ci1 * 16);
  };

  const int nt = K >> 6;
  stage(0, 0);
  __syncthreads();
  int cur = 0;
  for (int t = 0; t < nt; ++t) {
    if (t + 1 < nt) stage(cur ^ 1, (t + 1) * 64);
    const ushort_t* Ac = As[cur];
    const ushort_t* Bc = Bs[cur];
#pragma unroll
    for (int ks = 0; ks < 2; ++ks) {
      int arow = wid * 16 + l15;
      short8 af = *reinterpret_cast<const short8*>(&Ac[arow * 64 + SWZ(arow, ks * 32 + l4 * 8)]);
#pragma unroll
      for (int ni = 0; ni < 4; ++ni) {
        int row = ni * 16 + l15;
        short8 bf = *reinterpret_cast<const short8*>(&Bc[row * 64 + SWZ(row, ks * 32 + l4 * 8)]);
        acc[ni] = __builtin_amdgcn_mfma_f32_16x16x32_bf16(af, bf, acc[ni], 0, 0, 0);
      }
    }
    __syncthreads();
    cur ^= 1;
  }

#pragma unroll
  for (int ni = 0; ni < 2; ++ni) {
    int col = (n0 >> 1) + ni * 16 + l15;
    int rb  = m0 + wid * 16 + l4 * 4;
#pragma unroll
    for (int r = 0; r < 4; ++r) {
      int row = rb + r;
      if (row >= M) continue;
      float g = acc[ni][r];
      float u = acc[ni + 2][r];
      float inner = 0.7978845608028654f * (g + 0.044715f * g * g * g);
      float t = 0.5f * g * (1.f + tanhf(inner));
      C[(long)row * ldc + col] = bf1(t * u);
    }
  }
}

// ---------------------------------------------------------------------------
// f32-input GEMM (cond path, M=8). EPI: 1=+bias 2=silu(acc+bias)
// ---------------------------------------------------------------------------
template<int EPI>
__global__ __launch_bounds__(256)
void gemm_f32_kernel(const float* __restrict__ A,
                     const float* __restrict__ B1,
                     float* __restrict__ C,
                     int M, int N, int K, int lda, int ldb, int ldc,
                     const float* __restrict__ bias) {
  const int m0 = blockIdx.x * 64;
  const int n0 = blockIdx.y * 64;
  const int tid = threadIdx.x;
  const int lane = tid & 63;
  const int wid = tid >> 6;
  const int wm = (wid >> 1) * 32;
  const int wn = (wid & 1) * 32;
  const int l15 = lane & 15;
  const int l4  = lane >> 4;

  __shared__ __align__(16) ushort_t As[64][72];
  __shared__ __align__(16) ushort_t Bs[64][72];

  f32x4 acc[2][2] = {};

  for (int k0 = 0; k0 < K; k0 += 64) {
#pragma unroll
    for (int pass = 0; pass < 2; ++pass) {
      int c = tid + pass * 256;
      int row = c >> 3;
      int kc = (c & 7) * 8;
      int gr = m0 + row, gk = k0 + kc;
      float v[8];
#pragma unroll
      for (int j = 0; j < 8; ++j)
        v[j] = (gr < M && gk + j < K) ? A[(long)gr * lda + gk + j] : 0.f;
      *reinterpret_cast<uint4*>(&As[row][kc]) =
          make_uint4(pack_bf2(v[0],v[1]), pack_bf2(v[2],v[3]),
                     pack_bf2(v[4],v[5]), pack_bf2(v[6],v[7]));
    }
    {
      int n = tid & 63;
      int kg = tid >> 6;
      int gn = n0 + n;
      u32 pk[8];
#pragma unroll
      for (int kk = 0; kk < 16; kk += 2) {
        int kga = k0 + kg * 16 + kk;
        float v0 = (gn < N && kga < K)     ? B1[(long)kga * ldb + gn] : 0.f;
        float v1 = (gn < N && kga + 1 < K) ? B1[(long)(kga + 1) * ldb + gn] : 0.f;
        pk[kk >> 1] = pack_bf2(v0, v1);
      }
      *reinterpret_cast<uint4*>(&Bs[n][kg * 16])     = make_uint4(pk[0],pk[1],pk[2],pk[3]);
      *reinterpret_cast<uint4*>(&Bs[n][kg * 16 + 8]) = make_uint4(pk[4],pk[5],pk[6],pk[7]);
    }
    __syncthreads();
#pragma unroll
    for (int ks = 0; ks < 2; ++ks) {
      short8 af[2], bfr[2];
#pragma unroll
      for (int mi = 0; mi < 2; ++mi)
        af[mi] = *reinterpret_cast<const short8*>(&As[wm + mi*16 + l15][ks*32 + l4*8]);
#pragma unroll
      for (int ni = 0; ni < 2; ++ni)
        bfr[ni] = *reinterpret_cast<const short8*>(&Bs[wn + ni*16 + l15][ks*32 + l4*8]);
#pragma unroll
      for (int mi = 0; mi < 2; ++mi)
#pragma unroll
        for (int ni = 0; ni < 2; ++ni)
          acc[mi][ni] = __builtin_amdgcn_mfma_f32_16x16x32_bf16(af[mi], bfr[ni], acc[mi][ni], 0, 0, 0);
    }
    __syncthreads();
  }

#pragma unroll
  for (int mi = 0; mi < 2; ++mi) {
#pragma unroll
    for (int ni = 0; ni < 2; ++ni) {
      int col = n0 + wn + ni * 16 + l15;
      int rb  = m0 + wm + mi * 16 + l4 * 4;
#pragma unroll
      for (int r = 0; r < 4; ++r) {
        int row = rb + r;
        if (row < M && col < N) {
          float v = acc[mi][ni][r];
          if (EPI == 1) C[(long)row * ldc + col] = v + bias[col];
          else {
            float t = v + bias[col];
            C[(long)row * ldc + col] = t / (1.f + __expf(-t));
          }
        }
      }
    }
  }
}

// f32-input GEMM with layer batching + split-K, atomicAdd (ada path, M=8)
__global__ __launch_bounds__(256)
void gemm_f32sk(const float* __restrict__ A,
                const float* __restrict__ B, long bz,
                float* __restrict__ C, long cz,
                int M, int N, int K, int lda, int ldb, int ldc, int nks) {
  const int zz = blockIdx.z;
  const int layer = zz / nks;
  const int chunk = zz % nks;
  const int kpb = K / nks;
  const int kbeg = chunk * kpb, kend = kbeg + kpb;
  const float* Bb = B + (long)layer * bz;
  float* Cb = C + (long)layer * cz;

  const int m0 = blockIdx.x * 64;
  const int n0 = blockIdx.y * 64;
  const int tid = threadIdx.x;
  const int lane = tid & 63;
  const int wid = tid >> 6;
  const int wm = (wid >> 1) * 32;
  const int wn = (wid & 1) * 32;
  const int l15 = lane & 15;
  const int l4  = lane >> 4;

  __shared__ __align__(16) ushort_t As[64][72];
  __shared__ __align__(16) ushort_t Bs[64][72];

  f32x4 acc[2][2] = {};

  for (int k0 = kbeg; k0 < kend; k0 += 64) {
#pragma unroll
    for (int pass = 0; pass < 2; ++pass) {
      int c = tid + pass * 256;
      int row = c >> 3;
      int kc = (c & 7) * 8;
      int gr = m0 + row, gk = k0 + kc;
      float v[8];
#pragma unroll
      for (int j = 0; j < 8; ++j)
        v[j] = (gr < M) ? A[(long)gr * lda + gk + j] : 0.f;
      *reinterpret_cast<uint4*>(&As[row][kc]) =
          make_uint4(pack_bf2(v[0],v[1]), pack_bf2(v[2],v[3]),
                     pack_bf2(v[4],v[5]), pack_bf2(v[6],v[7]));
    }
    {
      int n = tid & 63;
      int kg = tid >> 6;
      int gn = n0 + n;
      u32 pk[8];
#pragma unroll
      for (int kk = 0; kk < 16; kk += 2) {
        int kga = k0 + kg * 16 + kk;
        float v0 = Bb[(long)kga * ldb + gn];
        float v1 = Bb[(long)(kga + 1) * ldb + gn];
        pk[kk >> 1] = pack_bf2(v0, v1);
      }
      *reinterpret_cast<uint4*>(&Bs[n][kg * 16])     = make_uint4(pk[0],pk[1],pk[2],pk[3]);
      *reinterpret_cast<uint4*>(&Bs[n][kg * 16 + 8]) = make_uint4(pk[4],pk[5],pk[6],pk[7]);
    }
    __syncthreads();
#pragma unroll
    for (int ks = 0; ks < 2; ++ks) {
      short8 af[2], bfr[2];
#pragma unroll
      for (int mi = 0; mi < 2; ++mi)
        af[mi] = *reinterpret_cast<const short8*>(&As[wm + mi*16 + l15][ks*32 + l4*8]);
#pragma unroll
      for (int ni = 0; ni < 2; ++ni)
        bfr[ni] = *reinterpret_cast<const short8*>(&Bs[wn + ni*16 + l15][ks*32 + l4*8]);
#pragma unroll
      for (int mi = 0; mi < 2; ++mi)
#pragma unroll
        for (int ni = 0; ni < 2; ++ni)
          acc[mi][ni] = __builtin_amdgcn_mfma_f32_16x16x32_bf16(af[mi], bfr[ni], acc[mi][ni], 0, 0, 0);
    }
    __syncthreads();
  }

#pragma unroll
  for (int mi = 0; mi < 2; ++mi) {
#pragma unroll
    for (int ni = 0; ni < 2; ++ni) {
      int col = n0 + wn + ni * 16 + l15;
      int rb  = m0 + wm + mi * 16 + l4 * 4;
#pragma unroll
      for (int r = 0; r < 4; ++r) {
        int row = rb + r;
        if (row < M && col < N)
          atomicAdd(&Cb[(long)row * ldc + col], acc[mi][ni][r]);
      }
    }
  }
}

// ---------------------------------------------------------------------------
extern "C" void kernel_launch(void* const* d_in, const int* in_sizes, int n_in,
                              void* d_out, int out_size, void* d_ws, size_t ws_size,
                              hipStream_t stream) {
  (void)in_sizes; (void)n_in; (void)out_size; (void)ws_size;
  const float* x_t      = (const float*)d_in[1];
  const float* tstep    = (const float*)d_in[2];
  const float* dtp      = (const float*)d_in[3];
  const float* cache_k  = (const float*)d_in[4];
  const float* cache_v  = (const float*)d_in[5];
  const float* w_act_in = (const float*)d_in[6];
  const float* b_act_in = (const float*)d_in[7];
  const float* w_t1     = (const float*)d_in[8];
  const float* b_t1     = (const float*)d_in[9];
  const float* w_t2     = (const float*)d_in[10];
  const float* b_t2     = (const float*)d_in[11];
  const float* ln1_w    = (const float*)d_in[12];
  const float* ada1_w   = (const float*)d_in[13];
  const float* ln2_w    = (const float*)d_in[14];
  const float* wq       = (const float*)d_in[15];
  const float* wk       = (const float*)d_in[16];
  const float* wv       = (const float*)d_in[17];
  const float* wo       = (const float*)d_in[18];
  const float* wg       = (const float*)d_in[19];
  const float* wu       = (const float*)d_in[20];
  const float* wd       = (const float*)d_in[21];
  const float* lnf_w    = (const float*)d_in[22];
  const float* adaf_w   = (const float*)d_in[23];
  const float* wao      = (const float*)d_in[24];
  const float* bao      = (const float*)d_in[25];
  float* outp = (float*)d_out;

  char* p = (char*)d_ws;
  auto alloc = [&](size_t bytes) { char* r = p; p += (bytes + 255) & ~(size_t)255; return r; };

  ushort_t* wqkvT  = (ushort_t*)alloc((size_t)12 * 2560 * 1024 * 2);
  ushort_t* woT    = (ushort_t*)alloc((size_t)12 * 1024 * 2048 * 2);
  ushort_t* wguT   = (ushort_t*)alloc((size_t)12 * 8192 * 1024 * 2);
  ushort_t* wdT    = (ushort_t*)alloc((size_t)12 * 1024 * 4096 * 2);
  ushort_t* kcache = (ushort_t*)alloc((size_t)12 * 8 * NP * 256 * 2);
  ushort_t* vT     = (ushort_t*)alloc((size_t)12 * 8 * 256 * KPAD * 2);
  ushort_t* qT     = (ushort_t*)alloc((size_t)64 * NS * 256 * 2);
  ushort_t* k_new  = (ushort_t*)alloc((size_t)400 * 256 * 2);
  float*    opart  = (float*)alloc((size_t)64 * 4 * NS * 256 * 4);
  float*    mpart  = (float*)alloc((size_t)64 * 4 * NS * 4);
  float*    lpart  = (float*)alloc((size_t)64 * 4 * NS * 4);
  ushort_t* o_buf  = (ushort_t*)alloc((size_t)400 * 2048 * 2);
  ushort_t* t_buf  = (ushort_t*)alloc((size_t)400 * 4096 * 2);
  ushort_t* x_buf  = (ushort_t*)alloc((size_t)400 * 1024 * 2);
  float*    h_buf  = (float*)alloc((size_t)400 * 1024 * 4);
  float*    temb   = (float*)alloc(8 * 1024 * 4);
  float*    tmp    = (float*)alloc(8 * 1024 * 4);
  float*    cond   = (float*)alloc(8 * 1024 * 4);
  float*    ada_all= (float*)alloc((size_t)12 * 8 * 1024 * 4);   // zeroed
  float*    adaf_o = (float*)alloc(8 * 1024 * 4);                // zeroed (adjacent)
  float*    cosT   = (float*)alloc(NS * 128 * 4);
  float*    sinT   = (float*)alloc(NS * 128 * 4);
  ushort_t* zpad   = (ushort_t*)alloc(512 * 2);

  hipMemsetAsync(zpad, 0, 512 * 2, stream);
  hipMemsetAsync(ada_all, 0, ((size_t)12 * 8 * 1024 + 8 * 1024) * 4, stream);

  // ---- conversion pass ----
  cvt_permute_kernel<<<9600, 256, 0, stream>>>(cache_k, kcache, (long)12 * 8 * NP);
  transpose_cvt<2><<<dim3(32, 16, 12), 256, 0, stream>>>(wq, (long)1024 * 2048, wqkvT, (long)2560 * 1024, 1024, 2048, 1024, 0);
  transpose_cvt<2><<<dim3(4, 16, 12), 256, 0, stream>>>(wk, (long)1024 * 256, wqkvT + (long)2048 * 1024, (long)2560 * 1024, 1024, 256, 1024, 0);
  transpose_cvt<0><<<dim3(4, 16, 12), 256, 0, stream>>>(wv, (long)1024 * 256, wqkvT + (long)2304 * 1024, (long)2560 * 1024, 1024, 256, 1024, 0);
  transpose_cvt<0><<<dim3(16, 32, 12), 256, 0, stream>>>(wo, (long)2048 * 1024, woT, (long)1024 * 2048, 2048, 1024, 2048, 0);
  transpose_cvt<1><<<dim3(64, 16, 12), 256, 0, stream>>>(wg, (long)1024 * 4096, wguT, (long)8192 * 1024, 1024, 4096, 1024, 0);
  transpose_cvt<1><<<dim3(64, 16, 12), 256, 0, stream>>>(wu, (long)1024 * 4096, wguT, (long)8192 * 1024, 1024, 4096, 1024, 32);
  transpose_cvt<0><<<dim3(16, 64, 12), 256, 0, stream>>>(wd, (long)4096 * 1024, wdT, (long)1024 * 4096, 4096, 1024, 4096, 0);
  transpose_cvt<0><<<dim3(4, 13, 96), 256, 0, stream>>>(cache_v, (long)NP * 256, vT, (long)256 * KPAD, NP, 256, KPAD, 0);

  // ---- embed + cond ----
  temb_kernel<<<32, 256, 0, stream>>>(tstep, temb);
  suffix_kernel<<<400, 256, 0, stream>>>(x_t, w_act_in, b_act_in, h_buf);
  rope_table_kernel<<<25, 256, 0, stream>>>(cosT, sinT);
  gemm_f32_kernel<2><<<dim3(1, 16, 1), 256, 0, stream>>>(temb, w_t1, tmp, NB, ND, ND, ND, ND, ND, b_t1);
  gemm_f32_kernel<1><<<dim3(1, 16, 1), 256, 0, stream>>>(tmp, w_t2, cond, NB, ND, ND, ND, ND, ND, b_t2);
  gemm_f32sk<<<dim3(1, 16, 48), 256, 0, stream>>>(cond, ada1_w, (long)ND * ND, ada_all, (long)NB * ND, NB, ND, ND, ND, ND, ND, 4);
  gemm_f32sk<<<dim3(1, 16, 4), 256, 0, stream>>>(cond, adaf_w, 0, adaf_o, 0, NB, ND, ND, ND, ND, ND, 4);

  for (int l = 0; l < NLAYER; ++l) {
    ushort_t* vT_l = vT + (long)l * 8 * 256 * KPAD;
    rms_kernel<true><<<400, 256, 0, stream>>>(h_buf, ln1_w + (long)l * ND, ada_all + (long)l * NB * ND, x_buf);
    // qkv + fused rope scatter (280 blocks)
    gemm64rope<<<dim3(7, 40, 1), 256, 0, stream>>>(
        x_buf, wqkvT + (long)l * 2560 * 1024, cosT, sinT, qT, k_new, vT_l);
    // flash2 attention partials (256 blocks, 4 chunks of 256 keys)
    flash2_kernel<<<dim3(64, 4, 1), 256, 0, stream>>>(
        qT, kcache + (long)l * 8 * NP * 256, k_new, vT_l, zpad, opart, mpart, lpart);
    att_combine<<<400, 256, 0, stream>>>(opart, mpart, lpart, o_buf);
    // h += o @ woT^T  (split-K 4, 448 blocks)
    gemm64acc<<<dim3(7, 16, 4), 256, 0, stream>>>(
        o_buf, woT + (long)l * 1024 * 2048, h_buf, 400, 1024, 2048, 2048, 2048, 1024, 512);
    rms_kernel<true><<<400, 256, 0, stream>>>(h_buf, ln2_w + (long)l * ND, nullptr, x_buf);
    // t = gelu(x@wg)*(x@wu)  fused  (896 blocks)
    gemm64G<<<dim3(7, 128, 1), 256, 0, stream>>>(
        x_buf, wguT + (long)l * 8192 * 1024, t_buf, 400, 1024, 1024, 1024, 4096);
    // h += t @ wdT^T  (split-K 4, 448 blocks)
    gemm64acc<<<dim3(7, 16, 4), 256, 0, stream>>>(
        t_buf, wdT + (long)l * 1024 * 4096, h_buf, 400, 1024, 4096, 4096, 4096, 1024, 1024);
  }

  final_fused<<<400, 256, 0, stream>>>(h_buf, lnf_w, adaf_o, wao, bao, x_t, dtp, outp);
}

// Round 9
// 1810.759 us; speedup vs baseline: 1.1948x; 1.0613x over previous
//
#include <hip/hip_runtime.h>
#include <hip/hip_bf16.h>
#include <math.h>

#define NLAYER 12
#define NB 8
#define NP 800
#define ND 1024
#define NH 8
#define NDH 256
#define NM 4096
#define NS 50
#define NA 32
#define NKEYS 850
#define KPAD 1024     // padded key count (covers 4 chunks of 256)

typedef unsigned short ushort_t;
typedef unsigned int u32;
using f32x4  = __attribute__((ext_vector_type(4))) float;
using short8 = __attribute__((ext_vector_type(8))) short;

__device__ __forceinline__ u32 pack_bf2(float lo, float hi) {
  u32 a = __float_as_uint(lo);
  u32 b = __float_as_uint(hi);
  a += 0x7fffu + ((a >> 16) & 1u);
  b += 0x7fffu + ((b >> 16) & 1u);
  return (a >> 16) | (b & 0xffff0000u);
}
__device__ __forceinline__ ushort_t bf1(float x) {
  u32 a = __float_as_uint(x);
  a += 0x7fffu + ((a >> 16) & 1u);
  return (ushort_t)(a >> 16);
}
__device__ __forceinline__ float ubf(ushort_t h) {
  return __uint_as_float(((u32)h) << 16);
}
__device__ __forceinline__ void async_cp16(const void* g, const void* l) {
  __builtin_amdgcn_global_load_lds(
      (const __attribute__((address_space(1))) u32*)g,
      (__attribute__((address_space(3))) u32*)l, 16, 0, 0);
}
// swizzled column index (ushort units) for 64-ushort LDS rows:
// element (row, c) lives at row*64 + (c ^ ((row&7)<<3))
#define SWZ(row, c) ((c) ^ (((row) & 7) << 3))

// ---------------------------------------------------------------------------
// conversion kernels
// ---------------------------------------------------------------------------

// kcache: f32 [rows][256] -> bf16 [rows][256] with d-permute j = 2*(d&127)+(d>>7)
__global__ void cvt_permute_kernel(const float* __restrict__ src, ushort_t* __restrict__ dst, long nrows) {
  long idx = (long)blockIdx.x * 256 + threadIdx.x;
  long row = idx >> 5;
  int t = (int)(idx & 31);
  if (row >= nrows) return;
  const float* s = src + row * 256 + t * 4;
  float4 lo = *reinterpret_cast<const float4*>(s);
  float4 hi = *reinterpret_cast<const float4*>(s + 128);
  ushort_t* d = dst + row * 256 + t * 8;
  *reinterpret_cast<uint4*>(d) =
      make_uint4(pack_bf2(lo.x, hi.x), pack_bf2(lo.y, hi.y),
                 pack_bf2(lo.z, hi.z), pack_bf2(lo.w, hi.w));
}

// tiled transpose + cvt: src f32 [z][R][C] -> dst bf16, dst_row = map(src col)
// MODE 0: row = c
// MODE 1 (g/u interleave): row = (c>>5)*64 + (c&31) + halfOff
// MODE 2 (rope pair-interleave per 256-head): row = (c&~255) + 2*(c&127) + ((c>>7)&1)
template<int MODE>
__global__ __launch_bounds__(256) void transpose_cvt(
    const float* __restrict__ src, long sz, ushort_t* __restrict__ dst, long dz,
    int R, int C, int ldd, int halfOff) {
  __shared__ float Ls[64][65];
  const float* s = src + (long)blockIdx.z * sz;
  ushort_t* d    = dst + (long)blockIdx.z * dz;
  int c0 = blockIdx.x * 64, r0 = blockIdx.y * 64;
  int t = threadIdx.x;
  int rr = t >> 4;
  int cc = (t & 15) * 4;
#pragma unroll
  for (int j = 0; j < 4; ++j) {
    int rl = rr + j * 16;
    int r = r0 + rl;
    float4 v = make_float4(0.f, 0.f, 0.f, 0.f);
    if (r < R) v = *reinterpret_cast<const float4*>(s + (long)r * C + c0 + cc);
    Ls[rl][cc] = v.x; Ls[rl][cc+1] = v.y; Ls[rl][cc+2] = v.z; Ls[rl][cc+3] = v.w;
  }
  __syncthreads();
  int dr = t >> 2;
  int rc = (t & 3) * 16;
  int cg = c0 + dr;
  long orow;
  if (MODE == 0)      orow = cg;
  else if (MODE == 1) orow = ((long)(cg >> 5) << 6) + (cg & 31) + halfOff;
  else                orow = (long)(cg & ~255) + ((cg & 127) << 1) + ((cg >> 7) & 1);
  ushort_t* drow = d + orow * ldd + r0 + rc;
#pragma unroll
  for (int i = 0; i < 16; i += 2) {
    int sr = r0 + rc + i;
    if (sr < R) {
      u32 p = pack_bf2(Ls[rc + i][dr], Ls[rc + i + 1][dr]);
      *reinterpret_cast<u32*>(drow + i) = p;
    }
  }
}

// ---------------------------------------------------------------------------
// small kernels
// ---------------------------------------------------------------------------

__global__ void temb_kernel(const float* __restrict__ ts, float* __restrict__ temb) {
  int idx = blockIdx.x * 256 + threadIdx.x;
  if (idx >= NB * ND) return;
  int b = idx >> 10, d = idx & 1023;
  int i = d & 511;
  float f = __expf(-logf(10000.f) * (float)i / 512.f);
  float ang = ts[b] * f;
  temb[idx] = (d < 512) ? sinf(ang) : cosf(ang);
}

__global__ void suffix_kernel(const float* __restrict__ x_t, const float* __restrict__ w,
                              const float* __restrict__ bias, float* __restrict__ h) {
  int m = blockIdx.x;
  __shared__ float xs[NA];
  if (threadIdx.x < NA) xs[threadIdx.x] = x_t[m * NA + threadIdx.x];
  __syncthreads();
  for (int n = threadIdx.x; n < ND; n += 256) {
    float acc = bias[n];
#pragma unroll
    for (int k = 0; k < NA; ++k) acc += xs[k] * w[k * ND + n];
    h[m * ND + n] = acc * 32.0f;
  }
}

__global__ void rope_table_kernel(float* __restrict__ cosT, float* __restrict__ sinT) {
  int idx = blockIdx.x * 256 + threadIdx.x;
  if (idx >= NS * 128) return;
  int s = idx >> 7, i = idx & 127;
  float inv = __expf(-(float)(2 * i) / 256.f * logf(10000.f));
  float ang = (float)(NP + s) * inv;
  cosT[idx] = cosf(ang);
  sinT[idx] = sinf(ang);
}

// rms with optional 4-slab residual completion: h += sum(slabs); out = rms(h)*(1+w)[*(1+ada)]
template<bool BFOUT>
__global__ void rms_kernel(float* __restrict__ hin, const float* __restrict__ slabs,
                           const float* __restrict__ w,
                           const float* __restrict__ ada, void* __restrict__ outv) {
  int m = blockIdx.x;
  int b = m / NS;
  int d0 = threadIdx.x * 4;
  float4 v = *reinterpret_cast<const float4*>(hin + (long)m * ND + d0);
  if (slabs) {
#pragma unroll
    for (int c = 0; c < 4; ++c) {
      float4 sv = *reinterpret_cast<const float4*>(slabs + ((long)c * 400 + m) * ND + d0);
      v.x += sv.x; v.y += sv.y; v.z += sv.z; v.w += sv.w;
    }
    *reinterpret_cast<float4*>(hin + (long)m * ND + d0) = v;
  }
  float ss = v.x*v.x + v.y*v.y + v.z*v.z + v.w*v.w;
#pragma unroll
  for (int off = 32; off > 0; off >>= 1) ss += __shfl_down(ss, off);
  __shared__ float red[4];
  int lane = threadIdx.x & 63, wid = threadIdx.x >> 6;
  if (lane == 0) red[wid] = ss;
  __syncthreads();
  float tot = red[0] + red[1] + red[2] + red[3];
  float r = rsqrtf(tot * (1.f / ND) + 1e-6f);
  float4 wv = *reinterpret_cast<const float4*>(w + d0);
  float4 o;
  o.x = v.x * r * (1.f + wv.x);
  o.y = v.y * r * (1.f + wv.y);
  o.z = v.z * r * (1.f + wv.z);
  o.w = v.w * r * (1.f + wv.w);
  if (ada) {
    float4 av = *reinterpret_cast<const float4*>(ada + (long)b * ND + d0);
    o.x *= (1.f + av.x); o.y *= (1.f + av.y); o.z *= (1.f + av.z); o.w *= (1.f + av.w);
  }
  if (BFOUT) {
    *reinterpret_cast<uint2*>((ushort_t*)outv + (long)m * ND + d0) =
        make_uint2(pack_bf2(o.x, o.y), pack_bf2(o.z, o.w));
  } else {
    *reinterpret_cast<float4*>((float*)outv + (long)m * ND + d0) = o;
  }
}

// fused final: h += sum(wd slabs); rms; out projection; euler step
__global__ void final_fused(const float* __restrict__ hin, const float* __restrict__ slabs,
                            const float* __restrict__ lnf,
                            const float* __restrict__ adaf, const float* __restrict__ w,
                            const float* __restrict__ bias, const float* __restrict__ x_t,
                            const float* __restrict__ dt, float* __restrict__ out) {
  int m = blockIdx.x;
  int b = m / NS;
  int d0 = threadIdx.x * 4;
  __shared__ float hfs[ND];
  __shared__ float red[256];
  float4 v = *reinterpret_cast<const float4*>(hin + (long)m * ND + d0);
#pragma unroll
  for (int c = 0; c < 4; ++c) {
    float4 sv = *reinterpret_cast<const float4*>(slabs + ((long)c * 400 + m) * ND + d0);
    v.x += sv.x; v.y += sv.y; v.z += sv.z; v.w += sv.w;
  }
  float ss = v.x*v.x + v.y*v.y + v.z*v.z + v.w*v.w;
#pragma unroll
  for (int off = 32; off > 0; off >>= 1) ss += __shfl_down(ss, off);
  __shared__ float red4[4];
  int lane = threadIdx.x & 63, wid = threadIdx.x >> 6;
  if (lane == 0) red4[wid] = ss;
  __syncthreads();
  float tot = red4[0] + red4[1] + red4[2] + red4[3];
  float r = rsqrtf(tot * (1.f / ND) + 1e-6f);
  float4 wv = *reinterpret_cast<const float4*>(lnf + d0);
  float4 av = *reinterpret_cast<const float4*>(adaf + (long)b * ND + d0);
  hfs[d0]     = v.x * r * (1.f + wv.x) * (1.f + av.x);
  hfs[d0 + 1] = v.y * r * (1.f + wv.y) * (1.f + av.y);
  hfs[d0 + 2] = v.z * r * (1.f + wv.z) * (1.f + av.z);
  hfs[d0 + 3] = v.w * r * (1.f + wv.w) * (1.f + av.w);
  __syncthreads();
  int a = threadIdx.x & 31;
  int kg = threadIdx.x >> 5;
  float acc = 0.f;
  for (int k = kg; k < ND; k += 8) acc += hfs[k] * w[k * NA + a];
  red[threadIdx.x] = acc;
  __syncthreads();
  if (threadIdx.x < NA) {
    float s = 0.f;
#pragma unroll
    for (int g = 0; g < 8; ++g) s += red[g * 32 + a];
    out[m * NA + a] = x_t[m * NA + a] + dt[0] * (s + bias[a]);
  }
}

// ---------------------------------------------------------------------------
// 64x64 GEMM (2-phase dbuf, swizzled LDS), split-K f32 slab epilogue.
// Grid MUST be (7,16,4); XCD-swizzled so same-B-panel blocks share an XCD.
// ---------------------------------------------------------------------------
__global__ __launch_bounds__(256) void gemm64slab(
    const ushort_t* __restrict__ A,
    const ushort_t* __restrict__ B,
    float* __restrict__ C,             // [4][400][ldc] slabs
    int M, int N, int K, int lda, int ldb, int ldc, int kpb) {
  const int flat3 = blockIdx.x + 7 * (blockIdx.y + 16 * blockIdx.z);   // 0..447
  const int wgid = (flat3 & 7) * 56 + (flat3 >> 3);
  const int chunk = wgid / 112;
  const int rem = wgid - chunk * 112;
  const int m0 = (rem % 7) * 64;
  const int n0 = (rem / 7) * 64;
  const int kbeg = chunk * kpb;
  const int kend = kbeg + kpb;

  const int tid = threadIdx.x;
  const int lane = tid & 63;
  const int wbase = tid & 192;
  const int wid = wbase >> 6;
  const int wm = (wid >> 1) * 32;
  const int wn = (wid & 1) * 32;
  const int l15 = lane & 15;
  const int l4  = lane >> 4;

  __shared__ ushort_t As[2][64 * 64];
  __shared__ ushort_t Bs[2][64 * 64];

  f32x4 acc[2][2] = {};

  const int ci0 = wbase + lane;
  const int row0 = ci0 >> 3;
  const int kc0 = (((ci0 & 7) ^ (row0 & 7)) << 3);   // inverse-swizzled source slot
  const int ci1 = 256 + ci0;
  const int row1 = ci1 >> 3;
  const int kc1 = (((ci1 & 7) ^ (row1 & 7)) << 3);
  int gra0 = m0 + row0; if (gra0 > M - 1) gra0 = M - 1;
  int gra1 = m0 + row1; if (gra1 > M - 1) gra1 = M - 1;
  const int n_0 = n0 + row0;
  const int n_1 = n0 + row1;

  auto stage = [&](int buf, int k0) {
    async_cp16(A + (long)gra0 * lda + k0 + kc0, (const char*)As[buf] + ci0 * 16);
    async_cp16(B + (long)n_0 * ldb + k0 + kc0, (const char*)Bs[buf] + ci0 * 16);
    async_cp16(A + (long)gra1 * lda + k0 + kc1, (const char*)As[buf] + ci1 * 16);
    async_cp16(B + (long)n_1 * ldb + k0 + kc1, (const char*)Bs[buf] + ci1 * 16);
  };

  const int nt = (kend - kbeg) >> 6;
  stage(0, kbeg);
  __syncthreads();
  int cur = 0;
  for (int t = 0; t < nt; ++t) {
    if (t + 1 < nt) stage(cur ^ 1, kbeg + (t + 1) * 64);
    const ushort_t* Ac = As[cur];
    const ushort_t* Bc = Bs[cur];
#pragma unroll
    for (int ks = 0; ks < 2; ++ks) {
      short8 af[2], bf[2];
#pragma unroll
      for (int mi = 0; mi < 2; ++mi) {
        int row = wm + mi * 16 + l15;
        af[mi] = *reinterpret_cast<const short8*>(&Ac[row * 64 + SWZ(row, ks * 32 + l4 * 8)]);
      }
#pragma unroll
      for (int ni = 0; ni < 2; ++ni) {
        int row = wn + ni * 16 + l15;
        bf[ni] = *reinterpret_cast<const short8*>(&Bc[row * 64 + SWZ(row, ks * 32 + l4 * 8)]);
      }
#pragma unroll
      for (int mi = 0; mi < 2; ++mi)
#pragma unroll
        for (int ni = 0; ni < 2; ++ni)
          acc[mi][ni] = __builtin_amdgcn_mfma_f32_16x16x32_bf16(af[mi], bf[ni], acc[mi][ni], 0, 0, 0);
    }
    __syncthreads();
    cur ^= 1;
  }

  float* Cs = C + (long)chunk * 400 * ldc;
#pragma unroll
  for (int mi = 0; mi < 2; ++mi) {
#pragma unroll
    for (int ni = 0; ni < 2; ++ni) {
      int col = n0 + wn + ni * 16 + l15;
      int rb  = m0 + wm + mi * 16 + l4 * 4;
      if (col >= N) continue;
#pragma unroll
      for (int r = 0; r < 4; ++r) {
        int row = rb + r;
        if (row >= M) continue;
        Cs[(long)row * ldc + col] = acc[mi][ni][r];
      }
    }
  }
}

// ---------------------------------------------------------------------------
// qkv GEMM with fused RoPE epilogue (swizzled LDS, XCD-swizzled grid (7,40)).
// B = wqkvT (rows pair-interleaved j-space for q/k sections; v natural).
// cols [0,2048)=q -> qT[bh][50][256]; [2048,2304)=k -> k_new; [2304,2560)=v -> vT scatter
// ---------------------------------------------------------------------------
__global__ __launch_bounds__(256) void gemm64rope(
    const ushort_t* __restrict__ A,
    const ushort_t* __restrict__ B,
    const float* __restrict__ cosT, const float* __restrict__ sinT,
    ushort_t* __restrict__ qTo, ushort_t* __restrict__ k_new,
    ushort_t* __restrict__ vT_l) {
  const int M = 400, lda = 1024, ldb = 1024;
  const int flat = blockIdx.x + 7 * blockIdx.y;          // 0..279
  const int wgid = (flat & 7) * 35 + (flat >> 3);
  const int m0 = (wgid % 7) * 64;
  const int n0 = (wgid / 7) * 64;
  const int tid = threadIdx.x;
  const int lane = tid & 63;
  const int wbase = tid & 192;
  const int wid = wbase >> 6;
  const int wm = (wid >> 1) * 32;
  const int wn = (wid & 1) * 32;
  const int l15 = lane & 15;
  const int l4  = lane >> 4;

  __shared__ ushort_t As[2][64 * 64];
  __shared__ ushort_t Bs[2][64 * 64];

  f32x4 acc[2][2] = {};

  const int ci0 = wbase + lane;
  const int row0 = ci0 >> 3;
  const int kc0 = (((ci0 & 7) ^ (row0 & 7)) << 3);
  const int ci1 = 256 + ci0;
  const int row1 = ci1 >> 3;
  const int kc1 = (((ci1 & 7) ^ (row1 & 7)) << 3);
  int gra0 = m0 + row0; if (gra0 > M - 1) gra0 = M - 1;
  int gra1 = m0 + row1; if (gra1 > M - 1) gra1 = M - 1;
  const int n_0 = n0 + row0;
  const int n_1 = n0 + row1;

  auto stage = [&](int buf, int k0) {
    async_cp16(A + (long)gra0 * lda + k0 + kc0, (const char*)As[buf] + ci0 * 16);
    async_cp16(B + (long)n_0 * ldb + k0 + kc0, (const char*)Bs[buf] + ci0 * 16);
    async_cp16(A + (long)gra1 * lda + k0 + kc1, (const char*)As[buf] + ci1 * 16);
    async_cp16(B + (long)n_1 * ldb + k0 + kc1, (const char*)Bs[buf] + ci1 * 16);
  };

  stage(0, 0);
  __syncthreads();
  int cur = 0;
  for (int t = 0; t < 16; ++t) {
    if (t + 1 < 16) stage(cur ^ 1, (t + 1) * 64);
    const ushort_t* Ac = As[cur];
    const ushort_t* Bc = Bs[cur];
#pragma unroll
    for (int ks = 0; ks < 2; ++ks) {
      short8 af[2], bf[2];
#pragma unroll
      for (int mi = 0; mi < 2; ++mi) {
        int row = wm + mi * 16 + l15;
        af[mi] = *reinterpret_cast<const short8*>(&Ac[row * 64 + SWZ(row, ks * 32 + l4 * 8)]);
      }
#pragma unroll
      for (int ni = 0; ni < 2; ++ni) {
        int row = wn + ni * 16 + l15;
        bf[ni] = *reinterpret_cast<const short8*>(&Bc[row * 64 + SWZ(row, ks * 32 + l4 * 8)]);
      }
#pragma unroll
      for (int mi = 0; mi < 2; ++mi)
#pragma unroll
        for (int ni = 0; ni < 2; ++ni)
          acc[mi][ni] = __builtin_amdgcn_mfma_f32_16x16x32_bf16(af[mi], bf[ni], acc[mi][ni], 0, 0, 0);
    }
    __syncthreads();
    cur ^= 1;
  }

#pragma unroll
  for (int mi = 0; mi < 2; ++mi) {
#pragma unroll
    for (int ni = 0; ni < 2; ++ni) {
      int col = n0 + wn + ni * 16 + l15;
      int rb  = m0 + wm + mi * 16 + l4 * 4;
      float pv[4];
#pragma unroll
      for (int r = 0; r < 4; ++r) pv[r] = __shfl_xor(acc[mi][ni][r], 1);
#pragma unroll
      for (int r = 0; r < 4; ++r) {
        int row = rb + r;
        if (row >= 400) continue;
        int b = row / NS, s = row - b * NS;
        float v = acc[mi][ni][r];
        if (col < 2304) {
          int j = col & 255;
          int i = j >> 1;
          float c = cosT[s * 128 + i], sn = sinT[s * 128 + i];
          float o = (col & 1) ? (v * c + pv[r] * sn) : (v * c - pv[r] * sn);
          if (col < 2048)
            qTo[((long)((b << 3) + (col >> 8)) * NS + s) * 256 + j] = bf1(o);
          else
            k_new[(long)row * 256 + j] = bf1(o);
        } else {
          vT_l[((long)(b * 256 + (col - 2304))) * KPAD + NP + s] = bf1(v);
        }
      }
    }
  }
}

// ---------------------------------------------------------------------------
// flash2: grid (64 bh, 4 chunks of 256 keys) XCD-swizzled, 256 threads,
// dbuf + swizzled K/V. Q straight to registers. opart f32 [bh][4][50][256].
// ---------------------------------------------------------------------------
__global__ __launch_bounds__(256) void flash2_kernel(
    const ushort_t* __restrict__ qT,
    const ushort_t* __restrict__ kcache_l,
    const ushort_t* __restrict__ k_new,
    const ushort_t* __restrict__ vT_l,
    const ushort_t* __restrict__ zpad,
    float* __restrict__ opart, float* __restrict__ mpart, float* __restrict__ lpart) {
  const int flat = blockIdx.x + 64 * blockIdx.y;     // 0..255
  const int wgid = (flat & 7) * 32 + (flat >> 3);
  const int bh = wgid & 63;
  const int ch = wgid >> 6;
  const int b  = bh >> 3;
  const int tid = threadIdx.x;
  const int lane = tid & 63;
  const int w = tid >> 6;
  const int wm = (w >> 1) * 32;     // q-row base of this wave
  const int wn = (w & 1) * 128;     // key / dout base of this wave
  const int l15 = lane & 15;
  const int l4  = lane >> 4;

  __shared__ __align__(16) char lds[100352];
  ushort_t* KV0 = (ushort_t*)lds;                   // 32KB
  ushort_t* KV1 = (ushort_t*)(lds + 32768);         // 32KB
  ushort_t* Ps  = (ushort_t*)(lds + 65536);         // [64][264] 33792B
  float* SMm = (float*)(lds + 99328);               // [2][64]
  float* SMl = (float*)(lds + 99840);               // [2][64]

  // ---- Q fragments straight to registers (rows wm..wm+31, dup rows >= 50) ----
  short8 qf[4][2][2];
  {
    const ushort_t* qbase = qT + (long)bh * NS * 256;
#pragma unroll
    for (int mi = 0; mi < 2; ++mi) {
      int row = wm + mi * 16 + l15;
      int qr = row < NS ? row : NS - 1;
      const ushort_t* qrow = qbase + (long)qr * 256;
#pragma unroll
      for (int s = 0; s < 4; ++s)
#pragma unroll
        for (int ks = 0; ks < 2; ++ks)
          qf[s][mi][ks] = *reinterpret_cast<const short8*>(qrow + s * 64 + ks * 32 + l4 * 8);
    }
  }

  // K slice stage: [256 keys][64 d] for d-slice s (inverse-swizzled source slot)
  auto stageK = [&](ushort_t* buf, int s) {
#pragma unroll
    for (int i = 0; i < 8; ++i) {
      int ci = i * 256 + tid;
      int key = ch * 256 + (ci >> 3);
      int seg = (ci ^ (ci >> 3)) & 7;
      const ushort_t* src;
      if (key < NP)         src = kcache_l + ((long)(b * NP + key)) * 256 + s * 64 + seg * 8;
      else if (key < NKEYS) src = k_new + ((long)(b * NS + key - NP)) * 256 + s * 64 + seg * 8;
      else                  src = zpad + seg * 8;
      async_cp16(src, (char*)buf + ci * 16);
    }
  };
  // V slice stage: [256 dout][64 keys] for key-slice s
  auto stageV = [&](ushort_t* buf, int s) {
#pragma unroll
    for (int i = 0; i < 8; ++i) {
      int ci = i * 256 + tid;
      int dout = ci >> 3;
      int seg = (ci ^ (ci >> 3)) & 7;
      async_cp16(vT_l + ((long)(b * 256 + dout)) * KPAD + ch * 256 + s * 64 + seg * 8,
                 (char*)buf + ci * 16);
    }
  };

  // ---- QK^T: S[64 rows][256 keys], d-loop 4 slices, double-buffered ----
  f32x4 s2[2][8] = {};
  stageK(KV0, 0);
  __syncthreads();
#pragma unroll
  for (int s = 0; s < 4; ++s) {
    ushort_t* buf = (s & 1) ? KV1 : KV0;
    ushort_t* nxt = (s & 1) ? KV0 : KV1;
    if (s < 3) stageK(nxt, s + 1);
    __builtin_amdgcn_s_setprio(1);
#pragma unroll
    for (int ks = 0; ks < 2; ++ks) {
      short8 bf[8];
#pragma unroll
      for (int ni = 0; ni < 8; ++ni) {
        int row = wn + ni * 16 + l15;
        bf[ni] = *reinterpret_cast<const short8*>(&buf[row * 64 + SWZ(row, ks * 32 + l4 * 8)]);
      }
#pragma unroll
      for (int mi = 0; mi < 2; ++mi)
#pragma unroll
        for (int ni = 0; ni < 8; ++ni)
          s2[mi][ni] = __builtin_amdgcn_mfma_f32_16x16x32_bf16(qf[s][mi][ks], bf[ni], s2[mi][ni], 0, 0, 0);
    }
    __builtin_amdgcn_s_setprio(0);
    __syncthreads();
  }

  // V slice 0 loads fly under the softmax
  stageV(KV0, 0);

  // ---- softmax: scale, mask, row max / sum across the 256 keys ----
  float mx[2][4];
#pragma unroll
  for (int mi = 0; mi < 2; ++mi)
#pragma unroll
    for (int r = 0; r < 4; ++r) mx[mi][r] = -1e30f;
#pragma unroll
  for (int mi = 0; mi < 2; ++mi)
#pragma unroll
    for (int ni = 0; ni < 8; ++ni) {
      int key = ch * 256 + wn + ni * 16 + l15;
      bool valid = key < NKEYS;
#pragma unroll
      for (int r = 0; r < 4; ++r) {
        float v = s2[mi][ni][r] * 0.0625f;
        v = valid ? v : -1e30f;
        s2[mi][ni][r] = v;
        mx[mi][r] = fmaxf(mx[mi][r], v);
      }
    }
#pragma unroll
  for (int off = 1; off < 16; off <<= 1)
#pragma unroll
    for (int mi = 0; mi < 2; ++mi)
#pragma unroll
      for (int r = 0; r < 4; ++r)
        mx[mi][r] = fmaxf(mx[mi][r], __shfl_xor(mx[mi][r], off));
  if (l15 == 0) {
#pragma unroll
    for (int mi = 0; mi < 2; ++mi)
#pragma unroll
      for (int r = 0; r < 4; ++r)
        SMm[(w & 1) * 64 + wm + mi * 16 + l4 * 4 + r] = mx[mi][r];
  }
  __syncthreads();
  float mrow[2][4], sum[2][4];
#pragma unroll
  for (int mi = 0; mi < 2; ++mi)
#pragma unroll
    for (int r = 0; r < 4; ++r) {
      int row = wm + mi * 16 + l4 * 4 + r;
      mrow[mi][r] = fmaxf(SMm[row], SMm[64 + row]);
      sum[mi][r] = 0.f;
    }
#pragma unroll
  for (int mi = 0; mi < 2; ++mi)
#pragma unroll
    for (int ni = 0; ni < 8; ++ni) {
      int colp = wn + ni * 16 + l15;
#pragma unroll
      for (int r = 0; r < 4; ++r) {
        float e = __expf(s2[mi][ni][r] - mrow[mi][r]);
        Ps[(wm + mi * 16 + l4 * 4 + r) * 264 + colp] = bf1(e);
        sum[mi][r] += e;
      }
    }
#pragma unroll
  for (int off = 1; off < 16; off <<= 1)
#pragma unroll
    for (int mi = 0; mi < 2; ++mi)
#pragma unroll
      for (int r = 0; r < 4; ++r)
        sum[mi][r] += __shfl_xor(sum[mi][r], off);
  if (l15 == 0) {
#pragma unroll
    for (int mi = 0; mi < 2; ++mi)
#pragma unroll
      for (int r = 0; r < 4; ++r)
        SMl[(w & 1) * 64 + wm + mi * 16 + l4 * 4 + r] = sum[mi][r];
  }
  __syncthreads();
  if ((w & 1) == 0 && l15 == 0) {
#pragma unroll
    for (int mi = 0; mi < 2; ++mi)
#pragma unroll
      for (int r = 0; r < 4; ++r) {
        int row = wm + mi * 16 + l4 * 4 + r;
        if (row < NS) {
          mpart[((long)bh * 4 + ch) * NS + row] = mrow[mi][r];
          lpart[((long)bh * 4 + ch) * NS + row] = SMl[row] + SMl[64 + row];
        }
      }
  }

  // ---- PV: O[64][256] = P[64][256] @ V[256][256], key-loop dbuf ----
  f32x4 o2[2][8] = {};
#pragma unroll
  for (int s = 0; s < 4; ++s) {
    ushort_t* buf = (s & 1) ? KV1 : KV0;
    ushort_t* nxt = (s & 1) ? KV0 : KV1;
    if (s < 3) stageV(nxt, s + 1);
    __builtin_amdgcn_s_setprio(1);
#pragma unroll
    for (int ks = 0; ks < 2; ++ks) {
      short8 af[2], bf[8];
#pragma unroll
      for (int mi = 0; mi < 2; ++mi)
        af[mi] = *reinterpret_cast<const short8*>(&Ps[(wm + mi * 16 + l15) * 264 + s * 64 + ks * 32 + l4 * 8]);
#pragma unroll
      for (int ni = 0; ni < 8; ++ni) {
        int row = wn + ni * 16 + l15;
        bf[ni] = *reinterpret_cast<const short8*>(&buf[row * 64 + SWZ(row, ks * 32 + l4 * 8)]);
      }
#pragma unroll
      for (int mi = 0; mi < 2; ++mi)
#pragma unroll
        for (int ni = 0; ni < 8; ++ni)
          o2[mi][ni] = __builtin_amdgcn_mfma_f32_16x16x32_bf16(af[mi], bf[ni], o2[mi][ni], 0, 0, 0);
    }
    __builtin_amdgcn_s_setprio(0);
    __syncthreads();
  }

#pragma unroll
  for (int mi = 0; mi < 2; ++mi)
#pragma unroll
    for (int ni = 0; ni < 8; ++ni) {
      int col = wn + ni * 16 + l15;
#pragma unroll
      for (int r = 0; r < 4; ++r) {
        int row = wm + mi * 16 + l4 * 4 + r;
        if (row < NS)
          opart[(((long)bh * 4 + ch) * NS + row) * 256 + col] = o2[mi][ni][r];
      }
    }
}

// combine 4 chunk partials -> o_buf bf16 [400][2048]
__global__ void att_combine(const float* __restrict__ opart, const float* __restrict__ mpart,
                            const float* __restrict__ lpart, ushort_t* __restrict__ o_buf) {
  int blk = blockIdx.x;           // b*50+s
  int b = blk / NS, s = blk - b * NS;
  int d = threadIdx.x;            // 0..255
  for (int h = 0; h < NH; ++h) {
    int bh = b * NH + h;
    float mv[4];
    float m = -1e30f;
#pragma unroll
    for (int c = 0; c < 4; ++c) {
      mv[c] = mpart[((long)bh * 4 + c) * NS + s];
      m = fmaxf(m, mv[c]);
    }
    float den = 0.f, o = 0.f;
#pragma unroll
    for (int c = 0; c < 4; ++c) {
      float wgt = __expf(mv[c] - m);
      den += wgt * lpart[((long)bh * 4 + c) * NS + s];
      o   += wgt * opart[(((long)bh * 4 + c) * NS + s) * 256 + d];
    }
    o_buf[(long)blk * 2048 + h * 256 + d] = bf1(o / den);
  }
}

// ---------------------------------------------------------------------------
// gated GEMM (2-phase, swizzled LDS, XCD-swizzled grid (7,128)):
// B = wguT interleaved [8192][1024]. out = gelu(g)*u, bf16 [M][4096].
// ---------------------------------------------------------------------------
__global__ __launch_bounds__(256) void gemm64G(
    const ushort_t* __restrict__ A, const ushort_t* __restrict__ B,
    ushort_t* __restrict__ C, int M, int K, int lda, int ldb, int ldc) {
  const int flat = blockIdx.x + 7 * blockIdx.y;      // 0..895
  const int wgid = (flat & 7) * 112 + (flat >> 3);
  const int m0 = (wgid % 7) * 64;
  const int n0 = (wgid / 7) * 64;
  const int tid = threadIdx.x;
  const int lane = tid & 63;
  const int wbase = tid & 192;
  const int wid = wbase >> 6;
  const int l15 = lane & 15;
  const int l4  = lane >> 4;

  __shared__ ushort_t As[2][64 * 64];
  __shared__ ushort_t Bs[2][64 * 64];

  f32x4 acc[4] = {};

  const int ci0 = wbase + lane;
  const int row0 = ci0 >> 3;
  const int kc0 = (((ci0 & 7) ^ (row0 & 7)) << 3);
  const int ci1 = 256 + ci0;
  const int row1 = ci1 >> 3;
  const int kc1 = (((ci1 & 7) ^ (row1 & 7)) << 3);
  int gra0 = m0 + row0; if (gra0 > M - 1) gra0 = M - 1;
  int gra1 = m0 + row1; if (gra1 > M - 1) gra1 = M - 1;

  auto stage = [&](int buf, int k0) {
    async_cp16(A + (long)gra0 * lda + k0 + kc0, (const char*)As[buf] + ci0 * 16);
    async_cp16(B + (long)(n0 + row0) * ldb + k0 + kc0, (const char*)Bs[buf] + ci0 * 16);
    async_cp16(A + (long)gra1 * lda + k0 + kc1, (const char*)As[buf] + ci1 * 16);
    async_cp16(B + (long)(n0 + row1) * ldb + k0 + kc1, (const char*)Bs[buf] + ci1 * 16);
  };

  const int nt = K >> 6;
  stage(0, 0);
  __syncthreads();
  int cur = 0;
  for (int t = 0; t < nt; ++t) {
    if (t + 1 < nt) stage(cur ^ 1, (t + 1) * 64);
    const ushort_t* Ac = As[cur];
    const ushort_t* Bc = Bs[cur];
#pragma unroll
    for (int ks = 0; ks < 2; ++ks) {
      int arow = wid * 16 + l15;
      short8 af = *reinterpret_cast<const short8*>(&Ac[arow * 64 + SWZ(arow, ks * 32 + l4 * 8)]);
#pragma unroll
      for (int ni = 0; ni < 4; ++ni) {
        int row = ni * 16 + l15;
        short8 bf = *reinterpret_cast<const short8*>(&Bc[row * 64 + SWZ(row, ks * 32 + l4 * 8)]);
        acc[ni] = __builtin_amdgcn_mfma_f32_16x16x32_bf16(af, bf, acc[ni], 0, 0, 0);
      }
    }
    __syncthreads();
    cur ^= 1;
  }

#pragma unroll
  for (int ni = 0; ni < 2; ++ni) {
    int col = (n0 >> 1) + ni * 16 + l15;
    int rb  = m0 + wid * 16 + l4 * 4;
#pragma unroll
    for (int r = 0; r < 4; ++r) {
      int row = rb + r;
      if (row >= M) continue;
      float g = acc[ni][r];
      float u = acc[ni + 2][r];
      float inner = 0.7978845608028654f * (g + 0.044715f * g * g * g);
      // gelu_tanh(g) = g * sigmoid(2*inner)  (exact identity)
      float t = g / (1.f + __expf(-2.f * inner));
      C[(long)row * ldc + col] = bf1(t * u);
    }
  }
}

// ---------------------------------------------------------------------------
// f32-input GEMM (cond path, M=8). EPI: 1=+bias 2=silu(acc+bias)
// ---------------------------------------------------------------------------
template<int EPI>
__global__ __launch_bounds__(256)
void gemm_f32_kernel(const float* __restrict__ A,
                     const float* __restrict__ B1,
                     float* __restrict__ C,
                     int M, int N, int K, int lda, int ldb, int ldc,
                     const float* __restrict__ bias) {
  const int m0 = blockIdx.x * 64;
  const int n0 = blockIdx.y * 64;
  const int tid = threadIdx.x;
  const int lane = tid & 63;
  const int wid = tid >> 6;
  const int wm = (wid >> 1) * 32;
  const int wn = (wid & 1) * 32;
  const int l15 = lane & 15;
  const int l4  = lane >> 4;

  __shared__ __align__(16) ushort_t As[64][72];
  __shared__ __align__(16) ushort_t Bs[64][72];

  f32x4 acc[2][2] = {};

  for (int k0 = 0; k0 < K; k0 += 64) {
#pragma unroll
    for (int pass = 0; pass < 2; ++pass) {
      int c = tid + pass * 256;
      int row = c >> 3;
      int kc = (c & 7) * 8;
      int gr = m0 + row, gk = k0 + kc;
      float v[8];
#pragma unroll
      for (int j = 0; j < 8; ++j)
        v[j] = (gr < M && gk + j < K) ? A[(long)gr * lda + gk + j] : 0.f;
      *reinterpret_cast<uint4*>(&As[row][kc]) =
          make_uint4(pack_bf2(v[0],v[1]), pack_bf2(v[2],v[3]),
                     pack_bf2(v[4],v[5]), pack_bf2(v[6],v[7]));
    }
    {
      int n = tid & 63;
      int kg = tid >> 6;
      int gn = n0 + n;
      u32 pk[8];
#pragma unroll
      for (int kk = 0; kk < 16; kk += 2) {
        int kga = k0 + kg * 16 + kk;
        float v0 = (gn < N && kga < K)     ? B1[(long)kga * ldb + gn] : 0.f;
        float v1 = (gn < N && kga + 1 < K) ? B1[(long)(kga + 1) * ldb + gn] : 0.f;
        pk[kk >> 1] = pack_bf2(v0, v1);
      }
      *reinterpret_cast<uint4*>(&Bs[n][kg * 16])     = make_uint4(pk[0],pk[1],pk[2],pk[3]);
      *reinterpret_cast<uint4*>(&Bs[n][kg * 16 + 8]) = make_uint4(pk[4],pk[5],pk[6],pk[7]);
    }
    __syncthreads();
#pragma unroll
    for (int ks = 0; ks < 2; ++ks) {
      short8 af[2], bfr[2];
#pragma unroll
      for (int mi = 0; mi < 2; ++mi)
        af[mi] = *reinterpret_cast<const short8*>(&As[wm + mi*16 + l15][ks*32 + l4*8]);
#pragma unroll
      for (int ni = 0; ni < 2; ++ni)
        bfr[ni] = *reinterpret_cast<const short8*>(&Bs[wn + ni*16 + l15][ks*32 + l4*8]);
#pragma unroll
      for (int mi = 0; mi < 2; ++mi)
#pragma unroll
        for (int ni = 0; ni < 2; ++ni)
          acc[mi][ni] = __builtin_amdgcn_mfma_f32_16x16x32_bf16(af[mi], bfr[ni], acc[mi][ni], 0, 0, 0);
    }
    __syncthreads();
  }

#pragma unroll
  for (int mi = 0; mi < 2; ++mi) {
#pragma unroll
    for (int ni = 0; ni < 2; ++ni) {
      int col = n0 + wn + ni * 16 + l15;
      int rb  = m0 + wm + mi * 16 + l4 * 4;
#pragma unroll
      for (int r = 0; r < 4; ++r) {
        int row = rb + r;
        if (row < M && col < N) {
          float v = acc[mi][ni][r];
          if (EPI == 1) C[(long)row * ldc + col] = v + bias[col];
          else {
            float t = v + bias[col];
            C[(long)row * ldc + col] = t / (1.f + __expf(-t));
          }
        }
      }
    }
  }
}

// f32-input GEMM with layer batching + split-K, atomicAdd (ada path, M=8)
__global__ __launch_bounds__(256)
void gemm_f32sk(const float* __restrict__ A,
                const float* __restrict__ B, long bz,
                float* __restrict__ C, long cz,
                int M, int N, int K, int lda, int ldb, int ldc, int nks) {
  const int zz = blockIdx.z;
  const int layer = zz / nks;
  const int chunk = zz % nks;
  const int kpb = K / nks;
  const int kbeg = chunk * kpb, kend = kbeg + kpb;
  const float* Bb = B + (long)layer * bz;
  float* Cb = C + (long)layer * cz;

  const int m0 = blockIdx.x * 64;
  const int n0 = blockIdx.y * 64;
  const int tid = threadIdx.x;
  const int lane = tid & 63;
  const int wid = tid >> 6;
  const int wm = (wid >> 1) * 32;
  const int wn = (wid & 1) * 32;
  const int l15 = lane & 15;
  const int l4  = lane >> 4;

  __shared__ __align__(16) ushort_t As[64][72];
  __shared__ __align__(16) ushort_t Bs[64][72];

  f32x4 acc[2][2] = {};

  for (int k0 = kbeg; k0 < kend; k0 += 64) {
#pragma unroll
    for (int pass = 0; pass < 2; ++pass) {
      int c = tid + pass * 256;
      int row = c >> 3;
      int kc = (c & 7) * 8;
      int gr = m0 + row, gk = k0 + kc;
      float v[8];
#pragma unroll
      for (int j = 0; j < 8; ++j)
        v[j] = (gr < M) ? A[(long)gr * lda + gk + j] : 0.f;
      *reinterpret_cast<uint4*>(&As[row][kc]) =
          make_uint4(pack_bf2(v[0],v[1]), pack_bf2(v[2],v[3]),
                     pack_bf2(v[4],v[5]), pack_bf2(v[6],v[7]));
    }
    {
      int n = tid & 63;
      int kg = tid >> 6;
      int gn = n0 + n;
      u32 pk[8];
#pragma unroll
      for (int kk = 0; kk < 16; kk += 2) {
        int kga = k0 + kg * 16 + kk;
        float v0 = Bb[(long)kga * ldb + gn];
        float v1 = Bb[(long)(kga + 1) * ldb + gn];
        pk[kk >> 1] = pack_bf2(v0, v1);
      }
      *reinterpret_cast<uint4*>(&Bs[n][kg * 16])     = make_uint4(pk[0],pk[1],pk[2],pk[3]);
      *reinterpret_cast<uint4*>(&Bs[n][kg * 16 + 8]) = make_uint4(pk[4],pk[5],pk[6],pk[7]);
    }
    __syncthreads();
#pragma unroll
    for (int ks = 0; ks < 2; ++ks) {
      short8 af[2], bfr[2];
#pragma unroll
      for (int mi = 0; mi < 2; ++mi)
        af[mi] = *reinterpret_cast<const short8*>(&As[wm + mi*16 + l15][ks*32 + l4*8]);
#pragma unroll
      for (int ni = 0; ni < 2; ++ni)
        bfr[ni] = *reinterpret_cast<const short8*>(&Bs[wn + ni*16 + l15][ks*32 + l4*8]);
#pragma unroll
      for (int mi = 0; mi < 2; ++mi)
#pragma unroll
        for (int ni = 0; ni < 2; ++ni)
          acc[mi][ni] = __builtin_amdgcn_mfma_f32_16x16x32_bf16(af[mi], bfr[ni], acc[mi][ni], 0, 0, 0);
    }
    __syncthreads();
  }

#pragma unroll
  for (int mi = 0; mi < 2; ++mi) {
#pragma unroll
    for (int ni = 0; ni < 2; ++ni) {
      int col = n0 + wn + ni * 16 + l15;
      int rb  = m0 + wm + mi * 16 + l4 * 4;
#pragma unroll
      for (int r = 0; r < 4; ++r) {
        int row = rb + r;
        if (row < M && col < N)
          atomicAdd(&Cb[(long)row * ldc + col], acc[mi][ni][r]);
      }
    }
  }
}

// ---------------------------------------------------------------------------
extern "C" void kernel_launch(void* const* d_in, const int* in_sizes, int n_in,
                              void* d_out, int out_size, void* d_ws, size_t ws_size,
                              hipStream_t stream) {
  (void)in_sizes; (void)n_in; (void)out_size; (void)ws_size;
  const float* x_t      = (const float*)d_in[1];
  const float* tstep    = (const float*)d_in[2];
  const float* dtp      = (const float*)d_in[3];
  const float* cache_k  = (const float*)d_in[4];
  const float* cache_v  = (const float*)d_in[5];
  const float* w_act_in = (const float*)d_in[6];
  const float* b_act_in = (const float*)d_in[7];
  const float* w_t1     = (const float*)d_in[8];
  const float* b_t1     = (const float*)d_in[9];
  const float* w_t2     = (const float*)d_in[10];
  const float* b_t2     = (const float*)d_in[11];
  const float* ln1_w    = (const float*)d_in[12];
  const float* ada1_w   = (const float*)d_in[13];
  const float* ln2_w    = (const float*)d_in[14];
  const float* wq       = (const float*)d_in[15];
  const float* wk       = (const float*)d_in[16];
  const float* wv       = (const float*)d_in[17];
  const float* wo       = (const float*)d_in[18];
  const float* wg       = (const float*)d_in[19];
  const float* wu       = (const float*)d_in[20];
  const float* wd       = (const float*)d_in[21];
  const float* lnf_w    = (const float*)d_in[22];
  const float* adaf_w   = (const float*)d_in[23];
  const float* wao      = (const float*)d_in[24];
  const float* bao      = (const float*)d_in[25];
  float* outp = (float*)d_out;

  char* p = (char*)d_ws;
  auto alloc = [&](size_t bytes) { char* r = p; p += (bytes + 255) & ~(size_t)255; return r; };

  ushort_t* wqkvT  = (ushort_t*)alloc((size_t)12 * 2560 * 1024 * 2);
  ushort_t* woT    = (ushort_t*)alloc((size_t)12 * 1024 * 2048 * 2);
  ushort_t* wguT   = (ushort_t*)alloc((size_t)12 * 8192 * 1024 * 2);
  ushort_t* wdT    = (ushort_t*)alloc((size_t)12 * 1024 * 4096 * 2);
  ushort_t* kcache = (ushort_t*)alloc((size_t)12 * 8 * NP * 256 * 2);
  ushort_t* vT     = (ushort_t*)alloc((size_t)12 * 8 * 256 * KPAD * 2);
  ushort_t* qT     = (ushort_t*)alloc((size_t)64 * NS * 256 * 2);
  ushort_t* k_new  = (ushort_t*)alloc((size_t)400 * 256 * 2);
  float*    opart  = (float*)alloc((size_t)64 * 4 * NS * 256 * 4);
  float*    mpart  = (float*)alloc((size_t)64 * 4 * NS * 4);
  float*    lpart  = (float*)alloc((size_t)64 * 4 * NS * 4);
  float*    woP    = (float*)alloc((size_t)4 * 400 * 1024 * 4);   // wo split-K slabs
  float*    wdP    = (float*)alloc((size_t)4 * 400 * 1024 * 4);   // wd split-K slabs
  ushort_t* o_buf  = (ushort_t*)alloc((size_t)400 * 2048 * 2);
  ushort_t* t_buf  = (ushort_t*)alloc((size_t)400 * 4096 * 2);
  ushort_t* x_buf  = (ushort_t*)alloc((size_t)400 * 1024 * 2);
  float*    h_buf  = (float*)alloc((size_t)400 * 1024 * 4);
  float*    temb   = (float*)alloc(8 * 1024 * 4);
  float*    tmp    = (float*)alloc(8 * 1024 * 4);
  float*    cond   = (float*)alloc(8 * 1024 * 4);
  float*    ada_all= (float*)alloc((size_t)12 * 8 * 1024 * 4);   // zeroed
  float*    adaf_o = (float*)alloc(8 * 1024 * 4);                // zeroed (adjacent)
  float*    cosT   = (float*)alloc(NS * 128 * 4);
  float*    sinT   = (float*)alloc(NS * 128 * 4);
  ushort_t* zpad   = (ushort_t*)alloc(512 * 2);

  hipMemsetAsync(zpad, 0, 512 * 2, stream);
  hipMemsetAsync(ada_all, 0, ((size_t)12 * 8 * 1024 + 8 * 1024) * 4, stream);

  // ---- conversion pass ----
  cvt_permute_kernel<<<9600, 256, 0, stream>>>(cache_k, kcache, (long)12 * 8 * NP);
  transpose_cvt<2><<<dim3(32, 16, 12), 256, 0, stream>>>(wq, (long)1024 * 2048, wqkvT, (long)2560 * 1024, 1024, 2048, 1024, 0);
  transpose_cvt<2><<<dim3(4, 16, 12), 256, 0, stream>>>(wk, (long)1024 * 256, wqkvT + (long)2048 * 1024, (long)2560 * 1024, 1024, 256, 1024, 0);
  transpose_cvt<0><<<dim3(4, 16, 12), 256, 0, stream>>>(wv, (long)1024 * 256, wqkvT + (long)2304 * 1024, (long)2560 * 1024, 1024, 256, 1024, 0);
  transpose_cvt<0><<<dim3(16, 32, 12), 256, 0, stream>>>(wo, (long)2048 * 1024, woT, (long)1024 * 2048, 2048, 1024, 2048, 0);
  transpose_cvt<1><<<dim3(64, 16, 12), 256, 0, stream>>>(wg, (long)1024 * 4096, wguT, (long)8192 * 1024, 1024, 4096, 1024, 0);
  transpose_cvt<1><<<dim3(64, 16, 12), 256, 0, stream>>>(wu, (long)1024 * 4096, wguT, (long)8192 * 1024, 1024, 4096, 1024, 32);
  transpose_cvt<0><<<dim3(16, 64, 12), 256, 0, stream>>>(wd, (long)4096 * 1024, wdT, (long)1024 * 4096, 4096, 1024, 4096, 0);
  transpose_cvt<0><<<dim3(4, 13, 96), 256, 0, stream>>>(cache_v, (long)NP * 256, vT, (long)256 * KPAD, NP, 256, KPAD, 0);

  // ---- embed + cond ----
  temb_kernel<<<32, 256, 0, stream>>>(tstep, temb);
  suffix_kernel<<<400, 256, 0, stream>>>(x_t, w_act_in, b_act_in, h_buf);
  rope_table_kernel<<<25, 256, 0, stream>>>(cosT, sinT);
  gemm_f32_kernel<2><<<dim3(1, 16, 1), 256, 0, stream>>>(temb, w_t1, tmp, NB, ND, ND, ND, ND, ND, b_t1);
  gemm_f32_kernel<1><<<dim3(1, 16, 1), 256, 0, stream>>>(tmp, w_t2, cond, NB, ND, ND, ND, ND, ND, b_t2);
  gemm_f32sk<<<dim3(1, 16, 48), 256, 0, stream>>>(cond, ada1_w, (long)ND * ND, ada_all, (long)NB * ND, NB, ND, ND, ND, ND, ND, 4);
  gemm_f32sk<<<dim3(1, 16, 4), 256, 0, stream>>>(cond, adaf_w, 0, adaf_o, 0, NB, ND, ND, ND, ND, ND, 4);

  for (int l = 0; l < NLAYER; ++l) {
    ushort_t* vT_l = vT + (long)l * 8 * 256 * KPAD;
    // rms1: complete previous layer's mlp residual (wd slabs), then rms*ada
    rms_kernel<true><<<400, 256, 0, stream>>>(
        h_buf, l == 0 ? nullptr : wdP, ln1_w + (long)l * ND, ada_all + (long)l * NB * ND, x_buf);
    // qkv + fused rope scatter (280 blocks, XCD-swizzled)
    gemm64rope<<<dim3(7, 40, 1), 256, 0, stream>>>(
        x_buf, wqkvT + (long)l * 2560 * 1024, cosT, sinT, qT, k_new, vT_l);
    // flash2 attention partials (256 blocks, XCD-swizzled)
    flash2_kernel<<<dim3(64, 4, 1), 256, 0, stream>>>(
        qT, kcache + (long)l * 8 * NP * 256, k_new, vT_l, zpad, opart, mpart, lpart);
    att_combine<<<400, 256, 0, stream>>>(opart, mpart, lpart, o_buf);
    // wo: split-K 4 slab writes (448 blocks, XCD-swizzled)
    gemm64slab<<<dim3(7, 16, 4), 256, 0, stream>>>(
        o_buf, woT + (long)l * 1024 * 2048, woP, 400, 1024, 2048, 2048, 2048, 1024, 512);
    // rms2: h += sum(woP); rms
    rms_kernel<true><<<400, 256, 0, stream>>>(
        h_buf, woP, ln2_w + (long)l * ND, nullptr, x_buf);
    // t = gelu(x@wg)*(x@wu)  fused  (896 blocks, XCD-swizzled)
    gemm64G<<<dim3(7, 128, 1), 256, 0, stream>>>(
        x_buf, wguT + (long)l * 8192 * 1024, t_buf, 400, 1024, 1024, 1024, 4096);
    // wd: split-K 4 slab writes (448 blocks, XCD-swizzled)
    gemm64slab<<<dim3(7, 16, 4), 256, 0, stream>>>(
        t_buf, wdT + (long)l * 1024 * 4096, wdP, 400, 1024, 4096, 4096, 4096, 1024, 1024);
  }

  final_fused<<<400, 256, 0, stream>>>(h_buf, wdP, lnf_w, adaf_o, wao, bao, x_t, dtp, outp);
}

// Round 10
// 1768.450 us; speedup vs baseline: 1.2234x; 1.0239x over previous
//
#include <hip/hip_runtime.h>
#include <hip/hip_bf16.h>
#include <math.h>

#define NLAYER 12
#define NB 8
#define NP 800
#define ND 1024
#define NH 8
#define NDH 256
#define NM 4096
#define NS 50
#define NA 32
#define NKEYS 850
#define KPAD 896      // padded key count (7 chunks of 128)
#define NCH 7         // flash chunks

typedef unsigned short ushort_t;
typedef unsigned int u32;
using f32x4  = __attribute__((ext_vector_type(4))) float;
using short8 = __attribute__((ext_vector_type(8))) short;

__device__ __forceinline__ u32 pack_bf2(float lo, float hi) {
  u32 a = __float_as_uint(lo);
  u32 b = __float_as_uint(hi);
  a += 0x7fffu + ((a >> 16) & 1u);
  b += 0x7fffu + ((b >> 16) & 1u);
  return (a >> 16) | (b & 0xffff0000u);
}
__device__ __forceinline__ ushort_t bf1(float x) {
  u32 a = __float_as_uint(x);
  a += 0x7fffu + ((a >> 16) & 1u);
  return (ushort_t)(a >> 16);
}
__device__ __forceinline__ float ubf(ushort_t h) {
  return __uint_as_float(((u32)h) << 16);
}
__device__ __forceinline__ void async_cp16(const void* g, const void* l) {
  __builtin_amdgcn_global_load_lds(
      (const __attribute__((address_space(1))) u32*)g,
      (__attribute__((address_space(3))) u32*)l, 16, 0, 0);
}
// swizzled column index (ushort units) for 64-ushort LDS rows:
// element (row, c) lives at row*64 + (c ^ ((row&7)<<3))
#define SWZ(row, c) ((c) ^ (((row) & 7) << 3))

// ---------------------------------------------------------------------------
// conversion kernels
// ---------------------------------------------------------------------------

// kcache: f32 [rows][256] -> bf16 [rows][256] with d-permute j = 2*(d&127)+(d>>7)
__global__ void cvt_permute_kernel(const float* __restrict__ src, ushort_t* __restrict__ dst, long nrows) {
  long idx = (long)blockIdx.x * 256 + threadIdx.x;
  long row = idx >> 5;
  int t = (int)(idx & 31);
  if (row >= nrows) return;
  const float* s = src + row * 256 + t * 4;
  float4 lo = *reinterpret_cast<const float4*>(s);
  float4 hi = *reinterpret_cast<const float4*>(s + 128);
  ushort_t* d = dst + row * 256 + t * 8;
  *reinterpret_cast<uint4*>(d) =
      make_uint4(pack_bf2(lo.x, hi.x), pack_bf2(lo.y, hi.y),
                 pack_bf2(lo.z, hi.z), pack_bf2(lo.w, hi.w));
}

// tiled transpose + cvt: src f32 [z][R][C] -> dst bf16, dst_row = map(src col)
// MODE 0: row = c
// MODE 1 (g/u interleave): row = (c>>5)*64 + (c&31) + halfOff
// MODE 2 (rope pair-interleave per 256-head): row = (c&~255) + 2*(c&127) + ((c>>7)&1)
template<int MODE>
__global__ __launch_bounds__(256) void transpose_cvt(
    const float* __restrict__ src, long sz, ushort_t* __restrict__ dst, long dz,
    int R, int C, int ldd, int halfOff) {
  __shared__ float Ls[64][65];
  const float* s = src + (long)blockIdx.z * sz;
  ushort_t* d    = dst + (long)blockIdx.z * dz;
  int c0 = blockIdx.x * 64, r0 = blockIdx.y * 64;
  int t = threadIdx.x;
  int rr = t >> 4;
  int cc = (t & 15) * 4;
#pragma unroll
  for (int j = 0; j < 4; ++j) {
    int rl = rr + j * 16;
    int r = r0 + rl;
    float4 v = make_float4(0.f, 0.f, 0.f, 0.f);
    if (r < R) v = *reinterpret_cast<const float4*>(s + (long)r * C + c0 + cc);
    Ls[rl][cc] = v.x; Ls[rl][cc+1] = v.y; Ls[rl][cc+2] = v.z; Ls[rl][cc+3] = v.w;
  }
  __syncthreads();
  int dr = t >> 2;
  int rc = (t & 3) * 16;
  int cg = c0 + dr;
  long orow;
  if (MODE == 0)      orow = cg;
  else if (MODE == 1) orow = ((long)(cg >> 5) << 6) + (cg & 31) + halfOff;
  else                orow = (long)(cg & ~255) + ((cg & 127) << 1) + ((cg >> 7) & 1);
  ushort_t* drow = d + orow * ldd + r0 + rc;
#pragma unroll
  for (int i = 0; i < 16; i += 2) {
    int sr = r0 + rc + i;
    if (sr < R) {
      u32 p = pack_bf2(Ls[rc + i][dr], Ls[rc + i + 1][dr]);
      *reinterpret_cast<u32*>(drow + i) = p;
    }
  }
}

// ---------------------------------------------------------------------------
// small kernels
// ---------------------------------------------------------------------------

__global__ void temb_kernel(const float* __restrict__ ts, float* __restrict__ temb) {
  int idx = blockIdx.x * 256 + threadIdx.x;
  if (idx >= NB * ND) return;
  int b = idx >> 10, d = idx & 1023;
  int i = d & 511;
  float f = __expf(-logf(10000.f) * (float)i / 512.f);
  float ang = ts[b] * f;
  temb[idx] = (d < 512) ? sinf(ang) : cosf(ang);
}

__global__ void suffix_kernel(const float* __restrict__ x_t, const float* __restrict__ w,
                              const float* __restrict__ bias, float* __restrict__ h) {
  int m = blockIdx.x;
  __shared__ float xs[NA];
  if (threadIdx.x < NA) xs[threadIdx.x] = x_t[m * NA + threadIdx.x];
  __syncthreads();
  for (int n = threadIdx.x; n < ND; n += 256) {
    float acc = bias[n];
#pragma unroll
    for (int k = 0; k < NA; ++k) acc += xs[k] * w[k * ND + n];
    h[m * ND + n] = acc * 32.0f;
  }
}

__global__ void rope_table_kernel(float* __restrict__ cosT, float* __restrict__ sinT) {
  int idx = blockIdx.x * 256 + threadIdx.x;
  if (idx >= NS * 128) return;
  int s = idx >> 7, i = idx & 127;
  float inv = __expf(-(float)(2 * i) / 256.f * logf(10000.f));
  float ang = (float)(NP + s) * inv;
  cosT[idx] = cosf(ang);
  sinT[idx] = sinf(ang);
}

// rms with optional 8-slab residual completion: h += sum(slabs); out = rms(h)*(1+w)[*(1+ada)]
template<bool BFOUT>
__global__ void rms_kernel(float* __restrict__ hin, const float* __restrict__ slabs,
                           const float* __restrict__ w,
                           const float* __restrict__ ada, void* __restrict__ outv) {
  int m = blockIdx.x;
  int b = m / NS;
  int d0 = threadIdx.x * 4;
  float4 v = *reinterpret_cast<const float4*>(hin + (long)m * ND + d0);
  if (slabs) {
#pragma unroll
    for (int c = 0; c < 8; ++c) {
      float4 sv = *reinterpret_cast<const float4*>(slabs + ((long)c * 400 + m) * ND + d0);
      v.x += sv.x; v.y += sv.y; v.z += sv.z; v.w += sv.w;
    }
    *reinterpret_cast<float4*>(hin + (long)m * ND + d0) = v;
  }
  float ss = v.x*v.x + v.y*v.y + v.z*v.z + v.w*v.w;
#pragma unroll
  for (int off = 32; off > 0; off >>= 1) ss += __shfl_down(ss, off);
  __shared__ float red[4];
  int lane = threadIdx.x & 63, wid = threadIdx.x >> 6;
  if (lane == 0) red[wid] = ss;
  __syncthreads();
  float tot = red[0] + red[1] + red[2] + red[3];
  float r = rsqrtf(tot * (1.f / ND) + 1e-6f);
  float4 wv = *reinterpret_cast<const float4*>(w + d0);
  float4 o;
  o.x = v.x * r * (1.f + wv.x);
  o.y = v.y * r * (1.f + wv.y);
  o.z = v.z * r * (1.f + wv.z);
  o.w = v.w * r * (1.f + wv.w);
  if (ada) {
    float4 av = *reinterpret_cast<const float4*>(ada + (long)b * ND + d0);
    o.x *= (1.f + av.x); o.y *= (1.f + av.y); o.z *= (1.f + av.z); o.w *= (1.f + av.w);
  }
  if (BFOUT) {
    *reinterpret_cast<uint2*>((ushort_t*)outv + (long)m * ND + d0) =
        make_uint2(pack_bf2(o.x, o.y), pack_bf2(o.z, o.w));
  } else {
    *reinterpret_cast<float4*>((float*)outv + (long)m * ND + d0) = o;
  }
}

// fused final: h += sum(8 wd slabs); rms; out projection; euler step
__global__ void final_fused(const float* __restrict__ hin, const float* __restrict__ slabs,
                            const float* __restrict__ lnf,
                            const float* __restrict__ adaf, const float* __restrict__ w,
                            const float* __restrict__ bias, const float* __restrict__ x_t,
                            const float* __restrict__ dt, float* __restrict__ out) {
  int m = blockIdx.x;
  int b = m / NS;
  int d0 = threadIdx.x * 4;
  __shared__ float hfs[ND];
  __shared__ float red[256];
  float4 v = *reinterpret_cast<const float4*>(hin + (long)m * ND + d0);
#pragma unroll
  for (int c = 0; c < 8; ++c) {
    float4 sv = *reinterpret_cast<const float4*>(slabs + ((long)c * 400 + m) * ND + d0);
    v.x += sv.x; v.y += sv.y; v.z += sv.z; v.w += sv.w;
  }
  float ss = v.x*v.x + v.y*v.y + v.z*v.z + v.w*v.w;
#pragma unroll
  for (int off = 32; off > 0; off >>= 1) ss += __shfl_down(ss, off);
  __shared__ float red4[4];
  int lane = threadIdx.x & 63, wid = threadIdx.x >> 6;
  if (lane == 0) red4[wid] = ss;
  __syncthreads();
  float tot = red4[0] + red4[1] + red4[2] + red4[3];
  float r = rsqrtf(tot * (1.f / ND) + 1e-6f);
  float4 wv = *reinterpret_cast<const float4*>(lnf + d0);
  float4 av = *reinterpret_cast<const float4*>(adaf + (long)b * ND + d0);
  hfs[d0]     = v.x * r * (1.f + wv.x) * (1.f + av.x);
  hfs[d0 + 1] = v.y * r * (1.f + wv.y) * (1.f + av.y);
  hfs[d0 + 2] = v.z * r * (1.f + wv.z) * (1.f + av.z);
  hfs[d0 + 3] = v.w * r * (1.f + wv.w) * (1.f + av.w);
  __syncthreads();
  int a = threadIdx.x & 31;
  int kg = threadIdx.x >> 5;
  float acc = 0.f;
  for (int k = kg; k < ND; k += 8) acc += hfs[k] * w[k * NA + a];
  red[threadIdx.x] = acc;
  __syncthreads();
  if (threadIdx.x < NA) {
    float s = 0.f;
#pragma unroll
    for (int g = 0; g < 8; ++g) s += red[g * 32 + a];
    out[m * NA + a] = x_t[m * NA + a] + dt[0] * (s + bias[a]);
  }
}

// ---------------------------------------------------------------------------
// 64x64 GEMM (2-phase dbuf, swizzled LDS), split-K-8 f32 slab epilogue.
// Grid MUST be (7,16,8); XCD-swizzled so same-B-panel blocks share an XCD.
// ---------------------------------------------------------------------------
__global__ __launch_bounds__(256) void gemm64slab(
    const ushort_t* __restrict__ A,
    const ushort_t* __restrict__ B,
    float* __restrict__ C,             // [8][400][ldc] slabs
    int M, int N, int K, int lda, int ldb, int ldc, int kpb) {
  const int flat3 = blockIdx.x + 7 * (blockIdx.y + 16 * blockIdx.z);   // 0..895
  const int wgid = (flat3 & 7) * 112 + (flat3 >> 3);
  const int chunk = wgid / 112;
  const int rem = wgid - chunk * 112;
  const int m0 = (rem % 7) * 64;
  const int n0 = (rem / 7) * 64;
  const int kbeg = chunk * kpb;
  const int kend = kbeg + kpb;

  const int tid = threadIdx.x;
  const int lane = tid & 63;
  const int wbase = tid & 192;
  const int wid = wbase >> 6;
  const int wm = (wid >> 1) * 32;
  const int wn = (wid & 1) * 32;
  const int l15 = lane & 15;
  const int l4  = lane >> 4;

  __shared__ ushort_t As[2][64 * 64];
  __shared__ ushort_t Bs[2][64 * 64];

  f32x4 acc[2][2] = {};

  const int ci0 = wbase + lane;
  const int row0 = ci0 >> 3;
  const int kc0 = (((ci0 & 7) ^ (row0 & 7)) << 3);   // inverse-swizzled source slot
  const int ci1 = 256 + ci0;
  const int row1 = ci1 >> 3;
  const int kc1 = (((ci1 & 7) ^ (row1 & 7)) << 3);
  int gra0 = m0 + row0; if (gra0 > M - 1) gra0 = M - 1;
  int gra1 = m0 + row1; if (gra1 > M - 1) gra1 = M - 1;
  const int n_0 = n0 + row0;
  const int n_1 = n0 + row1;

  auto stage = [&](int buf, int k0) {
    async_cp16(A + (long)gra0 * lda + k0 + kc0, (const char*)As[buf] + ci0 * 16);
    async_cp16(B + (long)n_0 * ldb + k0 + kc0, (const char*)Bs[buf] + ci0 * 16);
    async_cp16(A + (long)gra1 * lda + k0 + kc1, (const char*)As[buf] + ci1 * 16);
    async_cp16(B + (long)n_1 * ldb + k0 + kc1, (const char*)Bs[buf] + ci1 * 16);
  };

  const int nt = (kend - kbeg) >> 6;
  stage(0, kbeg);
  __syncthreads();
  int cur = 0;
  for (int t = 0; t < nt; ++t) {
    if (t + 1 < nt) stage(cur ^ 1, kbeg + (t + 1) * 64);
    const ushort_t* Ac = As[cur];
    const ushort_t* Bc = Bs[cur];
#pragma unroll
    for (int ks = 0; ks < 2; ++ks) {
      short8 af[2], bf[2];
#pragma unroll
      for (int mi = 0; mi < 2; ++mi) {
        int row = wm + mi * 16 + l15;
        af[mi] = *reinterpret_cast<const short8*>(&Ac[row * 64 + SWZ(row, ks * 32 + l4 * 8)]);
      }
#pragma unroll
      for (int ni = 0; ni < 2; ++ni) {
        int row = wn + ni * 16 + l15;
        bf[ni] = *reinterpret_cast<const short8*>(&Bc[row * 64 + SWZ(row, ks * 32 + l4 * 8)]);
      }
#pragma unroll
      for (int mi = 0; mi < 2; ++mi)
#pragma unroll
        for (int ni = 0; ni < 2; ++ni)
          acc[mi][ni] = __builtin_amdgcn_mfma_f32_16x16x32_bf16(af[mi], bf[ni], acc[mi][ni], 0, 0, 0);
    }
    __syncthreads();
    cur ^= 1;
  }

  float* Cs = C + (long)chunk * 400 * ldc;
#pragma unroll
  for (int mi = 0; mi < 2; ++mi) {
#pragma unroll
    for (int ni = 0; ni < 2; ++ni) {
      int col = n0 + wn + ni * 16 + l15;
      int rb  = m0 + wm + mi * 16 + l4 * 4;
      if (col >= N) continue;
#pragma unroll
      for (int r = 0; r < 4; ++r) {
        int row = rb + r;
        if (row >= M) continue;
        Cs[(long)row * ldc + col] = acc[mi][ni][r];
      }
    }
  }
}

// ---------------------------------------------------------------------------
// qkv GEMM with fused RoPE epilogue (swizzled LDS, XCD-swizzled grid (7,40)).
// B = wqkvT (rows pair-interleaved j-space for q/k sections; v natural).
// cols [0,2048)=q -> qT[bh][50][256]; [2048,2304)=k -> k_new; [2304,2560)=v -> vT scatter
// ---------------------------------------------------------------------------
__global__ __launch_bounds__(256) void gemm64rope(
    const ushort_t* __restrict__ A,
    const ushort_t* __restrict__ B,
    const float* __restrict__ cosT, const float* __restrict__ sinT,
    ushort_t* __restrict__ qTo, ushort_t* __restrict__ k_new,
    ushort_t* __restrict__ vT_l) {
  const int M = 400, lda = 1024, ldb = 1024;
  const int flat = blockIdx.x + 7 * blockIdx.y;          // 0..279
  const int wgid = (flat & 7) * 35 + (flat >> 3);
  const int m0 = (wgid % 7) * 64;
  const int n0 = (wgid / 7) * 64;
  const int tid = threadIdx.x;
  const int lane = tid & 63;
  const int wbase = tid & 192;
  const int wid = wbase >> 6;
  const int wm = (wid >> 1) * 32;
  const int wn = (wid & 1) * 32;
  const int l15 = lane & 15;
  const int l4  = lane >> 4;

  __shared__ ushort_t As[2][64 * 64];
  __shared__ ushort_t Bs[2][64 * 64];

  f32x4 acc[2][2] = {};

  const int ci0 = wbase + lane;
  const int row0 = ci0 >> 3;
  const int kc0 = (((ci0 & 7) ^ (row0 & 7)) << 3);
  const int ci1 = 256 + ci0;
  const int row1 = ci1 >> 3;
  const int kc1 = (((ci1 & 7) ^ (row1 & 7)) << 3);
  int gra0 = m0 + row0; if (gra0 > M - 1) gra0 = M - 1;
  int gra1 = m0 + row1; if (gra1 > M - 1) gra1 = M - 1;
  const int n_0 = n0 + row0;
  const int n_1 = n0 + row1;

  auto stage = [&](int buf, int k0) {
    async_cp16(A + (long)gra0 * lda + k0 + kc0, (const char*)As[buf] + ci0 * 16);
    async_cp16(B + (long)n_0 * ldb + k0 + kc0, (const char*)Bs[buf] + ci0 * 16);
    async_cp16(A + (long)gra1 * lda + k0 + kc1, (const char*)As[buf] + ci1 * 16);
    async_cp16(B + (long)n_1 * ldb + k0 + kc1, (const char*)Bs[buf] + ci1 * 16);
  };

  stage(0, 0);
  __syncthreads();
  int cur = 0;
  for (int t = 0; t < 16; ++t) {
    if (t + 1 < 16) stage(cur ^ 1, (t + 1) * 64);
    const ushort_t* Ac = As[cur];
    const ushort_t* Bc = Bs[cur];
#pragma unroll
    for (int ks = 0; ks < 2; ++ks) {
      short8 af[2], bf[2];
#pragma unroll
      for (int mi = 0; mi < 2; ++mi) {
        int row = wm + mi * 16 + l15;
        af[mi] = *reinterpret_cast<const short8*>(&Ac[row * 64 + SWZ(row, ks * 32 + l4 * 8)]);
      }
#pragma unroll
      for (int ni = 0; ni < 2; ++ni) {
        int row = wn + ni * 16 + l15;
        bf[ni] = *reinterpret_cast<const short8*>(&Bc[row * 64 + SWZ(row, ks * 32 + l4 * 8)]);
      }
#pragma unroll
      for (int mi = 0; mi < 2; ++mi)
#pragma unroll
        for (int ni = 0; ni < 2; ++ni)
          acc[mi][ni] = __builtin_amdgcn_mfma_f32_16x16x32_bf16(af[mi], bf[ni], acc[mi][ni], 0, 0, 0);
    }
    __syncthreads();
    cur ^= 1;
  }

#pragma unroll
  for (int mi = 0; mi < 2; ++mi) {
#pragma unroll
    for (int ni = 0; ni < 2; ++ni) {
      int col = n0 + wn + ni * 16 + l15;
      int rb  = m0 + wm + mi * 16 + l4 * 4;
      float pv[4];
#pragma unroll
      for (int r = 0; r < 4; ++r) pv[r] = __shfl_xor(acc[mi][ni][r], 1);
#pragma unroll
      for (int r = 0; r < 4; ++r) {
        int row = rb + r;
        if (row >= 400) continue;
        int b = row / NS, s = row - b * NS;
        float v = acc[mi][ni][r];
        if (col < 2304) {
          int j = col & 255;
          int i = j >> 1;
          float c = cosT[s * 128 + i], sn = sinT[s * 128 + i];
          float o = (col & 1) ? (v * c + pv[r] * sn) : (v * c - pv[r] * sn);
          if (col < 2048)
            qTo[((long)((b << 3) + (col >> 8)) * NS + s) * 256 + j] = bf1(o);
          else
            k_new[(long)row * 256 + j] = bf1(o);
        } else {
          vT_l[((long)(b * 256 + (col - 2304))) * KPAD + NP + s] = bf1(v);
        }
      }
    }
  }
}

// ---------------------------------------------------------------------------
// flash3: grid (64 bh, 7 chunks of 128 keys) XCD-swizzled, 256 threads.
// LDS 50 KB -> 3 blocks/CU. K-slices [128][64]; PV in 2 dout-halves x
// 2 key-slices of [128][64]. Q straight to registers. opart bf16.
// ---------------------------------------------------------------------------
__global__ __launch_bounds__(256) void flash3_kernel(
    const ushort_t* __restrict__ qT,
    const ushort_t* __restrict__ kcache_l,
    const ushort_t* __restrict__ k_new,
    const ushort_t* __restrict__ vT_l,
    const ushort_t* __restrict__ zpad,
    ushort_t* __restrict__ opart, float* __restrict__ mpart, float* __restrict__ lpart) {
  const int flat = blockIdx.x + 64 * blockIdx.y;     // 0..447
  const int wgid = (flat & 7) * 56 + (flat >> 3);
  const int bh = wgid & 63;
  const int ch = wgid >> 6;
  const int b  = bh >> 3;
  const int tid = threadIdx.x;
  const int lane = tid & 63;
  const int w = tid >> 6;
  const int wm = (w >> 1) * 32;      // q-row base of this wave
  const int wnK = (w & 1) * 64;      // key base (QK^T)
  const int wnV = (w & 1) * 64;      // dout base within a 128-half (PV)
  const int l15 = lane & 15;
  const int l4  = lane >> 4;

  __shared__ __align__(16) char lds[51200];
  ushort_t* KV0 = (ushort_t*)lds;                   // 16 KB: [128][64]
  ushort_t* KV1 = (ushort_t*)(lds + 16384);         // 16 KB
  ushort_t* Ps  = (ushort_t*)(lds + 32768);         // [64][136] = 17408 B
  float* SMm = (float*)(lds + 50176);               // [2][64]
  float* SMl = (float*)(lds + 50688);               // [2][64]

  // ---- Q fragments straight to registers (rows wm..wm+31, dup rows >= 50) ----
  short8 qf[4][2][2];
  {
    const ushort_t* qbase = qT + (long)bh * NS * 256;
#pragma unroll
    for (int mi = 0; mi < 2; ++mi) {
      int row = wm + mi * 16 + l15;
      int qr = row < NS ? row : NS - 1;
      const ushort_t* qrow = qbase + (long)qr * 256;
#pragma unroll
      for (int s = 0; s < 4; ++s)
#pragma unroll
        for (int ks = 0; ks < 2; ++ks)
          qf[s][mi][ks] = *reinterpret_cast<const short8*>(qrow + s * 64 + ks * 32 + l4 * 8);
    }
  }

  // K slice stage: [128 keys][64 d] for d-slice s (inverse-swizzled source slot)
  auto stageK = [&](ushort_t* buf, int s) {
#pragma unroll
    for (int i = 0; i < 4; ++i) {
      int ci = i * 256 + tid;
      int key = ch * 128 + (ci >> 3);
      int seg = (ci ^ (ci >> 3)) & 7;
      const ushort_t* src;
      if (key < NP)         src = kcache_l + ((long)(b * NP + key)) * 256 + s * 64 + seg * 8;
      else if (key < NKEYS) src = k_new + ((long)(b * NS + key - NP)) * 256 + s * 64 + seg * 8;
      else                  src = zpad + seg * 8;
      async_cp16(src, (char*)buf + ci * 16);
    }
  };
  // V piece stage: piece p: dout half dh=p>>1, key-slice ks2=p&1 -> [128 dout][64 keys]
  auto stageV = [&](ushort_t* buf, int p) {
    int dh = p >> 1, ks2 = p & 1;
#pragma unroll
    for (int i = 0; i < 4; ++i) {
      int ci = i * 256 + tid;
      int dout = dh * 128 + (ci >> 3);
      int seg = (ci ^ (ci >> 3)) & 7;
      async_cp16(vT_l + ((long)(b * 256 + dout)) * KPAD + ch * 128 + ks2 * 64 + seg * 8,
                 (char*)buf + ci * 16);
    }
  };

  // ---- QK^T: S[64 rows][128 keys], d-loop 4 slices, double-buffered ----
  f32x4 s2[2][4] = {};
  stageK(KV0, 0);
  __syncthreads();
#pragma unroll
  for (int s = 0; s < 4; ++s) {
    ushort_t* buf = (s & 1) ? KV1 : KV0;
    ushort_t* nxt = (s & 1) ? KV0 : KV1;
    if (s < 3) stageK(nxt, s + 1);
    __builtin_amdgcn_s_setprio(1);
#pragma unroll
    for (int ks = 0; ks < 2; ++ks) {
      short8 bf[4];
#pragma unroll
      for (int ni = 0; ni < 4; ++ni) {
        int row = wnK + ni * 16 + l15;
        bf[ni] = *reinterpret_cast<const short8*>(&buf[row * 64 + SWZ(row, ks * 32 + l4 * 8)]);
      }
#pragma unroll
      for (int mi = 0; mi < 2; ++mi)
#pragma unroll
        for (int ni = 0; ni < 4; ++ni)
          s2[mi][ni] = __builtin_amdgcn_mfma_f32_16x16x32_bf16(qf[s][mi][ks], bf[ni], s2[mi][ni], 0, 0, 0);
    }
    __builtin_amdgcn_s_setprio(0);
    __syncthreads();
  }

  // V piece 0 loads fly under the softmax
  stageV(KV0, 0);

  // ---- softmax over this chunk's 128 keys ----
  float mx[2][4];
#pragma unroll
  for (int mi = 0; mi < 2; ++mi)
#pragma unroll
    for (int r = 0; r < 4; ++r) mx[mi][r] = -1e30f;
#pragma unroll
  for (int mi = 0; mi < 2; ++mi)
#pragma unroll
    for (int ni = 0; ni < 4; ++ni) {
      int key = ch * 128 + wnK + ni * 16 + l15;
      bool valid = key < NKEYS;
#pragma unroll
      for (int r = 0; r < 4; ++r) {
        float v = s2[mi][ni][r] * 0.0625f;
        v = valid ? v : -1e30f;
        s2[mi][ni][r] = v;
        mx[mi][r] = fmaxf(mx[mi][r], v);
      }
    }
#pragma unroll
  for (int off = 1; off < 16; off <<= 1)
#pragma unroll
    for (int mi = 0; mi < 2; ++mi)
#pragma unroll
      for (int r = 0; r < 4; ++r)
        mx[mi][r] = fmaxf(mx[mi][r], __shfl_xor(mx[mi][r], off));
  if (l15 == 0) {
#pragma unroll
    for (int mi = 0; mi < 2; ++mi)
#pragma unroll
      for (int r = 0; r < 4; ++r)
        SMm[(w & 1) * 64 + wm + mi * 16 + l4 * 4 + r] = mx[mi][r];
  }
  __syncthreads();
  float mrow[2][4], sum[2][4];
#pragma unroll
  for (int mi = 0; mi < 2; ++mi)
#pragma unroll
    for (int r = 0; r < 4; ++r) {
      int row = wm + mi * 16 + l4 * 4 + r;
      mrow[mi][r] = fmaxf(SMm[row], SMm[64 + row]);
      sum[mi][r] = 0.f;
    }
#pragma unroll
  for (int mi = 0; mi < 2; ++mi)
#pragma unroll
    for (int ni = 0; ni < 4; ++ni) {
      int colp = wnK + ni * 16 + l15;
#pragma unroll
      for (int r = 0; r < 4; ++r) {
        float e = __expf(s2[mi][ni][r] - mrow[mi][r]);
        Ps[(wm + mi * 16 + l4 * 4 + r) * 136 + colp] = bf1(e);
        sum[mi][r] += e;
      }
    }
#pragma unroll
  for (int off = 1; off < 16; off <<= 1)
#pragma unroll
    for (int mi = 0; mi < 2; ++mi)
#pragma unroll
      for (int r = 0; r < 4; ++r)
        sum[mi][r] += __shfl_xor(sum[mi][r], off);
  if (l15 == 0) {
#pragma unroll
    for (int mi = 0; mi < 2; ++mi)
#pragma unroll
      for (int r = 0; r < 4; ++r)
        SMl[(w & 1) * 64 + wm + mi * 16 + l4 * 4 + r] = sum[mi][r];
  }
  __syncthreads();
  if ((w & 1) == 0 && l15 == 0) {
#pragma unroll
    for (int mi = 0; mi < 2; ++mi)
#pragma unroll
      for (int r = 0; r < 4; ++r) {
        int row = wm + mi * 16 + l4 * 4 + r;
        if (row < NS) {
          mpart[((long)bh * NCH + ch) * NS + row] = mrow[mi][r];
          lpart[((long)bh * NCH + ch) * NS + row] = SMl[row] + SMl[64 + row];
        }
      }
  }

  // ---- PV: O[64][256] = P[64][128] @ V[128][256], 4 pieces dbuf ----
  f32x4 o2[2][2][4] = {};   // [mi][dout half][ni]
#pragma unroll
  for (int p = 0; p < 4; ++p) {
    ushort_t* buf = (p & 1) ? KV1 : KV0;
    ushort_t* nxt = (p & 1) ? KV0 : KV1;
    if (p < 3) stageV(nxt, p + 1);
    int dh = p >> 1, ks2 = p & 1;
    __builtin_amdgcn_s_setprio(1);
#pragma unroll
    for (int ks = 0; ks < 2; ++ks) {
      short8 af[2], bf[4];
#pragma unroll
      for (int mi = 0; mi < 2; ++mi)
        af[mi] = *reinterpret_cast<const short8*>(&Ps[(wm + mi * 16 + l15) * 136 + ks2 * 64 + ks * 32 + l4 * 8]);
#pragma unroll
      for (int ni = 0; ni < 4; ++ni) {
        int row = wnV + ni * 16 + l15;
        bf[ni] = *reinterpret_cast<const short8*>(&buf[row * 64 + SWZ(row, ks * 32 + l4 * 8)]);
      }
#pragma unroll
      for (int mi = 0; mi < 2; ++mi)
#pragma unroll
        for (int ni = 0; ni < 4; ++ni)
          o2[mi][dh][ni] = __builtin_amdgcn_mfma_f32_16x16x32_bf16(af[mi], bf[ni], o2[mi][dh][ni], 0, 0, 0);
    }
    __builtin_amdgcn_s_setprio(0);
    __syncthreads();
  }

#pragma unroll
  for (int mi = 0; mi < 2; ++mi)
#pragma unroll
    for (int dh = 0; dh < 2; ++dh)
#pragma unroll
      for (int ni = 0; ni < 4; ++ni) {
        int col = dh * 128 + wnV + ni * 16 + l15;
#pragma unroll
        for (int r = 0; r < 4; ++r) {
          int row = wm + mi * 16 + l4 * 4 + r;
          if (row < NS)
            opart[(((long)bh * NCH + ch) * NS + row) * 256 + col] = bf1(o2[mi][dh][ni][r]);
        }
      }
}

// combine 7 chunk partials (bf16) -> o_buf bf16 [400][2048]
__global__ void att_combine(const ushort_t* __restrict__ opart, const float* __restrict__ mpart,
                            const float* __restrict__ lpart, ushort_t* __restrict__ o_buf) {
  int blk = blockIdx.x;           // b*50+s
  int b = blk / NS, s = blk - b * NS;
  int d = threadIdx.x;            // 0..255
  for (int h = 0; h < NH; ++h) {
    int bh = b * NH + h;
    float mv[NCH];
    float m = -1e30f;
#pragma unroll
    for (int c = 0; c < NCH; ++c) {
      mv[c] = mpart[((long)bh * NCH + c) * NS + s];
      m = fmaxf(m, mv[c]);
    }
    float den = 0.f, o = 0.f;
#pragma unroll
    for (int c = 0; c < NCH; ++c) {
      float wgt = __expf(mv[c] - m);
      den += wgt * lpart[((long)bh * NCH + c) * NS + s];
      o   += wgt * ubf(opart[(((long)bh * NCH + c) * NS + s) * 256 + d]);
    }
    o_buf[(long)blk * 2048 + h * 256 + d] = bf1(o / den);
  }
}

// ---------------------------------------------------------------------------
// gated GEMM (2-phase, swizzled LDS, XCD-swizzled grid (7,128)):
// B = wguT interleaved [8192][1024]. out = gelu(g)*u, bf16 [M][4096].
// ---------------------------------------------------------------------------
__global__ __launch_bounds__(256) void gemm64G(
    const ushort_t* __restrict__ A, const ushort_t* __restrict__ B,
    ushort_t* __restrict__ C, int M, int K, int lda, int ldb, int ldc) {
  const int flat = blockIdx.x + 7 * blockIdx.y;      // 0..895
  const int wgid = (flat & 7) * 112 + (flat >> 3);
  const int m0 = (wgid % 7) * 64;
  const int n0 = (wgid / 7) * 64;
  const int tid = threadIdx.x;
  const int lane = tid & 63;
  const int wbase = tid & 192;
  const int wid = wbase >> 6;
  const int l15 = lane & 15;
  const int l4  = lane >> 4;

  __shared__ ushort_t As[2][64 * 64];
  __shared__ ushort_t Bs[2][64 * 64];

  f32x4 acc[4] = {};

  const int ci0 = wbase + lane;
  const int row0 = ci0 >> 3;
  const int kc0 = (((ci0 & 7) ^ (row0 & 7)) << 3);
  const int ci1 = 256 + ci0;
  const int row1 = ci1 >> 3;
  const int kc1 = (((ci1 & 7) ^ (row1 & 7)) << 3);
  int gra0 = m0 + row0; if (gra0 > M - 1) gra0 = M - 1;
  int gra1 = m0 + row1; if (gra1 > M - 1) gra1 = M - 1;

  auto stage = [&](int buf, int k0) {
    async_cp16(A + (long)gra0 * lda + k0 + kc0, (const char*)As[buf] + ci0 * 16);
    async_cp16(B + (long)(n0 + row0) * ldb + k0 + kc0, (const char*)Bs[buf] + ci0 * 16);
    async_cp16(A + (long)gra1 * lda + k0 + kc1, (const char*)As[buf] + ci1 * 16);
    async_cp16(B + (long)(n0 + row1) * ldb + k0 + kc1, (const char*)Bs[buf] + ci1 * 16);
  };

  const int nt = K >> 6;
  stage(0, 0);
  __syncthreads();
  int cur = 0;
  for (int t = 0; t < nt; ++t) {
    if (t + 1 < nt) stage(cur ^ 1, (t + 1) * 64);
    const ushort_t* Ac = As[cur];
    const ushort_t* Bc = Bs[cur];
#pragma unroll
    for (int ks = 0; ks < 2; ++ks) {
      int arow = wid * 16 + l15;
      short8 af = *reinterpret_cast<const short8*>(&Ac[arow * 64 + SWZ(arow, ks * 32 + l4 * 8)]);
#pragma unroll
      for (int ni = 0; ni < 4; ++ni) {
        int row = ni * 16 + l15;
        short8 bf = *reinterpret_cast<const short8*>(&Bc[row * 64 + SWZ(row, ks * 32 + l4 * 8)]);
        acc[ni] = __builtin_amdgcn_mfma_f32_16x16x32_bf16(af, bf, acc[ni], 0, 0, 0);
      }
    }
    __syncthreads();
    cur ^= 1;
  }

#pragma unroll
  for (int ni = 0; ni < 2; ++ni) {
    int col = (n0 >> 1) + ni * 16 + l15;
    int rb  = m0 + wid * 16 + l4 * 4;
#pragma unroll
    for (int r = 0; r < 4; ++r) {
      int row = rb + r;
      if (row >= M) continue;
      float g = acc[ni][r];
      float u = acc[ni + 2][r];
      float inner = 0.7978845608028654f * (g + 0.044715f * g * g * g);
      // gelu_tanh(g) = g * sigmoid(2*inner)  (exact identity)
      float t = g / (1.f + __expf(-2.f * inner));
      C[(long)row * ldc + col] = bf1(t * u);
    }
  }
}

// ---------------------------------------------------------------------------
// f32-input GEMM (cond path, M=8). EPI: 1=+bias 2=silu(acc+bias)
// ---------------------------------------------------------------------------
template<int EPI>
__global__ __launch_bounds__(256)
void gemm_f32_kernel(const float* __restrict__ A,
                     const float* __restrict__ B1,
                     float* __restrict__ C,
                     int M, int N, int K, int lda, int ldb, int ldc,
                     const float* __restrict__ bias) {
  const int m0 = blockIdx.x * 64;
  const int n0 = blockIdx.y * 64;
  const int tid = threadIdx.x;
  const int lane = tid & 63;
  const int wid = tid >> 6;
  const int wm = (wid >> 1) * 32;
  const int wn = (wid & 1) * 32;
  const int l15 = lane & 15;
  const int l4  = lane >> 4;

  __shared__ __align__(16) ushort_t As[64][72];
  __shared__ __align__(16) ushort_t Bs[64][72];

  f32x4 acc[2][2] = {};

  for (int k0 = 0; k0 < K; k0 += 64) {
#pragma unroll
    for (int pass = 0; pass < 2; ++pass) {
      int c = tid + pass * 256;
      int row = c >> 3;
      int kc = (c & 7) * 8;
      int gr = m0 + row, gk = k0 + kc;
      float v[8];
#pragma unroll
      for (int j = 0; j < 8; ++j)
        v[j] = (gr < M && gk + j < K) ? A[(long)gr * lda + gk + j] : 0.f;
      *reinterpret_cast<uint4*>(&As[row][kc]) =
          make_uint4(pack_bf2(v[0],v[1]), pack_bf2(v[2],v[3]),
                     pack_bf2(v[4],v[5]), pack_bf2(v[6],v[7]));
    }
    {
      int n = tid & 63;
      int kg = tid >> 6;
      int gn = n0 + n;
      u32 pk[8];
#pragma unroll
      for (int kk = 0; kk < 16; kk += 2) {
        int kga = k0 + kg * 16 + kk;
        float v0 = (gn < N && kga < K)     ? B1[(long)kga * ldb + gn] : 0.f;
        float v1 = (gn < N && kga + 1 < K) ? B1[(long)(kga + 1) * ldb + gn] : 0.f;
        pk[kk >> 1] = pack_bf2(v0, v1);
      }
      *reinterpret_cast<uint4*>(&Bs[n][kg * 16])     = make_uint4(pk[0],pk[1],pk[2],pk[3]);
      *reinterpret_cast<uint4*>(&Bs[n][kg * 16 + 8]) = make_uint4(pk[4],pk[5],pk[6],pk[7]);
    }
    __syncthreads();
#pragma unroll
    for (int ks = 0; ks < 2; ++ks) {
      short8 af[2], bfr[2];
#pragma unroll
      for (int mi = 0; mi < 2; ++mi)
        af[mi] = *reinterpret_cast<const short8*>(&As[wm + mi*16 + l15][ks*32 + l4*8]);
#pragma unroll
      for (int ni = 0; ni < 2; ++ni)
        bfr[ni] = *reinterpret_cast<const short8*>(&Bs[wn + ni*16 + l15][ks*32 + l4*8]);
#pragma unroll
      for (int mi = 0; mi < 2; ++mi)
#pragma unroll
        for (int ni = 0; ni < 2; ++ni)
          acc[mi][ni] = __builtin_amdgcn_mfma_f32_16x16x32_bf16(af[mi], bfr[ni], acc[mi][ni], 0, 0, 0);
    }
    __syncthreads();
  }

#pragma unroll
  for (int mi = 0; mi < 2; ++mi) {
#pragma unroll
    for (int ni = 0; ni < 2; ++ni) {
      int col = n0 + wn + ni * 16 + l15;
      int rb  = m0 + wm + mi * 16 + l4 * 4;
#pragma unroll
      for (int r = 0; r < 4; ++r) {
        int row = rb + r;
        if (row < M && col < N) {
          float v = acc[mi][ni][r];
          if (EPI == 1) C[(long)row * ldc + col] = v + bias[col];
          else {
            float t = v + bias[col];
            C[(long)row * ldc + col] = t / (1.f + __expf(-t));
          }
        }
      }
    }
  }
}

// f32-input GEMM with layer batching + split-K, atomicAdd (ada path, M=8)
__global__ __launch_bounds__(256)
void gemm_f32sk(const float* __restrict__ A,
                const float* __restrict__ B, long bz,
                float* __restrict__ C, long cz,
                int M, int N, int K, int lda, int ldb, int ldc, int nks) {
  const int zz = blockIdx.z;
  const int layer = zz / nks;
  const int chunk = zz % nks;
  const int kpb = K / nks;
  const int kbeg = chunk * kpb, kend = kbeg + kpb;
  const float* Bb = B + (long)layer * bz;
  float* Cb = C + (long)layer * cz;

  const int m0 = blockIdx.x * 64;
  const int n0 = blockIdx.y * 64;
  const int tid = threadIdx.x;
  const int lane = tid & 63;
  const int wid = tid >> 6;
  const int wm = (wid >> 1) * 32;
  const int wn = (wid & 1) * 32;
  const int l15 = lane & 15;
  const int l4  = lane >> 4;

  __shared__ __align__(16) ushort_t As[64][72];
  __shared__ __align__(16) ushort_t Bs[64][72];

  f32x4 acc[2][2] = {};

  for (int k0 = kbeg; k0 < kend; k0 += 64) {
#pragma unroll
    for (int pass = 0; pass < 2; ++pass) {
      int c = tid + pass * 256;
      int row = c >> 3;
      int kc = (c & 7) * 8;
      int gr = m0 + row, gk = k0 + kc;
      float v[8];
#pragma unroll
      for (int j = 0; j < 8; ++j)
        v[j] = (gr < M) ? A[(long)gr * lda + gk + j] : 0.f;
      *reinterpret_cast<uint4*>(&As[row][kc]) =
          make_uint4(pack_bf2(v[0],v[1]), pack_bf2(v[2],v[3]),
                     pack_bf2(v[4],v[5]), pack_bf2(v[6],v[7]));
    }
    {
      int n = tid & 63;
      int kg = tid >> 6;
      int gn = n0 + n;
      u32 pk[8];
#pragma unroll
      for (int kk = 0; kk < 16; kk += 2) {
        int kga = k0 + kg * 16 + kk;
        float v0 = Bb[(long)kga * ldb + gn];
        float v1 = Bb[(long)(kga + 1) * ldb + gn];
        pk[kk >> 1] = pack_bf2(v0, v1);
      }
      *reinterpret_cast<uint4*>(&Bs[n][kg * 16])     = make_uint4(pk[0],pk[1],pk[2],pk[3]);
      *reinterpret_cast<uint4*>(&Bs[n][kg * 16 + 8]) = make_uint4(pk[4],pk[5],pk[6],pk[7]);
    }
    __syncthreads();
#pragma unroll
    for (int ks = 0; ks < 2; ++ks) {
      short8 af[2], bfr[2];
#pragma unroll
      for (int mi = 0; mi < 2; ++mi)
        af[mi] = *reinterpret_cast<const short8*>(&As[wm + mi*16 + l15][ks*32 + l4*8]);
#pragma unroll
      for (int ni = 0; ni < 2; ++ni)
        bfr[ni] = *reinterpret_cast<const short8*>(&Bs[wn + ni*16 + l15][ks*32 + l4*8]);
#pragma unroll
      for (int mi = 0; mi < 2; ++mi)
#pragma unroll
        for (int ni = 0; ni < 2; ++ni)
          acc[mi][ni] = __builtin_amdgcn_mfma_f32_16x16x32_bf16(af[mi], bfr[ni], acc[mi][ni], 0, 0, 0);
    }
    __syncthreads();
  }

#pragma unroll
  for (int mi = 0; mi < 2; ++mi) {
#pragma unroll
    for (int ni = 0; ni < 2; ++ni) {
      int col = n0 + wn + ni * 16 + l15;
      int rb  = m0 + wm + mi * 16 + l4 * 4;
#pragma unroll
      for (int r = 0; r < 4; ++r) {
        int row = rb + r;
        if (row < M && col < N)
          atomicAdd(&Cb[(long)row * ldc + col], acc[mi][ni][r]);
      }
    }
  }
}

// ---------------------------------------------------------------------------
extern "C" void kernel_launch(void* const* d_in, const int* in_sizes, int n_in,
                              void* d_out, int out_size, void* d_ws, size_t ws_size,
                              hipStream_t stream) {
  (void)in_sizes; (void)n_in; (void)out_size; (void)ws_size;
  const float* x_t      = (const float*)d_in[1];
  const float* tstep    = (const float*)d_in[2];
  const float* dtp      = (const float*)d_in[3];
  const float* cache_k  = (const float*)d_in[4];
  const float* cache_v  = (const float*)d_in[5];
  const float* w_act_in = (const float*)d_in[6];
  const float* b_act_in = (const float*)d_in[7];
  const float* w_t1     = (const float*)d_in[8];
  const float* b_t1     = (const float*)d_in[9];
  const float* w_t2     = (const float*)d_in[10];
  const float* b_t2     = (const float*)d_in[11];
  const float* ln1_w    = (const float*)d_in[12];
  const float* ada1_w   = (const float*)d_in[13];
  const float* ln2_w    = (const float*)d_in[14];
  const float* wq       = (const float*)d_in[15];
  const float* wk       = (const float*)d_in[16];
  const float* wv       = (const float*)d_in[17];
  const float* wo       = (const float*)d_in[18];
  const float* wg       = (const float*)d_in[19];
  const float* wu       = (const float*)d_in[20];
  const float* wd       = (const float*)d_in[21];
  const float* lnf_w    = (const float*)d_in[22];
  const float* adaf_w   = (const float*)d_in[23];
  const float* wao      = (const float*)d_in[24];
  const float* bao      = (const float*)d_in[25];
  float* outp = (float*)d_out;

  char* p = (char*)d_ws;
  auto alloc = [&](size_t bytes) { char* r = p; p += (bytes + 255) & ~(size_t)255; return r; };

  ushort_t* wqkvT  = (ushort_t*)alloc((size_t)12 * 2560 * 1024 * 2);
  ushort_t* woT    = (ushort_t*)alloc((size_t)12 * 1024 * 2048 * 2);
  ushort_t* wguT   = (ushort_t*)alloc((size_t)12 * 8192 * 1024 * 2);
  ushort_t* wdT    = (ushort_t*)alloc((size_t)12 * 1024 * 4096 * 2);
  ushort_t* kcache = (ushort_t*)alloc((size_t)12 * 8 * NP * 256 * 2);
  ushort_t* vT     = (ushort_t*)alloc((size_t)12 * 8 * 256 * KPAD * 2);
  ushort_t* qT     = (ushort_t*)alloc((size_t)64 * NS * 256 * 2);
  ushort_t* k_new  = (ushort_t*)alloc((size_t)400 * 256 * 2);
  ushort_t* opart  = (ushort_t*)alloc((size_t)64 * NCH * NS * 256 * 2);
  float*    mpart  = (float*)alloc((size_t)64 * NCH * NS * 4);
  float*    lpart  = (float*)alloc((size_t)64 * NCH * NS * 4);
  float*    woP    = (float*)alloc((size_t)8 * 400 * 1024 * 4);   // wo split-K slabs
  float*    wdP    = (float*)alloc((size_t)8 * 400 * 1024 * 4);   // wd split-K slabs
  ushort_t* o_buf  = (ushort_t*)alloc((size_t)400 * 2048 * 2);
  ushort_t* t_buf  = (ushort_t*)alloc((size_t)400 * 4096 * 2);
  ushort_t* x_buf  = (ushort_t*)alloc((size_t)400 * 1024 * 2);
  float*    h_buf  = (float*)alloc((size_t)400 * 1024 * 4);
  float*    temb   = (float*)alloc(8 * 1024 * 4);
  float*    tmp    = (float*)alloc(8 * 1024 * 4);
  float*    cond   = (float*)alloc(8 * 1024 * 4);
  float*    ada_all= (float*)alloc((size_t)12 * 8 * 1024 * 4);   // zeroed
  float*    adaf_o = (float*)alloc(8 * 1024 * 4);                // zeroed (adjacent)
  float*    cosT   = (float*)alloc(NS * 128 * 4);
  float*    sinT   = (float*)alloc(NS * 128 * 4);
  ushort_t* zpad   = (ushort_t*)alloc(512 * 2);

  hipMemsetAsync(zpad, 0, 512 * 2, stream);
  hipMemsetAsync(ada_all, 0, ((size_t)12 * 8 * 1024 + 8 * 1024) * 4, stream);

  // ---- conversion pass ----
  cvt_permute_kernel<<<9600, 256, 0, stream>>>(cache_k, kcache, (long)12 * 8 * NP);
  transpose_cvt<2><<<dim3(32, 16, 12), 256, 0, stream>>>(wq, (long)1024 * 2048, wqkvT, (long)2560 * 1024, 1024, 2048, 1024, 0);
  transpose_cvt<2><<<dim3(4, 16, 12), 256, 0, stream>>>(wk, (long)1024 * 256, wqkvT + (long)2048 * 1024, (long)2560 * 1024, 1024, 256, 1024, 0);
  transpose_cvt<0><<<dim3(4, 16, 12), 256, 0, stream>>>(wv, (long)1024 * 256, wqkvT + (long)2304 * 1024, (long)2560 * 1024, 1024, 256, 1024, 0);
  transpose_cvt<0><<<dim3(16, 32, 12), 256, 0, stream>>>(wo, (long)2048 * 1024, woT, (long)1024 * 2048, 2048, 1024, 2048, 0);
  transpose_cvt<1><<<dim3(64, 16, 12), 256, 0, stream>>>(wg, (long)1024 * 4096, wguT, (long)8192 * 1024, 1024, 4096, 1024, 0);
  transpose_cvt<1><<<dim3(64, 16, 12), 256, 0, stream>>>(wu, (long)1024 * 4096, wguT, (long)8192 * 1024, 1024, 4096, 1024, 32);
  transpose_cvt<0><<<dim3(16, 64, 12), 256, 0, stream>>>(wd, (long)4096 * 1024, wdT, (long)1024 * 4096, 4096, 1024, 4096, 0);
  transpose_cvt<0><<<dim3(4, 13, 96), 256, 0, stream>>>(cache_v, (long)NP * 256, vT, (long)256 * KPAD, NP, 256, KPAD, 0);

  // ---- embed + cond ----
  temb_kernel<<<32, 256, 0, stream>>>(tstep, temb);
  suffix_kernel<<<400, 256, 0, stream>>>(x_t, w_act_in, b_act_in, h_buf);
  rope_table_kernel<<<25, 256, 0, stream>>>(cosT, sinT);
  gemm_f32_kernel<2><<<dim3(1, 16, 1), 256, 0, stream>>>(temb, w_t1, tmp, NB, ND, ND, ND, ND, ND, b_t1);
  gemm_f32_kernel<1><<<dim3(1, 16, 1), 256, 0, stream>>>(tmp, w_t2, cond, NB, ND, ND, ND, ND, ND, b_t2);
  gemm_f32sk<<<dim3(1, 16, 48), 256, 0, stream>>>(cond, ada1_w, (long)ND * ND, ada_all, (long)NB * ND, NB, ND, ND, ND, ND, ND, 4);
  gemm_f32sk<<<dim3(1, 16, 4), 256, 0, stream>>>(cond, adaf_w, 0, adaf_o, 0, NB, ND, ND, ND, ND, ND, 4);

  for (int l = 0; l < NLAYER; ++l) {
    ushort_t* vT_l = vT + (long)l * 8 * 256 * KPAD;
    // rms1: complete previous layer's mlp residual (8 wd slabs), then rms*ada
    rms_kernel<true><<<400, 256, 0, stream>>>(
        h_buf, l == 0 ? nullptr : wdP, ln1_w + (long)l * ND, ada_all + (long)l * NB * ND, x_buf);
    // qkv + fused rope scatter (280 blocks, XCD-swizzled)
    gemm64rope<<<dim3(7, 40, 1), 256, 0, stream>>>(
        x_buf, wqkvT + (long)l * 2560 * 1024, cosT, sinT, qT, k_new, vT_l);
    // flash3 attention partials (448 blocks, 7 chunks of 128 keys, XCD-swizzled)
    flash3_kernel<<<dim3(64, NCH, 1), 256, 0, stream>>>(
        qT, kcache + (long)l * 8 * NP * 256, k_new, vT_l, zpad, opart, mpart, lpart);
    att_combine<<<400, 256, 0, stream>>>(opart, mpart, lpart, o_buf);
    // wo: split-K 8 slab writes (896 blocks, XCD-swizzled)
    gemm64slab<<<dim3(7, 16, 8), 256, 0, stream>>>(
        o_buf, woT + (long)l * 1024 * 2048, woP, 400, 1024, 2048, 2048, 2048, 1024, 256);
    // rms2: h += sum(woP); rms
    rms_kernel<true><<<400, 256, 0, stream>>>(
        h_buf, woP, ln2_w + (long)l * ND, nullptr, x_buf);
    // t = gelu(x@wg)*(x@wu)  fused  (896 blocks, XCD-swizzled)
    gemm64G<<<dim3(7, 128, 1), 256, 0, stream>>>(
        x_buf, wguT + (long)l * 8192 * 1024, t_buf, 400, 1024, 1024, 1024, 4096);
    // wd: split-K 8 slab writes (896 blocks, XCD-swizzled)
    gemm64slab<<<dim3(7, 16, 8), 256, 0, stream>>>(
        t_buf, wdT + (long)l * 1024 * 4096, wdP, 400, 1024, 4096, 4096, 4096, 1024, 512);
  }

  final_fused<<<400, 256, 0, stream>>>(h_buf, wdP, lnf_w, adaf_o, wao, bao, x_t, dtp, outp);
}